// Round 7
// baseline (7211.562 us; speedup 1.0000x reference)
//
#include <hip/hip_runtime.h>
#include <cfloat>

constexpr int BATCH = 8, NPTS = 2048, KNN = 20;
constexpr int NROWS = BATCH * NPTS;
constexpr float EPSV = 1e-5f;
constexpr int QCAP = 512;

using u16 = unsigned short;
using u64 = unsigned long long;

// ---------------------------------------------------------------- diag / fill
__global__ void diag_kernel(float* out, float v) {
    if (threadIdx.x < 8) out[threadIdx.x] = v;
}

__global__ __launch_bounds__(256) void fill_zero_kernel(float* __restrict__ p, int n) {
    int i = blockIdx.x * 256 + threadIdx.x;
    if (i < n) p[i] = 0.f;
}

// ---------------------------------------------------------------- sqnorm over all rows
template<int C>
__global__ __launch_bounds__(256) void sqnorm_kernel(const float* __restrict__ X,
                                                     float* __restrict__ sq) {
    int r = blockIdx.x * 256 + threadIdx.x;     // grid = NROWS/256
    const float* x = X + (size_t)r * C;
    float s = 0.f;
#pragma unroll
    for (int c = 0; c < C; ++c) { float v = x[c]; s = fmaf(v, v, s); }
    sq[r] = s;
}

// ---------------------------------------------------------------- dist GEMM: D[i][j] = x_i · x_j (batch b), 64x64 tile, 4x4/lane
template<int C>
__global__ __launch_bounds__(256) void dist_gemm_kernel(const float* __restrict__ X,
                                                        float* __restrict__ D, int b) {
    constexpr int KC = (C < 32) ? C : 32;
    __shared__ __align__(16) float As[KC][68];
    __shared__ __align__(16) float Bs[KC][68];
    int i0 = blockIdx.y * 64, j0 = blockIdx.x * 64;
    const float* Xb = X + (size_t)b * NPTS * C;
    int tx = threadIdx.x & 15, ty = threadIdx.x >> 4;
    float acc[4][4] = {};
    for (int c0 = 0; c0 < C; c0 += KC) {
        for (int t = threadIdx.x; t < 64 * KC; t += 256) {
            int i = t / KC, c = t % KC;
            As[c][i] = Xb[(size_t)(i0 + i) * C + c0 + c];
            Bs[c][i] = Xb[(size_t)(j0 + i) * C + c0 + c];
        }
        __syncthreads();
#pragma unroll
        for (int c = 0; c < KC; ++c) {
            const float4 av = *(const float4*)&As[c][ty * 4];
            const float4 bv = *(const float4*)&Bs[c][tx * 4];
            float ar[4] = {av.x, av.y, av.z, av.w};
            float br[4] = {bv.x, bv.y, bv.z, bv.w};
#pragma unroll
            for (int r = 0; r < 4; ++r)
#pragma unroll
                for (int q = 0; q < 4; ++q) acc[r][q] = fmaf(ar[r], br[q], acc[r][q]);
        }
        __syncthreads();
    }
#pragma unroll
    for (int r = 0; r < 4; ++r) {
        float4 o4 = make_float4(acc[r][0], acc[r][1], acc[r][2], acc[r][3]);
        *(float4*)&D[(size_t)(i0 + ty * 4 + r) * NPTS + j0 + tx * 4] = o4;
    }
}

// ---------------------------------------------------------------- wave-64 bitonic sorts (descending, lane 0 = max)
__device__ __forceinline__ float bitonic64_desc_f32(float key, int lane) {
#pragma unroll
    for (int k = 2; k <= 64; k <<= 1) {
#pragma unroll
        for (int j = k >> 1; j > 0; j >>= 1) {
            float p = __shfl_xor(key, j);
            bool keepMax = (((lane & j) == 0) == ((lane & k) == 0));
            key = ((key > p) == keepMax) ? key : p;
        }
    }
    return key;
}

__device__ __forceinline__ u64 bitonic64_desc_u64(u64 key, int lane) {
#pragma unroll
    for (int k = 2; k <= 64; k <<= 1) {
#pragma unroll
        for (int j = k >> 1; j > 0; j >>= 1) {
            u64 p = __shfl_xor(key, j);
            bool keepMax = (((lane & j) == 0) == ((lane & k) == 0));
            key = ((key > p) == keepMax) ? key : p;
        }
    }
    return key;
}

// ---------------------------------------------------------------- top-k: threshold from 20th lane-max, then exact bitonic select
// one wave per row; exact top_k semantics (value desc, idx asc ties)
__global__ __launch_bounds__(256) void topk_kernel(const float* __restrict__ D,
                                                   const float* __restrict__ sq,
                                                   u16* __restrict__ idx_out, int b) {
    __shared__ u64 qkey[4][QCAP];
    __shared__ int qn[4];
    int w = threadIdx.x >> 6, lane = threadIdx.x & 63;
    int i = blockIdx.x * 4 + w;
    const float* Drow = D + (size_t)i * NPTS;
    const float* sqb = sq + b * NPTS;
    float sqi = sqb[i];
    if (lane == 0) qn[w] = 0;

    // phase A: 32 values in registers + lane max
    float vals[32];
    float mx = -FLT_MAX;
#pragma unroll
    for (int t = 0; t < 8; ++t) {
        int j = t * 256 + lane * 4;
        float4 v4 = *(const float4*)&Drow[j];
        float4 s4 = *(const float4*)&sqb[j];
        float a0 = (2.f * v4.x - sqi - s4.x) + 0.f;   // +0 folds -0 -> +0
        float a1 = (2.f * v4.y - sqi - s4.y) + 0.f;
        float a2 = (2.f * v4.z - sqi - s4.z) + 0.f;
        float a3 = (2.f * v4.w - sqi - s4.w) + 0.f;
        vals[t * 4 + 0] = a0; vals[t * 4 + 1] = a1;
        vals[t * 4 + 2] = a2; vals[t * 4 + 3] = a3;
        mx = fmaxf(mx, fmaxf(fmaxf(a0, a1), fmaxf(a2, a3)));
    }

    // phase B: T0 = 20th largest lane max (provable lower bound on true 20th value)
    float sm = bitonic64_desc_f32(mx, lane);
    float T0 = __shfl(sm, 19);

    // phase C: compact candidates >= T0 into LDS queue as packed sort keys
#pragma unroll
    for (int t = 0; t < 32; ++t) {
        float v = vals[t];
        if (v >= T0) {
            unsigned j = (unsigned)((t >> 2) * 256 + lane * 4 + (t & 3));
            unsigned bu = __float_as_uint(v);
            unsigned u = (bu & 0x80000000u) ? ~bu : (bu | 0x80000000u);
            u64 key = ((u64)u << 32) | (u64)(0xFFFFFFFFu - j);
            int slot = atomicAdd(&qn[w], 1);
            if (slot < QCAP) qkey[w][slot] = key;
        }
    }
    int C = qn[w];
    if (C > QCAP) C = QCAP;                      // degenerate clamp

    // phase D: bitonic select of top-20 (chunked if C > 64)
    u64 key = (lane < C) ? qkey[w][lane] : 0ull;
    key = bitonic64_desc_u64(key, lane);
    int base = 64;
    while (base < C) {
        if (lane >= 20) {
            int src = base + (lane - 20);
            key = (src < C) ? qkey[w][src] : 0ull;
        }
        key = bitonic64_desc_u64(key, lane);
        base += 44;
    }
    if (lane < 20) {
        unsigned j = 0xFFFFFFFFu - (unsigned)(key & 0xFFFFFFFFull);
        idx_out[(size_t)(b * NPTS + i) * KNN + lane] = (u16)j;
    }
}

// ---------------------------------------------------------------- per-batch UV GEMM: UVb[r][0:O]=W1·x_r, [O:2O]=(W2-W1)·x_r + bias
template<int C, int O>
__global__ __launch_bounds__(256) void uvb_gemm_kernel(const float* __restrict__ X,
                                                       const float* __restrict__ W,
                                                       const float* __restrict__ bias,
                                                       float* __restrict__ UVb, int b) {
    constexpr int KC = (C < 32) ? C : 32;
    __shared__ __align__(16) float As[KC][68];
    __shared__ __align__(16) float Bs[KC][68];
    int r0 = blockIdx.y * 64, n0 = blockIdx.x * 64;
    int tx = threadIdx.x & 15, ty = threadIdx.x >> 4;
    float acc[4][4] = {};
    for (int c0 = 0; c0 < C; c0 += KC) {
        for (int t = threadIdx.x; t < 64 * KC; t += 256) {
            int i = t / KC, c = t % KC;
            As[c][i] = X[(size_t)(b * NPTS + r0 + i) * C + c0 + c];
            int n = n0 + i;
            float wv;
            if (n < O) wv = W[(size_t)n * (2 * C) + c0 + c];
            else {
                int o = n - O;
                wv = W[(size_t)o * (2 * C) + C + c0 + c] - W[(size_t)o * (2 * C) + c0 + c];
            }
            Bs[c][i] = wv;
        }
        __syncthreads();
#pragma unroll
        for (int c = 0; c < KC; ++c) {
            const float4 av = *(const float4*)&As[c][ty * 4];
            const float4 bv = *(const float4*)&Bs[c][tx * 4];
            float ar[4] = {av.x, av.y, av.z, av.w};
            float br[4] = {bv.x, bv.y, bv.z, bv.w};
#pragma unroll
            for (int r = 0; r < 4; ++r)
#pragma unroll
                for (int q = 0; q < 4; ++q) acc[r][q] = fmaf(ar[r], br[q], acc[r][q]);
        }
        __syncthreads();
    }
    float badd[4] = {0.f, 0.f, 0.f, 0.f};
    if (n0 >= O) {
#pragma unroll
        for (int q = 0; q < 4; ++q) badd[q] = bias[n0 - O + tx * 4 + q];
    }
#pragma unroll
    for (int r = 0; r < 4; ++r) {
        float4 o4 = make_float4(acc[r][0] + badd[0], acc[r][1] + badd[1],
                                acc[r][2] + badd[2], acc[r][3] + badd[3]);
        *(float4*)&UVb[(size_t)(r0 + ty * 4 + r) * (2 * O) + n0 + tx * 4] = o4;
    }
}

// ---------------------------------------------------------------- stats: global sum/sumsq of h over batch b (float4 gathers)
template<int O>
__global__ __launch_bounds__(256) void statsb_kernel(const float* __restrict__ UVb,
                                                     const u16* __restrict__ idx,
                                                     float* __restrict__ sums, int b) {
    constexpr int TPR = O / 4;                  // threads per row
    constexpr int RPAR = 256 / TPR;             // rows in parallel per block
    constexpr int RPB = NPTS / 128;             // grid = 128
    int o = (threadIdx.x % TPR) * 4;
    int rsub = threadIdx.x / TPR;
    int rbase = blockIdx.x * RPB;
    float s0 = 0, s1 = 0, s2 = 0, s3 = 0, q0 = 0, q1 = 0, q2 = 0, q3 = 0;
    for (int r = rbase + rsub; r < rbase + RPB; r += RPAR) {
        const float4 v4 = *(const float4*)&UVb[(size_t)r * (2 * O) + O + o];
        const u16* ix = idx + (size_t)(b * NPTS + r) * KNN;
#pragma unroll
        for (int k = 0; k < KNN; ++k) {
            int j = (int)ix[k] & (NPTS - 1);
            const float4 u4 = *(const float4*)&UVb[(size_t)j * (2 * O) + o];
            float h0 = u4.x + v4.x, h1 = u4.y + v4.y, h2 = u4.z + v4.z, h3 = u4.w + v4.w;
            s0 += h0; q0 = fmaf(h0, h0, q0);
            s1 += h1; q1 = fmaf(h1, h1, q1);
            s2 += h2; q2 = fmaf(h2, h2, q2);
            s3 += h3; q3 = fmaf(h3, h3, q3);
        }
    }
    atomicAdd(&sums[o + 0], s0); atomicAdd(&sums[o + 1], s1);
    atomicAdd(&sums[o + 2], s2); atomicAdd(&sums[o + 3], s3);
    atomicAdd(&sums[O + o + 0], q0); atomicAdd(&sums[O + o + 1], q1);
    atomicAdd(&sums[O + o + 2], q2); atomicAdd(&sums[O + o + 3], q3);
}

template<int O>
__global__ void bnp_kernel(const float* __restrict__ sums, const float* __restrict__ g,
                           const float* __restrict__ beta, float* __restrict__ bnp) {
    int o = threadIdx.x;
    const float cnt = (float)NROWS * (float)KNN;
    float m = sums[o] / cnt;
    float var = sums[O + o] / cnt - m * m;
    float sc = g[o] / sqrtf(var + EPSV);
    bnp[o] = sc;
    bnp[O + o] = beta[o] - m * sc;
}

// ---------------------------------------------------------------- apply: gather max/min + BN + relu -> Xn (stages 1..3, float4)
template<int O>
__global__ __launch_bounds__(256) void applyb_kernel(const float* __restrict__ UVb,
                                                     const u16* __restrict__ idx,
                                                     const float* __restrict__ bnp,
                                                     float* __restrict__ Xn, int b) {
    constexpr int TPR = O / 4;
    int e = blockIdx.x * 256 + threadIdx.x;     // grid = NPTS*TPR/256
    int o = (e % TPR) * 4, r = e / TPR;
    const float4 v4 = *(const float4*)&UVb[(size_t)r * (2 * O) + O + o];
    const u16* ix = idx + (size_t)(b * NPTS + r) * KNN;
    float mx0 = -FLT_MAX, mx1 = -FLT_MAX, mx2 = -FLT_MAX, mx3 = -FLT_MAX;
    float mn0 = FLT_MAX, mn1 = FLT_MAX, mn2 = FLT_MAX, mn3 = FLT_MAX;
#pragma unroll
    for (int k = 0; k < KNN; ++k) {
        int j = (int)ix[k] & (NPTS - 1);
        const float4 u4 = *(const float4*)&UVb[(size_t)j * (2 * O) + o];
        float h0 = u4.x + v4.x, h1 = u4.y + v4.y, h2 = u4.z + v4.z, h3 = u4.w + v4.w;
        mx0 = fmaxf(mx0, h0); mn0 = fminf(mn0, h0);
        mx1 = fmaxf(mx1, h1); mn1 = fminf(mn1, h1);
        mx2 = fmaxf(mx2, h2); mn2 = fminf(mn2, h2);
        mx3 = fmaxf(mx3, h3); mn3 = fminf(mn3, h3);
    }
    float4 out;
    {
        float sc = bnp[o + 0], t = bnp[O + o + 0];
        out.x = fmaxf(fmaf(sc, (sc >= 0.f) ? mx0 : mn0, t), 0.f);
    }
    {
        float sc = bnp[o + 1], t = bnp[O + o + 1];
        out.y = fmaxf(fmaf(sc, (sc >= 0.f) ? mx1 : mn1, t), 0.f);
    }
    {
        float sc = bnp[o + 2], t = bnp[O + o + 2];
        out.z = fmaxf(fmaf(sc, (sc >= 0.f) ? mx2 : mn2, t), 0.f);
    }
    {
        float sc = bnp[o + 3], t = bnp[O + o + 3];
        out.w = fmaxf(fmaf(sc, (sc >= 0.f) ? mx3 : mn3, t), 0.f);
    }
    *(float4*)&Xn[(size_t)(b * NPTS + r) * O + o] = out;
}

// ---------------------------------------------------------------- stage-4 apply: fuse point-max into G0T (float4 gathers)
__global__ __launch_bounds__(256) void applyb4_kernel(const float* __restrict__ UVb,
                                                      const u16* __restrict__ idx,
                                                      const float* __restrict__ bnp,
                                                      float* __restrict__ g0T, int b) {
    constexpr int O = 256;
    constexpr int TPR = O / 4;
    int e = blockIdx.x * 256 + threadIdx.x;     // grid = NPTS*TPR/256 = 512
    int o = (e % TPR) * 4, r = e / TPR;
    const float4 v4 = *(const float4*)&UVb[(size_t)r * (2 * O) + O + o];
    const u16* ix = idx + (size_t)(b * NPTS + r) * KNN;
    float mx0 = -FLT_MAX, mx1 = -FLT_MAX, mx2 = -FLT_MAX, mx3 = -FLT_MAX;
    float mn0 = FLT_MAX, mn1 = FLT_MAX, mn2 = FLT_MAX, mn3 = FLT_MAX;
#pragma unroll
    for (int k = 0; k < KNN; ++k) {
        int j = (int)ix[k] & (NPTS - 1);
        const float4 u4 = *(const float4*)&UVb[(size_t)j * (2 * O) + o];
        float h0 = u4.x + v4.x, h1 = u4.y + v4.y, h2 = u4.z + v4.z, h3 = u4.w + v4.w;
        mx0 = fmaxf(mx0, h0); mn0 = fminf(mn0, h0);
        mx1 = fmaxf(mx1, h1); mn1 = fminf(mn1, h1);
        mx2 = fmaxf(mx2, h2); mn2 = fminf(mn2, h2);
        mx3 = fmaxf(mx3, h3); mn3 = fminf(mn3, h3);
    }
#pragma unroll
    for (int q = 0; q < 4; ++q) {
        float mxv = q == 0 ? mx0 : q == 1 ? mx1 : q == 2 ? mx2 : mx3;
        float mnv = q == 0 ? mn0 : q == 1 ? mn1 : q == 2 ? mn2 : mn3;
        float sc = bnp[o + q], t = bnp[O + o + q];
        float y = fmaxf(fmaf(sc, (sc >= 0.f) ? mxv : mnv, t), 0.f);
        atomicMax((int*)&g0T[(o + q) * 8 + b], __float_as_int(y));   // y >= 0: int order ok
    }
}

// ---------------------------------------------------------------- point-max of X2/X3 into G0T channels [256,448)
__global__ __launch_bounds__(256) void gmax23_kernel(const float* __restrict__ X2,
                                                     const float* __restrict__ X3,
                                                     float* __restrict__ g0T) {
    int b = blockIdx.x;
    int n0 = blockIdx.y * 256;
    int o = threadIdx.x;
    if (o >= 192) return;
    const float* src; int col, stride, ch;
    if (o < 128) { src = X3; col = o;       stride = 128; ch = 256 + o; }
    else         { src = X2; col = o - 128; stride = 64;  ch = 384 + (o - 128); }
    float m = 0.f;
#pragma unroll 8
    for (int n = n0; n < n0 + 256; ++n)
        m = fmaxf(m, src[((size_t)(b * NPTS + n)) * stride + col]);
    atomicMax((int*)&g0T[ch * 8 + b], __float_as_int(m));
}

// ---------------------------------------------------------------- fc weight transpose ([o][c] -> [c][o])
__global__ __launch_bounds__(256) void transpose_kernel(const float* __restrict__ w,
                                                        float* __restrict__ wT, int O, int Cc) {
    int e = blockIdx.x * 256 + threadIdx.x;
    if (e >= O * Cc) return;
    int o = e / Cc, c = e - o * Cc;
    wT[c * O + o] = w[e];
}

// ---------------------------------------------------------------- fc1 + bnf1 + relu (batch stats in-register)
__global__ __launch_bounds__(64) void fc1_kernel(const float* __restrict__ g0T,
                                                 const float* __restrict__ w1T,
                                                 const float* __restrict__ b1,
                                                 const float* __restrict__ bng,
                                                 const float* __restrict__ bnb,
                                                 float* __restrict__ A) {
    int o = blockIdx.x * 64 + threadIdx.x;
    float acc[8] = {};
    for (int c = 0; c < 448; ++c) {
        float wv = w1T[c * 256 + o];
        const float4 h0 = *(const float4*)&g0T[c * 8];
        const float4 h1 = *(const float4*)&g0T[c * 8 + 4];
        acc[0] = fmaf(wv, h0.x, acc[0]); acc[1] = fmaf(wv, h0.y, acc[1]);
        acc[2] = fmaf(wv, h0.z, acc[2]); acc[3] = fmaf(wv, h0.w, acc[3]);
        acc[4] = fmaf(wv, h1.x, acc[4]); acc[5] = fmaf(wv, h1.y, acc[5]);
        acc[6] = fmaf(wv, h1.z, acc[6]); acc[7] = fmaf(wv, h1.w, acc[7]);
    }
    float bb = b1[o];
    float h[8], m = 0.f;
#pragma unroll
    for (int b = 0; b < 8; ++b) { h[b] = acc[b] + bb; m += h[b]; }
    m *= 0.125f;
    float var = 0.f;
#pragma unroll
    for (int b = 0; b < 8; ++b) { float d = h[b] - m; var = fmaf(d, d, var); }
    var *= 0.125f;
    float sc = bng[o] / sqrtf(var + EPSV);
    float t = bnb[o] - m * sc;
#pragma unroll
    for (int b = 0; b < 8; ++b) A[o * 8 + b] = fmaxf(fmaf(sc, h[b], t), 0.f);
}

// ---------------------------------------------------------------- fc2..fc4 tail (one block)
__global__ __launch_bounds__(256) void tail_kernel(const float* __restrict__ A,
                                                   const float* __restrict__ w2T, const float* __restrict__ b2,
                                                   const float* __restrict__ g2, const float* __restrict__ be2,
                                                   const float* __restrict__ w3T, const float* __restrict__ b3,
                                                   const float* __restrict__ g3, const float* __restrict__ be3,
                                                   const float* __restrict__ w4, const float* __restrict__ b4,
                                                   float* __restrict__ out) {
    __shared__ __align__(16) float B2[128 * 8];
    __shared__ __align__(16) float C3[16 * 8];
    int tid = threadIdx.x;
    if (tid < 128) {
        int o = tid;
        float acc[8] = {};
        for (int c = 0; c < 256; ++c) {
            float wv = w2T[c * 128 + o];
            const float4 a0 = *(const float4*)&A[c * 8];
            const float4 a1 = *(const float4*)&A[c * 8 + 4];
            acc[0] = fmaf(wv, a0.x, acc[0]); acc[1] = fmaf(wv, a0.y, acc[1]);
            acc[2] = fmaf(wv, a0.z, acc[2]); acc[3] = fmaf(wv, a0.w, acc[3]);
            acc[4] = fmaf(wv, a1.x, acc[4]); acc[5] = fmaf(wv, a1.y, acc[5]);
            acc[6] = fmaf(wv, a1.z, acc[6]); acc[7] = fmaf(wv, a1.w, acc[7]);
        }
        float bb = b2[o];
        float h[8], m = 0.f;
#pragma unroll
        for (int b = 0; b < 8; ++b) { h[b] = acc[b] + bb; m += h[b]; }
        m *= 0.125f;
        float var = 0.f;
#pragma unroll
        for (int b = 0; b < 8; ++b) { float d = h[b] - m; var = fmaf(d, d, var); }
        var *= 0.125f;
        float sc = g2[o] / sqrtf(var + EPSV);
        float t = be2[o] - m * sc;
#pragma unroll
        for (int b = 0; b < 8; ++b) B2[o * 8 + b] = fmaxf(fmaf(sc, h[b], t), 0.f);
    }
    __syncthreads();
    if (tid < 16) {
        int o = tid;
        float acc[8] = {};
        for (int c = 0; c < 128; ++c) {
            float wv = w3T[c * 16 + o];
            const float4 a0 = *(const float4*)&B2[c * 8];
            const float4 a1 = *(const float4*)&B2[c * 8 + 4];
            acc[0] = fmaf(wv, a0.x, acc[0]); acc[1] = fmaf(wv, a0.y, acc[1]);
            acc[2] = fmaf(wv, a0.z, acc[2]); acc[3] = fmaf(wv, a0.w, acc[3]);
            acc[4] = fmaf(wv, a1.x, acc[4]); acc[5] = fmaf(wv, a1.y, acc[5]);
            acc[6] = fmaf(wv, a1.z, acc[6]); acc[7] = fmaf(wv, a1.w, acc[7]);
        }
        float bb = b3[o];
        float h[8], m = 0.f;
#pragma unroll
        for (int b = 0; b < 8; ++b) { h[b] = acc[b] + bb; m += h[b]; }
        m *= 0.125f;
        float var = 0.f;
#pragma unroll
        for (int b = 0; b < 8; ++b) { float d = h[b] - m; var = fmaf(d, d, var); }
        var *= 0.125f;
        float sc = g3[o] / sqrtf(var + EPSV);
        float t = be3[o] - m * sc;
#pragma unroll
        for (int b = 0; b < 8; ++b) C3[o * 8 + b] = fmaxf(fmaf(sc, h[b], t), 0.f);
    }
    __syncthreads();
    if (tid < 8) {
        int b = tid;
        float acc = b4[0];
#pragma unroll
        for (int c = 0; c < 16; ++c) acc = fmaf(w4[c], C3[c * 8 + b], acc);
        out[b] = acc;
    }
}

// ================================================================ host side
struct Arena {
    char* base; size_t off, cap; bool ok;
    Arena(void* b, size_t c) : base((char*)b), off(0), cap(c), ok(true) {}
    void* get(size_t bytes) {
        char* p = base + off;
        off += (bytes + 255) & ~(size_t)255;
        if (off > cap) ok = false;
        return p;
    }
};

// one EdgeConv stage, output stored to Xout (stages 1..3)
template<int C, int O>
static void run_stage(const float* Xin, float* Xout, const float* W, const float* bias,
                      const float* g, const float* be, float* SCR,
                      u16* IDX, float* SQ, float* SUMS, float* BNP, hipStream_t s) {
    dim3 blk(256);
    sqnorm_kernel<C><<<NROWS / 256, blk, 0, s>>>(Xin, SQ);
    for (int b = 0; b < BATCH; ++b) {
        dist_gemm_kernel<C><<<dim3(NPTS / 64, NPTS / 64), blk, 0, s>>>(Xin, SCR, b);
        topk_kernel<<<NPTS / 4, blk, 0, s>>>(SCR, SQ, IDX, b);
    }
    fill_zero_kernel<<<2, blk, 0, s>>>(SUMS, 512);
    for (int b = 0; b < BATCH; ++b) {
        uvb_gemm_kernel<C, O><<<dim3(2 * O / 64, NPTS / 64), blk, 0, s>>>(Xin, W, bias, SCR, b);
        statsb_kernel<O><<<128, blk, 0, s>>>(SCR, IDX, SUMS, b);
    }
    bnp_kernel<O><<<1, O, 0, s>>>(SUMS, g, be, BNP);
    for (int b = 0; b < BATCH; ++b) {
        uvb_gemm_kernel<C, O><<<dim3(2 * O / 64, NPTS / 64), blk, 0, s>>>(Xin, W, bias, SCR, b);
        applyb_kernel<O><<<NPTS * (O / 4) / 256, blk, 0, s>>>(SCR, IDX, BNP, Xout, b);
    }
}

// stage 4: point-max fused into G0T (no X4 buffer)
static void run_stage4(const float* Xin, const float* W, const float* bias,
                       const float* g, const float* be, float* SCR,
                       u16* IDX, float* SQ, float* SUMS, float* BNP, float* G0T,
                       hipStream_t s) {
    constexpr int C = 128;
    dim3 blk(256);
    sqnorm_kernel<C><<<NROWS / 256, blk, 0, s>>>(Xin, SQ);
    for (int b = 0; b < BATCH; ++b) {
        dist_gemm_kernel<C><<<dim3(NPTS / 64, NPTS / 64), blk, 0, s>>>(Xin, SCR, b);
        topk_kernel<<<NPTS / 4, blk, 0, s>>>(SCR, SQ, IDX, b);
    }
    fill_zero_kernel<<<2, blk, 0, s>>>(SUMS, 512);
    for (int b = 0; b < BATCH; ++b) {
        uvb_gemm_kernel<C, 256><<<dim3(8, NPTS / 64), blk, 0, s>>>(Xin, W, bias, SCR, b);
        statsb_kernel<256><<<128, blk, 0, s>>>(SCR, IDX, SUMS, b);
    }
    bnp_kernel<256><<<1, 256, 0, s>>>(SUMS, g, be, BNP);
    fill_zero_kernel<<<14, blk, 0, s>>>(G0T, 448 * 8);
    for (int b = 0; b < BATCH; ++b) {
        uvb_gemm_kernel<C, 256><<<dim3(8, NPTS / 64), blk, 0, s>>>(Xin, W, bias, SCR, b);
        applyb4_kernel<<<512, blk, 0, s>>>(SCR, IDX, BNP, G0T, b);
    }
}

extern "C" void kernel_launch(void* const* d_in, const int* in_sizes, int n_in,
                              void* d_out, int out_size, void* d_ws, size_t ws_size,
                              hipStream_t stream) {
    float* out = (float*)d_out;
    if (n_in < 31) { diag_kernel<<<1, 64, 0, stream>>>(out, 9000.f); return; }

    const float* x       = (const float*)d_in[0];
    const float* cw[4]   = {(const float*)d_in[1], (const float*)d_in[5], (const float*)d_in[9],  (const float*)d_in[13]};
    const float* cb[4]   = {(const float*)d_in[2], (const float*)d_in[6], (const float*)d_in[10], (const float*)d_in[14]};
    const float* bg[4]   = {(const float*)d_in[3], (const float*)d_in[7], (const float*)d_in[11], (const float*)d_in[15]};
    const float* bb[4]   = {(const float*)d_in[4], (const float*)d_in[8], (const float*)d_in[12], (const float*)d_in[16]};
    const float* fc1_w = (const float*)d_in[17]; const float* fc1_b = (const float*)d_in[18];
    const float* bnf1_g = (const float*)d_in[19]; const float* bnf1_b = (const float*)d_in[20];
    const float* fc2_w = (const float*)d_in[21]; const float* fc2_b = (const float*)d_in[22];
    const float* bnf2_g = (const float*)d_in[23]; const float* bnf2_b = (const float*)d_in[24];
    const float* fc3_w = (const float*)d_in[25]; const float* fc3_b = (const float*)d_in[26];
    const float* bnf3_g = (const float*)d_in[27]; const float* bnf3_b = (const float*)d_in[28];
    const float* fc4_w = (const float*)d_in[29]; const float* fc4_b = (const float*)d_in[30];

    Arena ar(d_ws, ws_size);
    float* X1 = (float*)ar.get((size_t)NROWS * 64 * 4);
    float* X2 = (float*)ar.get((size_t)NROWS * 64 * 4);
    float* X3 = (float*)ar.get((size_t)NROWS * 128 * 4);
    u16* IDX = (u16*)ar.get((size_t)NROWS * KNN * 2);
    float* SQ = (float*)ar.get((size_t)NROWS * 4);
    float* SUMS = (float*)ar.get(512 * 4);
    float* BNP = (float*)ar.get(512 * 4);
    float* G0T = (float*)ar.get(448 * 8 * 4);
    float* ABUF = (float*)ar.get(256 * 8 * 4);
    float* SCR = (float*)ar.get((size_t)NPTS * NPTS * 4);   // DIST / UVb / W-transposes alias
    if (!ar.ok) {
        diag_kernel<<<1, 64, 0, stream>>>(out, 3000.f + (float)(ws_size >> 20));
        return;
    }

    dim3 blk(256);
    run_stage<3, 64>(x, X1, cw[0], cb[0], bg[0], bb[0], SCR, IDX, SQ, SUMS, BNP, stream);
    run_stage<64, 64>(X1, X2, cw[1], cb[1], bg[1], bb[1], SCR, IDX, SQ, SUMS, BNP, stream);
    run_stage<64, 128>(X2, X3, cw[2], cb[2], bg[2], bb[2], SCR, IDX, SQ, SUMS, BNP, stream);
    run_stage4(X3, cw[3], cb[3], bg[3], bb[3], SCR, IDX, SQ, SUMS, BNP, G0T, stream);

    gmax23_kernel<<<dim3(BATCH, NPTS / 256), blk, 0, stream>>>(X2, X3, G0T);

    float* W1T = SCR;                            // head reuses SCR (UV dead now)
    float* W2T = W1T + 448 * 256;
    float* W3T = W2T + 256 * 128;
    transpose_kernel<<<(256 * 448 + 255) / 256, blk, 0, stream>>>(fc1_w, W1T, 256, 448);
    transpose_kernel<<<(128 * 256 + 255) / 256, blk, 0, stream>>>(fc2_w, W2T, 128, 256);
    transpose_kernel<<<(16 * 128 + 255) / 256, blk, 0, stream>>>(fc3_w, W3T, 16, 128);
    fc1_kernel<<<4, 64, 0, stream>>>(G0T, W1T, fc1_b, bnf1_g, bnf1_b, ABUF);
    tail_kernel<<<1, 256, 0, stream>>>(ABUF, W2T, fc2_b, bnf2_g, bnf2_b,
                                       W3T, fc3_b, bnf3_g, bnf3_b, fc4_w, fc4_b, out);
}

// Round 8
// 2050.363 us; speedup vs baseline: 3.5172x; 3.5172x over previous
//
#include <hip/hip_runtime.h>
#include <cfloat>

constexpr int BATCH = 8, NPTS = 2048, KNN = 20;
constexpr int NROWS = BATCH * NPTS;
constexpr float EPSV = 1e-5f;
constexpr int QCAP = 512;
constexpr int SB = 64;                           // statsb blocks per dispatch

using u16 = unsigned short;
using u64 = unsigned long long;

// ---------------------------------------------------------------- diag / fill
__global__ void diag_kernel(float* out, float v) {
    if (threadIdx.x < 8) out[threadIdx.x] = v;
}

__global__ __launch_bounds__(256) void fill_zero_kernel(float* __restrict__ p, int n) {
    int i = blockIdx.x * 256 + threadIdx.x;
    if (i < n) p[i] = 0.f;
}

// ---------------------------------------------------------------- sqnorm over all rows
template<int C>
__global__ __launch_bounds__(256) void sqnorm_kernel(const float* __restrict__ X,
                                                     float* __restrict__ sq) {
    int r = blockIdx.x * 256 + threadIdx.x;     // grid = NROWS/256
    const float* x = X + (size_t)r * C;
    float s = 0.f;
#pragma unroll
    for (int c = 0; c < C; ++c) { float v = x[c]; s = fmaf(v, v, s); }
    sq[r] = s;
}

// ---------------------------------------------------------------- dist GEMM: D[i][j] = x_i · x_j (batch b), 64x64 tile, 4x4/lane
template<int C>
__global__ __launch_bounds__(256) void dist_gemm_kernel(const float* __restrict__ X,
                                                        float* __restrict__ D, int b) {
    constexpr int KC = (C < 32) ? C : 32;
    __shared__ __align__(16) float As[KC][68];
    __shared__ __align__(16) float Bs[KC][68];
    int i0 = blockIdx.y * 64, j0 = blockIdx.x * 64;
    const float* Xb = X + (size_t)b * NPTS * C;
    int tx = threadIdx.x & 15, ty = threadIdx.x >> 4;
    float acc[4][4] = {};
    for (int c0 = 0; c0 < C; c0 += KC) {
        for (int t = threadIdx.x; t < 64 * KC; t += 256) {
            int i = t / KC, c = t % KC;
            As[c][i] = Xb[(size_t)(i0 + i) * C + c0 + c];
            Bs[c][i] = Xb[(size_t)(j0 + i) * C + c0 + c];
        }
        __syncthreads();
#pragma unroll
        for (int c = 0; c < KC; ++c) {
            const float4 av = *(const float4*)&As[c][ty * 4];
            const float4 bv = *(const float4*)&Bs[c][tx * 4];
            float ar[4] = {av.x, av.y, av.z, av.w};
            float br[4] = {bv.x, bv.y, bv.z, bv.w};
#pragma unroll
            for (int r = 0; r < 4; ++r)
#pragma unroll
                for (int q = 0; q < 4; ++q) acc[r][q] = fmaf(ar[r], br[q], acc[r][q]);
        }
        __syncthreads();
    }
#pragma unroll
    for (int r = 0; r < 4; ++r) {
        float4 o4 = make_float4(acc[r][0], acc[r][1], acc[r][2], acc[r][3]);
        *(float4*)&D[(size_t)(i0 + ty * 4 + r) * NPTS + j0 + tx * 4] = o4;
    }
}

// ---------------------------------------------------------------- wave-64 bitonic sorts (descending, lane 0 = max)
__device__ __forceinline__ float bitonic64_desc_f32(float key, int lane) {
#pragma unroll
    for (int k = 2; k <= 64; k <<= 1) {
#pragma unroll
        for (int j = k >> 1; j > 0; j >>= 1) {
            float p = __shfl_xor(key, j);
            bool keepMax = (((lane & j) == 0) == ((lane & k) == 0));
            key = ((key > p) == keepMax) ? key : p;
        }
    }
    return key;
}

__device__ __forceinline__ u64 bitonic64_desc_u64(u64 key, int lane) {
#pragma unroll
    for (int k = 2; k <= 64; k <<= 1) {
#pragma unroll
        for (int j = k >> 1; j > 0; j >>= 1) {
            u64 p = __shfl_xor(key, j);
            bool keepMax = (((lane & j) == 0) == ((lane & k) == 0));
            key = ((key > p) == keepMax) ? key : p;
        }
    }
    return key;
}

// ---------------------------------------------------------------- top-k: threshold from 20th lane-max, then exact bitonic select
__global__ __launch_bounds__(256) void topk_kernel(const float* __restrict__ D,
                                                   const float* __restrict__ sq,
                                                   u16* __restrict__ idx_out, int b) {
    __shared__ u64 qkey[4][QCAP];
    __shared__ int qn[4];
    int w = threadIdx.x >> 6, lane = threadIdx.x & 63;
    int i = blockIdx.x * 4 + w;
    const float* Drow = D + (size_t)i * NPTS;
    const float* sqb = sq + b * NPTS;
    float sqi = sqb[i];
    if (lane == 0) qn[w] = 0;

    float vals[32];
    float mx = -FLT_MAX;
#pragma unroll
    for (int t = 0; t < 8; ++t) {
        int j = t * 256 + lane * 4;
        float4 v4 = *(const float4*)&Drow[j];
        float4 s4 = *(const float4*)&sqb[j];
        float a0 = (2.f * v4.x - sqi - s4.x) + 0.f;
        float a1 = (2.f * v4.y - sqi - s4.y) + 0.f;
        float a2 = (2.f * v4.z - sqi - s4.z) + 0.f;
        float a3 = (2.f * v4.w - sqi - s4.w) + 0.f;
        vals[t * 4 + 0] = a0; vals[t * 4 + 1] = a1;
        vals[t * 4 + 2] = a2; vals[t * 4 + 3] = a3;
        mx = fmaxf(mx, fmaxf(fmaxf(a0, a1), fmaxf(a2, a3)));
    }

    float sm = bitonic64_desc_f32(mx, lane);
    float T0 = __shfl(sm, 19);

#pragma unroll
    for (int t = 0; t < 32; ++t) {
        float v = vals[t];
        if (v >= T0) {
            unsigned j = (unsigned)((t >> 2) * 256 + lane * 4 + (t & 3));
            unsigned bu = __float_as_uint(v);
            unsigned u = (bu & 0x80000000u) ? ~bu : (bu | 0x80000000u);
            u64 key = ((u64)u << 32) | (u64)(0xFFFFFFFFu - j);
            int slot = atomicAdd(&qn[w], 1);
            if (slot < QCAP) qkey[w][slot] = key;
        }
    }
    int C = qn[w];
    if (C > QCAP) C = QCAP;

    u64 key = (lane < C) ? qkey[w][lane] : 0ull;
    key = bitonic64_desc_u64(key, lane);
    int base = 64;
    while (base < C) {
        if (lane >= 20) {
            int src = base + (lane - 20);
            key = (src < C) ? qkey[w][src] : 0ull;
        }
        key = bitonic64_desc_u64(key, lane);
        base += 44;
    }
    if (lane < 20) {
        unsigned j = 0xFFFFFFFFu - (unsigned)(key & 0xFFFFFFFFull);
        idx_out[(size_t)(b * NPTS + i) * KNN + lane] = (u16)j;
    }
}

// ---------------------------------------------------------------- per-batch UV GEMM: UVb[r][0:O]=W1·x_r, [O:2O]=(W2-W1)·x_r + bias
template<int C, int O>
__global__ __launch_bounds__(256) void uvb_gemm_kernel(const float* __restrict__ X,
                                                       const float* __restrict__ W,
                                                       const float* __restrict__ bias,
                                                       float* __restrict__ UVb, int b) {
    constexpr int KC = (C < 32) ? C : 32;
    __shared__ __align__(16) float As[KC][68];
    __shared__ __align__(16) float Bs[KC][68];
    int r0 = blockIdx.y * 64, n0 = blockIdx.x * 64;
    int tx = threadIdx.x & 15, ty = threadIdx.x >> 4;
    float acc[4][4] = {};
    for (int c0 = 0; c0 < C; c0 += KC) {
        for (int t = threadIdx.x; t < 64 * KC; t += 256) {
            int i = t / KC, c = t % KC;
            As[c][i] = X[(size_t)(b * NPTS + r0 + i) * C + c0 + c];
            int n = n0 + i;
            float wv;
            if (n < O) wv = W[(size_t)n * (2 * C) + c0 + c];
            else {
                int o = n - O;
                wv = W[(size_t)o * (2 * C) + C + c0 + c] - W[(size_t)o * (2 * C) + c0 + c];
            }
            Bs[c][i] = wv;
        }
        __syncthreads();
#pragma unroll
        for (int c = 0; c < KC; ++c) {
            const float4 av = *(const float4*)&As[c][ty * 4];
            const float4 bv = *(const float4*)&Bs[c][tx * 4];
            float ar[4] = {av.x, av.y, av.z, av.w};
            float br[4] = {bv.x, bv.y, bv.z, bv.w};
#pragma unroll
            for (int r = 0; r < 4; ++r)
#pragma unroll
                for (int q = 0; q < 4; ++q) acc[r][q] = fmaf(ar[r], br[q], acc[r][q]);
        }
        __syncthreads();
    }
    float badd[4] = {0.f, 0.f, 0.f, 0.f};
    if (n0 >= O) {
#pragma unroll
        for (int q = 0; q < 4; ++q) badd[q] = bias[n0 - O + tx * 4 + q];
    }
#pragma unroll
    for (int r = 0; r < 4; ++r) {
        float4 o4 = make_float4(acc[r][0] + badd[0], acc[r][1] + badd[1],
                                acc[r][2] + badd[2], acc[r][3] + badd[3]);
        *(float4*)&UVb[(size_t)(r0 + ty * 4 + r) * (2 * O) + n0 + tx * 4] = o4;
    }
}

// ---------------------------------------------------------------- stats: block-partial sum/sumsq of h (NO atomics)
// PART[(b*SB + blk) * 2*O + {o, O+o}] ; bnp sums the BATCH*SB partials
template<int O>
__global__ __launch_bounds__(256) void statsb_kernel(const float* __restrict__ UVb,
                                                     const u16* __restrict__ idx,
                                                     float* __restrict__ PART, int b) {
    constexpr int TPR = O / 4;                  // threads per row
    constexpr int RPAR = 256 / TPR;             // rows in parallel
    constexpr int RPB = NPTS / SB;              // rows per block (32)
    __shared__ float sh[256 * 8];
    int otid = threadIdx.x % TPR;
    int o = otid * 4;
    int rsub = threadIdx.x / TPR;
    int rbase = blockIdx.x * RPB;
    float s0 = 0, s1 = 0, s2 = 0, s3 = 0, q0 = 0, q1 = 0, q2 = 0, q3 = 0;
    for (int r = rbase + rsub; r < rbase + RPB; r += RPAR) {
        const float4 v4 = *(const float4*)&UVb[(size_t)r * (2 * O) + O + o];
        const u16* ix = idx + (size_t)(b * NPTS + r) * KNN;
#pragma unroll
        for (int k = 0; k < KNN; ++k) {
            int j = (int)ix[k] & (NPTS - 1);
            const float4 u4 = *(const float4*)&UVb[(size_t)j * (2 * O) + o];
            float h0 = u4.x + v4.x, h1 = u4.y + v4.y, h2 = u4.z + v4.z, h3 = u4.w + v4.w;
            s0 += h0; q0 = fmaf(h0, h0, q0);
            s1 += h1; q1 = fmaf(h1, h1, q1);
            s2 += h2; q2 = fmaf(h2, h2, q2);
            s3 += h3; q3 = fmaf(h3, h3, q3);
        }
    }
    float* my = &sh[threadIdx.x * 8];
    my[0] = s0; my[1] = s1; my[2] = s2; my[3] = s3;
    my[4] = q0; my[5] = q1; my[6] = q2; my[7] = q3;
    __syncthreads();
    if (threadIdx.x < TPR) {
        float a[8];
#pragma unroll
        for (int c = 0; c < 8; ++c) a[c] = sh[threadIdx.x * 8 + c];
        for (int g = 1; g < RPAR; ++g) {
            const float* p = &sh[(g * TPR + threadIdx.x) * 8];
#pragma unroll
            for (int c = 0; c < 8; ++c) a[c] += p[c];
        }
        float* dst = &PART[((size_t)b * SB + blockIdx.x) * (2 * O)];
#pragma unroll
        for (int c = 0; c < 4; ++c) { dst[o + c] = a[c]; dst[O + o + c] = a[4 + c]; }
    }
}

template<int O>
__global__ void bnp_kernel(const float* __restrict__ PART, const float* __restrict__ g,
                           const float* __restrict__ beta, float* __restrict__ bnp) {
    int o = threadIdx.x;
    float s = 0.f, ss = 0.f;
    for (int p = 0; p < BATCH * SB; ++p) {
        s += PART[(size_t)p * (2 * O) + o];
        ss += PART[(size_t)p * (2 * O) + O + o];
    }
    const float cnt = (float)NROWS * (float)KNN;
    float m = s / cnt;
    float var = ss / cnt - m * m;
    float sc = g[o] / sqrtf(var + EPSV);
    bnp[o] = sc;
    bnp[O + o] = beta[o] - m * sc;
}

// ---------------------------------------------------------------- apply: gather max/min + BN + relu -> Xn (stages 1..3, float4)
template<int O>
__global__ __launch_bounds__(256) void applyb_kernel(const float* __restrict__ UVb,
                                                     const u16* __restrict__ idx,
                                                     const float* __restrict__ bnp,
                                                     float* __restrict__ Xn, int b) {
    constexpr int TPR = O / 4;
    int e = blockIdx.x * 256 + threadIdx.x;     // grid = NPTS*TPR/256
    int o = (e % TPR) * 4, r = e / TPR;
    const float4 v4 = *(const float4*)&UVb[(size_t)r * (2 * O) + O + o];
    const u16* ix = idx + (size_t)(b * NPTS + r) * KNN;
    float mx0 = -FLT_MAX, mx1 = -FLT_MAX, mx2 = -FLT_MAX, mx3 = -FLT_MAX;
    float mn0 = FLT_MAX, mn1 = FLT_MAX, mn2 = FLT_MAX, mn3 = FLT_MAX;
#pragma unroll
    for (int k = 0; k < KNN; ++k) {
        int j = (int)ix[k] & (NPTS - 1);
        const float4 u4 = *(const float4*)&UVb[(size_t)j * (2 * O) + o];
        float h0 = u4.x + v4.x, h1 = u4.y + v4.y, h2 = u4.z + v4.z, h3 = u4.w + v4.w;
        mx0 = fmaxf(mx0, h0); mn0 = fminf(mn0, h0);
        mx1 = fmaxf(mx1, h1); mn1 = fminf(mn1, h1);
        mx2 = fmaxf(mx2, h2); mn2 = fminf(mn2, h2);
        mx3 = fmaxf(mx3, h3); mn3 = fminf(mn3, h3);
    }
    float4 out;
    { float sc = bnp[o + 0], t = bnp[O + o + 0]; out.x = fmaxf(fmaf(sc, (sc >= 0.f) ? mx0 : mn0, t), 0.f); }
    { float sc = bnp[o + 1], t = bnp[O + o + 1]; out.y = fmaxf(fmaf(sc, (sc >= 0.f) ? mx1 : mn1, t), 0.f); }
    { float sc = bnp[o + 2], t = bnp[O + o + 2]; out.z = fmaxf(fmaf(sc, (sc >= 0.f) ? mx2 : mn2, t), 0.f); }
    { float sc = bnp[o + 3], t = bnp[O + o + 3]; out.w = fmaxf(fmaf(sc, (sc >= 0.f) ? mx3 : mn3, t), 0.f); }
    *(float4*)&Xn[(size_t)(b * NPTS + r) * O + o] = out;
}

// ---------------------------------------------------------------- stage-4 apply: running point-max in registers, LDS reduce, few atomics
__global__ __launch_bounds__(256) void applyb4_kernel(const float* __restrict__ UVb,
                                                      const u16* __restrict__ idx,
                                                      const float* __restrict__ bnp,
                                                      float* __restrict__ g0T, int b) {
    constexpr int O = 256;
    constexpr int TPR = O / 4;                  // 64
    constexpr int RPAR = 256 / TPR;             // 4
    constexpr int AB = 32;                      // grid
    constexpr int RPB = NPTS / AB;              // 64 rows/block
    __shared__ float sh[256 * 4];
    int otid = threadIdx.x & (TPR - 1);
    int o = otid * 4;
    int rsub = threadIdx.x >> 6;
    int rbase = blockIdx.x * RPB;
    float sc0 = bnp[o + 0], t0 = bnp[O + o + 0];
    float sc1 = bnp[o + 1], t1 = bnp[O + o + 1];
    float sc2 = bnp[o + 2], t2 = bnp[O + o + 2];
    float sc3 = bnp[o + 3], t3 = bnp[O + o + 3];
    float ym0 = 0.f, ym1 = 0.f, ym2 = 0.f, ym3 = 0.f;   // relu >= 0
    for (int r = rbase + rsub; r < rbase + RPB; r += RPAR) {
        const float4 v4 = *(const float4*)&UVb[(size_t)r * (2 * O) + O + o];
        const u16* ix = idx + (size_t)(b * NPTS + r) * KNN;
        float mx0 = -FLT_MAX, mx1 = -FLT_MAX, mx2 = -FLT_MAX, mx3 = -FLT_MAX;
        float mn0 = FLT_MAX, mn1 = FLT_MAX, mn2 = FLT_MAX, mn3 = FLT_MAX;
#pragma unroll
        for (int k = 0; k < KNN; ++k) {
            int j = (int)ix[k] & (NPTS - 1);
            const float4 u4 = *(const float4*)&UVb[(size_t)j * (2 * O) + o];
            float h0 = u4.x + v4.x, h1 = u4.y + v4.y, h2 = u4.z + v4.z, h3 = u4.w + v4.w;
            mx0 = fmaxf(mx0, h0); mn0 = fminf(mn0, h0);
            mx1 = fmaxf(mx1, h1); mn1 = fminf(mn1, h1);
            mx2 = fmaxf(mx2, h2); mn2 = fminf(mn2, h2);
            mx3 = fmaxf(mx3, h3); mn3 = fminf(mn3, h3);
        }
        ym0 = fmaxf(ym0, fmaf(sc0, (sc0 >= 0.f) ? mx0 : mn0, t0));
        ym1 = fmaxf(ym1, fmaf(sc1, (sc1 >= 0.f) ? mx1 : mn1, t1));
        ym2 = fmaxf(ym2, fmaf(sc2, (sc2 >= 0.f) ? mx2 : mn2, t2));
        ym3 = fmaxf(ym3, fmaf(sc3, (sc3 >= 0.f) ? mx3 : mn3, t3));
    }
    float* my = &sh[threadIdx.x * 4];
    my[0] = ym0; my[1] = ym1; my[2] = ym2; my[3] = ym3;
    __syncthreads();
    if (threadIdx.x < TPR) {
        float a0 = ym0, a1 = ym1, a2 = ym2, a3 = ym3;   // rsub==0 partial is ours
        for (int g = 1; g < RPAR; ++g) {
            const float* p = &sh[(g * TPR + threadIdx.x) * 4];
            a0 = fmaxf(a0, p[0]); a1 = fmaxf(a1, p[1]);
            a2 = fmaxf(a2, p[2]); a3 = fmaxf(a3, p[3]);
        }
        a0 = fmaxf(a0, 0.f); a1 = fmaxf(a1, 0.f);
        a2 = fmaxf(a2, 0.f); a3 = fmaxf(a3, 0.f);
        atomicMax((int*)&g0T[(o + 0) * 8 + b], __float_as_int(a0));
        atomicMax((int*)&g0T[(o + 1) * 8 + b], __float_as_int(a1));
        atomicMax((int*)&g0T[(o + 2) * 8 + b], __float_as_int(a2));
        atomicMax((int*)&g0T[(o + 3) * 8 + b], __float_as_int(a3));
    }
}

// ---------------------------------------------------------------- point-max of X2/X3 into G0T channels [256,448)
__global__ __launch_bounds__(256) void gmax23_kernel(const float* __restrict__ X2,
                                                     const float* __restrict__ X3,
                                                     float* __restrict__ g0T) {
    int b = blockIdx.x;
    int n0 = blockIdx.y * 256;
    int o = threadIdx.x;
    if (o >= 192) return;
    const float* src; int col, stride, ch;
    if (o < 128) { src = X3; col = o;       stride = 128; ch = 256 + o; }
    else         { src = X2; col = o - 128; stride = 64;  ch = 384 + (o - 128); }
    float m = 0.f;
#pragma unroll 8
    for (int n = n0; n < n0 + 256; ++n)
        m = fmaxf(m, src[((size_t)(b * NPTS + n)) * stride + col]);
    atomicMax((int*)&g0T[ch * 8 + b], __float_as_int(m));
}

// ---------------------------------------------------------------- fc weight transpose ([o][c] -> [c][o])
__global__ __launch_bounds__(256) void transpose_kernel(const float* __restrict__ w,
                                                        float* __restrict__ wT, int O, int Cc) {
    int e = blockIdx.x * 256 + threadIdx.x;
    if (e >= O * Cc) return;
    int o = e / Cc, c = e - o * Cc;
    wT[c * O + o] = w[e];
}

// ---------------------------------------------------------------- fc1 + bnf1 + relu (batch stats in-register)
__global__ __launch_bounds__(64) void fc1_kernel(const float* __restrict__ g0T,
                                                 const float* __restrict__ w1T,
                                                 const float* __restrict__ b1,
                                                 const float* __restrict__ bng,
                                                 const float* __restrict__ bnb,
                                                 float* __restrict__ A) {
    int o = blockIdx.x * 64 + threadIdx.x;
    float acc[8] = {};
    for (int c = 0; c < 448; ++c) {
        float wv = w1T[c * 256 + o];
        const float4 h0 = *(const float4*)&g0T[c * 8];
        const float4 h1 = *(const float4*)&g0T[c * 8 + 4];
        acc[0] = fmaf(wv, h0.x, acc[0]); acc[1] = fmaf(wv, h0.y, acc[1]);
        acc[2] = fmaf(wv, h0.z, acc[2]); acc[3] = fmaf(wv, h0.w, acc[3]);
        acc[4] = fmaf(wv, h1.x, acc[4]); acc[5] = fmaf(wv, h1.y, acc[5]);
        acc[6] = fmaf(wv, h1.z, acc[6]); acc[7] = fmaf(wv, h1.w, acc[7]);
    }
    float bb = b1[o];
    float h[8], m = 0.f;
#pragma unroll
    for (int b = 0; b < 8; ++b) { h[b] = acc[b] + bb; m += h[b]; }
    m *= 0.125f;
    float var = 0.f;
#pragma unroll
    for (int b = 0; b < 8; ++b) { float d = h[b] - m; var = fmaf(d, d, var); }
    var *= 0.125f;
    float sc = bng[o] / sqrtf(var + EPSV);
    float t = bnb[o] - m * sc;
#pragma unroll
    for (int b = 0; b < 8; ++b) A[o * 8 + b] = fmaxf(fmaf(sc, h[b], t), 0.f);
}

// ---------------------------------------------------------------- fc2..fc4 tail (one block)
__global__ __launch_bounds__(256) void tail_kernel(const float* __restrict__ A,
                                                   const float* __restrict__ w2T, const float* __restrict__ b2,
                                                   const float* __restrict__ g2, const float* __restrict__ be2,
                                                   const float* __restrict__ w3T, const float* __restrict__ b3,
                                                   const float* __restrict__ g3, const float* __restrict__ be3,
                                                   const float* __restrict__ w4, const float* __restrict__ b4,
                                                   float* __restrict__ out) {
    __shared__ __align__(16) float B2[128 * 8];
    __shared__ __align__(16) float C3[16 * 8];
    int tid = threadIdx.x;
    if (tid < 128) {
        int o = tid;
        float acc[8] = {};
        for (int c = 0; c < 256; ++c) {
            float wv = w2T[c * 128 + o];
            const float4 a0 = *(const float4*)&A[c * 8];
            const float4 a1 = *(const float4*)&A[c * 8 + 4];
            acc[0] = fmaf(wv, a0.x, acc[0]); acc[1] = fmaf(wv, a0.y, acc[1]);
            acc[2] = fmaf(wv, a0.z, acc[2]); acc[3] = fmaf(wv, a0.w, acc[3]);
            acc[4] = fmaf(wv, a1.x, acc[4]); acc[5] = fmaf(wv, a1.y, acc[5]);
            acc[6] = fmaf(wv, a1.z, acc[6]); acc[7] = fmaf(wv, a1.w, acc[7]);
        }
        float bb = b2[o];
        float h[8], m = 0.f;
#pragma unroll
        for (int b = 0; b < 8; ++b) { h[b] = acc[b] + bb; m += h[b]; }
        m *= 0.125f;
        float var = 0.f;
#pragma unroll
        for (int b = 0; b < 8; ++b) { float d = h[b] - m; var = fmaf(d, d, var); }
        var *= 0.125f;
        float sc = g2[o] / sqrtf(var + EPSV);
        float t = be2[o] - m * sc;
#pragma unroll
        for (int b = 0; b < 8; ++b) B2[o * 8 + b] = fmaxf(fmaf(sc, h[b], t), 0.f);
    }
    __syncthreads();
    if (tid < 16) {
        int o = tid;
        float acc[8] = {};
        for (int c = 0; c < 128; ++c) {
            float wv = w3T[c * 16 + o];
            const float4 a0 = *(const float4*)&B2[c * 8];
            const float4 a1 = *(const float4*)&B2[c * 8 + 4];
            acc[0] = fmaf(wv, a0.x, acc[0]); acc[1] = fmaf(wv, a0.y, acc[1]);
            acc[2] = fmaf(wv, a0.z, acc[2]); acc[3] = fmaf(wv, a0.w, acc[3]);
            acc[4] = fmaf(wv, a1.x, acc[4]); acc[5] = fmaf(wv, a1.y, acc[5]);
            acc[6] = fmaf(wv, a1.z, acc[6]); acc[7] = fmaf(wv, a1.w, acc[7]);
        }
        float bb = b3[o];
        float h[8], m = 0.f;
#pragma unroll
        for (int b = 0; b < 8; ++b) { h[b] = acc[b] + bb; m += h[b]; }
        m *= 0.125f;
        float var = 0.f;
#pragma unroll
        for (int b = 0; b < 8; ++b) { float d = h[b] - m; var = fmaf(d, d, var); }
        var *= 0.125f;
        float sc = g3[o] / sqrtf(var + EPSV);
        float t = be3[o] - m * sc;
#pragma unroll
        for (int b = 0; b < 8; ++b) C3[o * 8 + b] = fmaxf(fmaf(sc, h[b], t), 0.f);
    }
    __syncthreads();
    if (tid < 8) {
        int b = tid;
        float acc = b4[0];
#pragma unroll
        for (int c = 0; c < 16; ++c) acc = fmaf(w4[c], C3[c * 8 + b], acc);
        out[b] = acc;
    }
}

// ================================================================ host side
struct Arena {
    char* base; size_t off, cap; bool ok;
    Arena(void* b, size_t c) : base((char*)b), off(0), cap(c), ok(true) {}
    void* get(size_t bytes) {
        char* p = base + off;
        off += (bytes + 255) & ~(size_t)255;
        if (off > cap) ok = false;
        return p;
    }
};

// one EdgeConv stage, output stored to Xout (stages 1..3)
template<int C, int O>
static void run_stage(const float* Xin, float* Xout, const float* W, const float* bias,
                      const float* g, const float* be, float* SCR, float* UVA,
                      u16* IDX, float* SQ, float* PART, float* BNP, hipStream_t s) {
    dim3 blk(256);
    sqnorm_kernel<C><<<NROWS / 256, blk, 0, s>>>(Xin, SQ);
    for (int b = 0; b < BATCH; ++b) {
        dist_gemm_kernel<C><<<dim3(NPTS / 64, NPTS / 64), blk, 0, s>>>(Xin, SCR, b);
        topk_kernel<<<NPTS / 4, blk, 0, s>>>(SCR, SQ, IDX, b);
    }
    for (int b = 0; b < BATCH; ++b) {
        float* UVb = UVA + (size_t)b * NPTS * 2 * O;
        uvb_gemm_kernel<C, O><<<dim3(2 * O / 64, NPTS / 64), blk, 0, s>>>(Xin, W, bias, UVb, b);
        statsb_kernel<O><<<SB, blk, 0, s>>>(UVb, IDX, PART, b);
    }
    bnp_kernel<O><<<1, O, 0, s>>>(PART, g, be, BNP);
    for (int b = 0; b < BATCH; ++b) {
        float* UVb = UVA + (size_t)b * NPTS * 2 * O;
        applyb_kernel<O><<<NPTS * (O / 4) / 256, blk, 0, s>>>(UVb, IDX, BNP, Xout, b);
    }
}

// stage 4: point-max fused into G0T (no X4 buffer)
static void run_stage4(const float* Xin, const float* W, const float* bias,
                       const float* g, const float* be, float* SCR, float* UVA,
                       u16* IDX, float* SQ, float* PART, float* BNP, float* G0T,
                       hipStream_t s) {
    constexpr int C = 128;
    dim3 blk(256);
    sqnorm_kernel<C><<<NROWS / 256, blk, 0, s>>>(Xin, SQ);
    for (int b = 0; b < BATCH; ++b) {
        dist_gemm_kernel<C><<<dim3(NPTS / 64, NPTS / 64), blk, 0, s>>>(Xin, SCR, b);
        topk_kernel<<<NPTS / 4, blk, 0, s>>>(SCR, SQ, IDX, b);
    }
    for (int b = 0; b < BATCH; ++b) {
        float* UVb = UVA + (size_t)b * NPTS * 512;
        uvb_gemm_kernel<C, 256><<<dim3(8, NPTS / 64), blk, 0, s>>>(Xin, W, bias, UVb, b);
        statsb_kernel<256><<<SB, blk, 0, s>>>(UVb, IDX, PART, b);
    }
    bnp_kernel<256><<<1, 256, 0, s>>>(PART, g, be, BNP);
    fill_zero_kernel<<<14, blk, 0, s>>>(G0T, 448 * 8);
    for (int b = 0; b < BATCH; ++b) {
        float* UVb = UVA + (size_t)b * NPTS * 512;
        applyb4_kernel<<<32, blk, 0, s>>>(UVb, IDX, BNP, G0T, b);
    }
}

extern "C" void kernel_launch(void* const* d_in, const int* in_sizes, int n_in,
                              void* d_out, int out_size, void* d_ws, size_t ws_size,
                              hipStream_t stream) {
    float* out = (float*)d_out;
    if (n_in < 31) { diag_kernel<<<1, 64, 0, stream>>>(out, 9000.f); return; }

    const float* x       = (const float*)d_in[0];
    const float* cw[4]   = {(const float*)d_in[1], (const float*)d_in[5], (const float*)d_in[9],  (const float*)d_in[13]};
    const float* cb[4]   = {(const float*)d_in[2], (const float*)d_in[6], (const float*)d_in[10], (const float*)d_in[14]};
    const float* bg[4]   = {(const float*)d_in[3], (const float*)d_in[7], (const float*)d_in[11], (const float*)d_in[15]};
    const float* bb[4]   = {(const float*)d_in[4], (const float*)d_in[8], (const float*)d_in[12], (const float*)d_in[16]};
    const float* fc1_w = (const float*)d_in[17]; const float* fc1_b = (const float*)d_in[18];
    const float* bnf1_g = (const float*)d_in[19]; const float* bnf1_b = (const float*)d_in[20];
    const float* fc2_w = (const float*)d_in[21]; const float* fc2_b = (const float*)d_in[22];
    const float* bnf2_g = (const float*)d_in[23]; const float* bnf2_b = (const float*)d_in[24];
    const float* fc3_w = (const float*)d_in[25]; const float* fc3_b = (const float*)d_in[26];
    const float* bnf3_g = (const float*)d_in[27]; const float* bnf3_b = (const float*)d_in[28];
    const float* fc4_w = (const float*)d_in[29]; const float* fc4_b = (const float*)d_in[30];

    Arena ar(d_ws, ws_size);
    float* X1 = (float*)ar.get((size_t)NROWS * 64 * 4);
    float* X2 = (float*)ar.get((size_t)NROWS * 64 * 4);
    float* X3 = (float*)ar.get((size_t)NROWS * 128 * 4);
    u16* IDX = (u16*)ar.get((size_t)NROWS * KNN * 2);
    float* SQ = (float*)ar.get((size_t)NROWS * 4);
    float* PART = (float*)ar.get((size_t)BATCH * SB * 512 * 4);   // 1 MB
    float* BNP = (float*)ar.get(512 * 4);
    float* G0T = (float*)ar.get(448 * 8 * 4);
    float* ABUF = (float*)ar.get(256 * 8 * 4);
    float* SCR = (float*)ar.get((size_t)NPTS * NPTS * 4);         // DIST / W-transposes alias (16 MB)
    float* UVA = (float*)ar.get((size_t)NROWS * 512 * 4);         // UV all batches, worst O=256 (32 MB)
    if (!ar.ok) {
        diag_kernel<<<1, 64, 0, stream>>>(out, 3000.f + (float)(ws_size >> 20));
        return;
    }

    dim3 blk(256);
    run_stage<3, 64>(x, X1, cw[0], cb[0], bg[0], bb[0], SCR, UVA, IDX, SQ, PART, BNP, stream);
    run_stage<64, 64>(X1, X2, cw[1], cb[1], bg[1], bb[1], SCR, UVA, IDX, SQ, PART, BNP, stream);
    run_stage<64, 128>(X2, X3, cw[2], cb[2], bg[2], bb[2], SCR, UVA, IDX, SQ, PART, BNP, stream);
    run_stage4(X3, cw[3], cb[3], bg[3], bb[3], SCR, UVA, IDX, SQ, PART, BNP, G0T, stream);

    gmax23_kernel<<<dim3(BATCH, NPTS / 256), blk, 0, stream>>>(X2, X3, G0T);

    float* W1T = SCR;                            // head reuses SCR (DIST dead now)
    float* W2T = W1T + 448 * 256;
    float* W3T = W2T + 256 * 128;
    transpose_kernel<<<(256 * 448 + 255) / 256, blk, 0, stream>>>(fc1_w, W1T, 256, 448);
    transpose_kernel<<<(128 * 256 + 255) / 256, blk, 0, stream>>>(fc2_w, W2T, 128, 256);
    transpose_kernel<<<(16 * 128 + 255) / 256, blk, 0, stream>>>(fc3_w, W3T, 16, 128);
    fc1_kernel<<<4, 64, 0, stream>>>(G0T, W1T, fc1_b, bnf1_g, bnf1_b, ABUF);
    tail_kernel<<<1, 256, 0, stream>>>(ABUF, W2T, fc2_b, bnf2_g, bnf2_b,
                                       W3T, fc3_b, bnf3_g, bnf3_b, fc4_w, fc4_b, out);
}

// Round 9
// 1116.428 us; speedup vs baseline: 6.4595x; 1.8365x over previous
//
#include <hip/hip_runtime.h>
#include <cfloat>

constexpr int BATCH = 8, NPTS = 2048, KNN = 20;
constexpr int NROWS = BATCH * NPTS;
constexpr float EPSV = 1e-5f;
constexpr int QCAP = 512;
constexpr int SB = 64;                           // statsb blocks per batch

using u16 = unsigned short;
using u64 = unsigned long long;

// ---------------------------------------------------------------- diag / fill
__global__ void diag_kernel(float* out, float v) {
    if (threadIdx.x < 8) out[threadIdx.x] = v;
}

__global__ __launch_bounds__(256) void fill_zero_kernel(float* __restrict__ p, int n) {
    int i = blockIdx.x * 256 + threadIdx.x;
    if (i < n) p[i] = 0.f;
}

// ---------------------------------------------------------------- sqnorm over all rows
template<int C>
__global__ __launch_bounds__(256) void sqnorm_kernel(const float* __restrict__ X,
                                                     float* __restrict__ sq) {
    int r = blockIdx.x * 256 + threadIdx.x;     // grid = NROWS/256
    const float* x = X + (size_t)r * C;
    float s = 0.f;
#pragma unroll
    for (int c = 0; c < C; ++c) { float v = x[c]; s = fmaf(v, v, s); }
    sq[r] = s;
}

// ---------------------------------------------------------------- dist GEMM: D[z][i][j] = x_i · x_j (batch b0+z)
template<int C>
__global__ __launch_bounds__(256) void dist_gemm_kernel(const float* __restrict__ X,
                                                        float* __restrict__ D, int b0) {
    constexpr int KC = (C < 32) ? C : 32;
    __shared__ __align__(16) float As[KC][68];
    __shared__ __align__(16) float Bs[KC][68];
    int b = b0 + blockIdx.z;
    int i0 = blockIdx.y * 64, j0 = blockIdx.x * 64;
    const float* Xb = X + (size_t)b * NPTS * C;
    int tx = threadIdx.x & 15, ty = threadIdx.x >> 4;
    float acc[4][4] = {};
    for (int c0 = 0; c0 < C; c0 += KC) {
        for (int t = threadIdx.x; t < 64 * KC; t += 256) {
            int i = t / KC, c = t % KC;
            As[c][i] = Xb[(size_t)(i0 + i) * C + c0 + c];
            Bs[c][i] = Xb[(size_t)(j0 + i) * C + c0 + c];
        }
        __syncthreads();
#pragma unroll
        for (int c = 0; c < KC; ++c) {
            const float4 av = *(const float4*)&As[c][ty * 4];
            const float4 bv = *(const float4*)&Bs[c][tx * 4];
            float ar[4] = {av.x, av.y, av.z, av.w};
            float br[4] = {bv.x, bv.y, bv.z, bv.w};
#pragma unroll
            for (int r = 0; r < 4; ++r)
#pragma unroll
                for (int q = 0; q < 4; ++q) acc[r][q] = fmaf(ar[r], br[q], acc[r][q]);
        }
        __syncthreads();
    }
    float* Dz = D + (size_t)blockIdx.z * NPTS * NPTS;
#pragma unroll
    for (int r = 0; r < 4; ++r) {
        float4 o4 = make_float4(acc[r][0], acc[r][1], acc[r][2], acc[r][3]);
        *(float4*)&Dz[(size_t)(i0 + ty * 4 + r) * NPTS + j0 + tx * 4] = o4;
    }
}

// ---------------------------------------------------------------- wave-64 bitonic sorts (descending, lane 0 = max)
__device__ __forceinline__ float bitonic64_desc_f32(float key, int lane) {
#pragma unroll
    for (int k = 2; k <= 64; k <<= 1) {
#pragma unroll
        for (int j = k >> 1; j > 0; j >>= 1) {
            float p = __shfl_xor(key, j);
            bool keepMax = (((lane & j) == 0) == ((lane & k) == 0));
            key = ((key > p) == keepMax) ? key : p;
        }
    }
    return key;
}

__device__ __forceinline__ u64 bitonic64_desc_u64(u64 key, int lane) {
#pragma unroll
    for (int k = 2; k <= 64; k <<= 1) {
#pragma unroll
        for (int j = k >> 1; j > 0; j >>= 1) {
            u64 p = __shfl_xor(key, j);
            bool keepMax = (((lane & j) == 0) == ((lane & k) == 0));
            key = ((key > p) == keepMax) ? key : p;
        }
    }
    return key;
}

// ---------------------------------------------------------------- top-k: threshold from 20th lane-max, then exact bitonic select
__global__ __launch_bounds__(256) void topk_kernel(const float* __restrict__ D,
                                                   const float* __restrict__ sq,
                                                   u16* __restrict__ idx_out, int b0) {
    __shared__ u64 qkey[4][QCAP];
    __shared__ int qn[4];
    int b = b0 + blockIdx.z;
    int w = threadIdx.x >> 6, lane = threadIdx.x & 63;
    int i = blockIdx.x * 4 + w;
    const float* Drow = D + ((size_t)blockIdx.z * NPTS + i) * NPTS;
    const float* sqb = sq + b * NPTS;
    float sqi = sqb[i];
    if (lane == 0) qn[w] = 0;

    float vals[32];
    float mx = -FLT_MAX;
#pragma unroll
    for (int t = 0; t < 8; ++t) {
        int j = t * 256 + lane * 4;
        float4 v4 = *(const float4*)&Drow[j];
        float4 s4 = *(const float4*)&sqb[j];
        float a0 = (2.f * v4.x - sqi - s4.x) + 0.f;
        float a1 = (2.f * v4.y - sqi - s4.y) + 0.f;
        float a2 = (2.f * v4.z - sqi - s4.z) + 0.f;
        float a3 = (2.f * v4.w - sqi - s4.w) + 0.f;
        vals[t * 4 + 0] = a0; vals[t * 4 + 1] = a1;
        vals[t * 4 + 2] = a2; vals[t * 4 + 3] = a3;
        mx = fmaxf(mx, fmaxf(fmaxf(a0, a1), fmaxf(a2, a3)));
    }

    float sm = bitonic64_desc_f32(mx, lane);
    float T0 = __shfl(sm, 19);

#pragma unroll
    for (int t = 0; t < 32; ++t) {
        float v = vals[t];
        if (v >= T0) {
            unsigned j = (unsigned)((t >> 2) * 256 + lane * 4 + (t & 3));
            unsigned bu = __float_as_uint(v);
            unsigned u = (bu & 0x80000000u) ? ~bu : (bu | 0x80000000u);
            u64 key = ((u64)u << 32) | (u64)(0xFFFFFFFFu - j);
            int slot = atomicAdd(&qn[w], 1);
            if (slot < QCAP) qkey[w][slot] = key;
        }
    }
    int C = qn[w];
    if (C > QCAP) C = QCAP;

    u64 key = (lane < C) ? qkey[w][lane] : 0ull;
    key = bitonic64_desc_u64(key, lane);
    int base = 64;
    while (base < C) {
        if (lane >= 20) {
            int src = base + (lane - 20);
            key = (src < C) ? qkey[w][src] : 0ull;
        }
        key = bitonic64_desc_u64(key, lane);
        base += 44;
    }
    if (lane < 20) {
        unsigned j = 0xFFFFFFFFu - (unsigned)(key & 0xFFFFFFFFull);
        idx_out[(size_t)(b * NPTS + i) * KNN + lane] = (u16)j;
    }
}

// ---------------------------------------------------------------- all-batch UV GEMM (z = batch)
template<int C, int O>
__global__ __launch_bounds__(256) void uvb_gemm_kernel(const float* __restrict__ X,
                                                       const float* __restrict__ W,
                                                       const float* __restrict__ bias,
                                                       float* __restrict__ UVA) {
    constexpr int KC = (C < 32) ? C : 32;
    __shared__ __align__(16) float As[KC][68];
    __shared__ __align__(16) float Bs[KC][68];
    int b = blockIdx.z;
    int r0 = blockIdx.y * 64, n0 = blockIdx.x * 64;
    int tx = threadIdx.x & 15, ty = threadIdx.x >> 4;
    float acc[4][4] = {};
    for (int c0 = 0; c0 < C; c0 += KC) {
        for (int t = threadIdx.x; t < 64 * KC; t += 256) {
            int i = t / KC, c = t % KC;
            As[c][i] = X[(size_t)(b * NPTS + r0 + i) * C + c0 + c];
            int n = n0 + i;
            float wv;
            if (n < O) wv = W[(size_t)n * (2 * C) + c0 + c];
            else {
                int o = n - O;
                wv = W[(size_t)o * (2 * C) + C + c0 + c] - W[(size_t)o * (2 * C) + c0 + c];
            }
            Bs[c][i] = wv;
        }
        __syncthreads();
#pragma unroll
        for (int c = 0; c < KC; ++c) {
            const float4 av = *(const float4*)&As[c][ty * 4];
            const float4 bv = *(const float4*)&Bs[c][tx * 4];
            float ar[4] = {av.x, av.y, av.z, av.w};
            float br[4] = {bv.x, bv.y, bv.z, bv.w};
#pragma unroll
            for (int r = 0; r < 4; ++r)
#pragma unroll
                for (int q = 0; q < 4; ++q) acc[r][q] = fmaf(ar[r], br[q], acc[r][q]);
        }
        __syncthreads();
    }
    float badd[4] = {0.f, 0.f, 0.f, 0.f};
    if (n0 >= O) {
#pragma unroll
        for (int q = 0; q < 4; ++q) badd[q] = bias[n0 - O + tx * 4 + q];
    }
    float* UVb = UVA + (size_t)b * NPTS * 2 * O;
#pragma unroll
    for (int r = 0; r < 4; ++r) {
        float4 o4 = make_float4(acc[r][0] + badd[0], acc[r][1] + badd[1],
                                acc[r][2] + badd[2], acc[r][3] + badd[3]);
        *(float4*)&UVb[(size_t)(r0 + ty * 4 + r) * (2 * O) + n0 + tx * 4] = o4;
    }
}

// ---------------------------------------------------------------- stats: block-partial sum/sumsq (z = batch, NO atomics)
template<int O>
__global__ __launch_bounds__(256) void statsb_kernel(const float* __restrict__ UVA,
                                                     const u16* __restrict__ idx,
                                                     float* __restrict__ PART) {
    constexpr int TPR = O / 4;
    constexpr int RPAR = 256 / TPR;
    constexpr int RPB = NPTS / SB;
    __shared__ float sh[256 * 8];
    int b = blockIdx.z;
    const float* UVb = UVA + (size_t)b * NPTS * 2 * O;
    int otid = threadIdx.x % TPR;
    int o = otid * 4;
    int rsub = threadIdx.x / TPR;
    int rbase = blockIdx.x * RPB;
    float s0 = 0, s1 = 0, s2 = 0, s3 = 0, q0 = 0, q1 = 0, q2 = 0, q3 = 0;
    for (int r = rbase + rsub; r < rbase + RPB; r += RPAR) {
        const float4 v4 = *(const float4*)&UVb[(size_t)r * (2 * O) + O + o];
        const u16* ix = idx + (size_t)(b * NPTS + r) * KNN;
#pragma unroll
        for (int k = 0; k < KNN; ++k) {
            int j = (int)ix[k] & (NPTS - 1);
            const float4 u4 = *(const float4*)&UVb[(size_t)j * (2 * O) + o];
            float h0 = u4.x + v4.x, h1 = u4.y + v4.y, h2 = u4.z + v4.z, h3 = u4.w + v4.w;
            s0 += h0; q0 = fmaf(h0, h0, q0);
            s1 += h1; q1 = fmaf(h1, h1, q1);
            s2 += h2; q2 = fmaf(h2, h2, q2);
            s3 += h3; q3 = fmaf(h3, h3, q3);
        }
    }
    float* my = &sh[threadIdx.x * 8];
    my[0] = s0; my[1] = s1; my[2] = s2; my[3] = s3;
    my[4] = q0; my[5] = q1; my[6] = q2; my[7] = q3;
    __syncthreads();
    if (threadIdx.x < TPR) {
        float a[8];
#pragma unroll
        for (int c = 0; c < 8; ++c) a[c] = sh[threadIdx.x * 8 + c];
        for (int g = 1; g < RPAR; ++g) {
            const float* p = &sh[(g * TPR + threadIdx.x) * 8];
#pragma unroll
            for (int c = 0; c < 8; ++c) a[c] += p[c];
        }
        float* dst = &PART[((size_t)b * SB + blockIdx.x) * (2 * O)];
#pragma unroll
        for (int c = 0; c < 4; ++c) { dst[o + c] = a[c]; dst[O + o + c] = a[4 + c]; }
    }
}

template<int O>
__global__ void bnp_kernel(const float* __restrict__ PART, const float* __restrict__ g,
                           const float* __restrict__ beta, float* __restrict__ bnp) {
    int o = threadIdx.x;
    float s = 0.f, ss = 0.f;
    for (int p = 0; p < BATCH * SB; ++p) {
        s += PART[(size_t)p * (2 * O) + o];
        ss += PART[(size_t)p * (2 * O) + O + o];
    }
    const float cnt = (float)NROWS * (float)KNN;
    float m = s / cnt;
    float var = ss / cnt - m * m;
    float sc = g[o] / sqrtf(var + EPSV);
    bnp[o] = sc;
    bnp[O + o] = beta[o] - m * sc;
}

// ---------------------------------------------------------------- apply (stages 1..3, z = batch)
template<int O>
__global__ __launch_bounds__(256) void applyb_kernel(const float* __restrict__ UVA,
                                                     const u16* __restrict__ idx,
                                                     const float* __restrict__ bnp,
                                                     float* __restrict__ Xn) {
    constexpr int TPR = O / 4;
    int b = blockIdx.z;
    const float* UVb = UVA + (size_t)b * NPTS * 2 * O;
    int e = blockIdx.x * 256 + threadIdx.x;     // grid.x = NPTS*TPR/256
    int o = (e % TPR) * 4, r = e / TPR;
    const float4 v4 = *(const float4*)&UVb[(size_t)r * (2 * O) + O + o];
    const u16* ix = idx + (size_t)(b * NPTS + r) * KNN;
    float mx0 = -FLT_MAX, mx1 = -FLT_MAX, mx2 = -FLT_MAX, mx3 = -FLT_MAX;
    float mn0 = FLT_MAX, mn1 = FLT_MAX, mn2 = FLT_MAX, mn3 = FLT_MAX;
#pragma unroll
    for (int k = 0; k < KNN; ++k) {
        int j = (int)ix[k] & (NPTS - 1);
        const float4 u4 = *(const float4*)&UVb[(size_t)j * (2 * O) + o];
        float h0 = u4.x + v4.x, h1 = u4.y + v4.y, h2 = u4.z + v4.z, h3 = u4.w + v4.w;
        mx0 = fmaxf(mx0, h0); mn0 = fminf(mn0, h0);
        mx1 = fmaxf(mx1, h1); mn1 = fminf(mn1, h1);
        mx2 = fmaxf(mx2, h2); mn2 = fminf(mn2, h2);
        mx3 = fmaxf(mx3, h3); mn3 = fminf(mn3, h3);
    }
    float4 out;
    { float sc = bnp[o + 0], t = bnp[O + o + 0]; out.x = fmaxf(fmaf(sc, (sc >= 0.f) ? mx0 : mn0, t), 0.f); }
    { float sc = bnp[o + 1], t = bnp[O + o + 1]; out.y = fmaxf(fmaf(sc, (sc >= 0.f) ? mx1 : mn1, t), 0.f); }
    { float sc = bnp[o + 2], t = bnp[O + o + 2]; out.z = fmaxf(fmaf(sc, (sc >= 0.f) ? mx2 : mn2, t), 0.f); }
    { float sc = bnp[o + 3], t = bnp[O + o + 3]; out.w = fmaxf(fmaf(sc, (sc >= 0.f) ? mx3 : mn3, t), 0.f); }
    *(float4*)&Xn[(size_t)(b * NPTS + r) * O + o] = out;
}

// ---------------------------------------------------------------- stage-4 apply: point-max into G0T (z = batch)
__global__ __launch_bounds__(256) void applyb4_kernel(const float* __restrict__ UVA,
                                                      const u16* __restrict__ idx,
                                                      const float* __restrict__ bnp,
                                                      float* __restrict__ g0T) {
    constexpr int O = 256;
    constexpr int TPR = O / 4;                  // 64
    constexpr int RPAR = 256 / TPR;             // 4
    constexpr int AB = 32;                      // grid.x
    constexpr int RPB = NPTS / AB;              // 64 rows/block
    __shared__ float sh[256 * 4];
    int b = blockIdx.z;
    const float* UVb = UVA + (size_t)b * NPTS * 2 * O;
    int otid = threadIdx.x & (TPR - 1);
    int o = otid * 4;
    int rsub = threadIdx.x >> 6;
    int rbase = blockIdx.x * RPB;
    float sc0 = bnp[o + 0], t0 = bnp[O + o + 0];
    float sc1 = bnp[o + 1], t1 = bnp[O + o + 1];
    float sc2 = bnp[o + 2], t2 = bnp[O + o + 2];
    float sc3 = bnp[o + 3], t3 = bnp[O + o + 3];
    float ym0 = 0.f, ym1 = 0.f, ym2 = 0.f, ym3 = 0.f;
    for (int r = rbase + rsub; r < rbase + RPB; r += RPAR) {
        const float4 v4 = *(const float4*)&UVb[(size_t)r * (2 * O) + O + o];
        const u16* ix = idx + (size_t)(b * NPTS + r) * KNN;
        float mx0 = -FLT_MAX, mx1 = -FLT_MAX, mx2 = -FLT_MAX, mx3 = -FLT_MAX;
        float mn0 = FLT_MAX, mn1 = FLT_MAX, mn2 = FLT_MAX, mn3 = FLT_MAX;
#pragma unroll
        for (int k = 0; k < KNN; ++k) {
            int j = (int)ix[k] & (NPTS - 1);
            const float4 u4 = *(const float4*)&UVb[(size_t)j * (2 * O) + o];
            float h0 = u4.x + v4.x, h1 = u4.y + v4.y, h2 = u4.z + v4.z, h3 = u4.w + v4.w;
            mx0 = fmaxf(mx0, h0); mn0 = fminf(mn0, h0);
            mx1 = fmaxf(mx1, h1); mn1 = fminf(mn1, h1);
            mx2 = fmaxf(mx2, h2); mn2 = fminf(mn2, h2);
            mx3 = fmaxf(mx3, h3); mn3 = fminf(mn3, h3);
        }
        ym0 = fmaxf(ym0, fmaf(sc0, (sc0 >= 0.f) ? mx0 : mn0, t0));
        ym1 = fmaxf(ym1, fmaf(sc1, (sc1 >= 0.f) ? mx1 : mn1, t1));
        ym2 = fmaxf(ym2, fmaf(sc2, (sc2 >= 0.f) ? mx2 : mn2, t2));
        ym3 = fmaxf(ym3, fmaf(sc3, (sc3 >= 0.f) ? mx3 : mn3, t3));
    }
    float* my = &sh[threadIdx.x * 4];
    my[0] = ym0; my[1] = ym1; my[2] = ym2; my[3] = ym3;
    __syncthreads();
    if (threadIdx.x < TPR) {
        float a0 = ym0, a1 = ym1, a2 = ym2, a3 = ym3;
        for (int g = 1; g < RPAR; ++g) {
            const float* p = &sh[(g * TPR + threadIdx.x) * 4];
            a0 = fmaxf(a0, p[0]); a1 = fmaxf(a1, p[1]);
            a2 = fmaxf(a2, p[2]); a3 = fmaxf(a3, p[3]);
        }
        a0 = fmaxf(a0, 0.f); a1 = fmaxf(a1, 0.f);
        a2 = fmaxf(a2, 0.f); a3 = fmaxf(a3, 0.f);
        atomicMax((int*)&g0T[(o + 0) * 8 + b], __float_as_int(a0));
        atomicMax((int*)&g0T[(o + 1) * 8 + b], __float_as_int(a1));
        atomicMax((int*)&g0T[(o + 2) * 8 + b], __float_as_int(a2));
        atomicMax((int*)&g0T[(o + 3) * 8 + b], __float_as_int(a3));
    }
}

// ---------------------------------------------------------------- point-max of X2/X3 into G0T channels [256,448) — parallel chunks
__global__ __launch_bounds__(256) void gmax23_kernel(const float* __restrict__ X2,
                                                     const float* __restrict__ X3,
                                                     float* __restrict__ g0T) {
    int b = blockIdx.x;
    int n0 = blockIdx.y * 32;                   // grid.y = 64 -> 32 rows per block
    int o = threadIdx.x;
    if (o >= 192) return;
    const float* src; int col, stride, ch;
    if (o < 128) { src = X3; col = o;       stride = 128; ch = 256 + o; }
    else         { src = X2; col = o - 128; stride = 64;  ch = 384 + (o - 128); }
    float m = 0.f;
#pragma unroll 8
    for (int n = n0; n < n0 + 32; ++n)
        m = fmaxf(m, src[((size_t)(b * NPTS + n)) * stride + col]);
    atomicMax((int*)&g0T[ch * 8 + b], __float_as_int(m));
}

// ---------------------------------------------------------------- fc weight transpose ([o][c] -> [c][o])
__global__ __launch_bounds__(256) void transpose_kernel(const float* __restrict__ w,
                                                        float* __restrict__ wT, int O, int Cc) {
    int e = blockIdx.x * 256 + threadIdx.x;
    if (e >= O * Cc) return;
    int o = e / Cc, c = e - o * Cc;
    wT[c * O + o] = w[e];
}

// ---------------------------------------------------------------- fc1 + bnf1 + relu
__global__ __launch_bounds__(64) void fc1_kernel(const float* __restrict__ g0T,
                                                 const float* __restrict__ w1T,
                                                 const float* __restrict__ b1,
                                                 const float* __restrict__ bng,
                                                 const float* __restrict__ bnb,
                                                 float* __restrict__ A) {
    int o = blockIdx.x * 64 + threadIdx.x;
    float acc[8] = {};
    for (int c = 0; c < 448; ++c) {
        float wv = w1T[c * 256 + o];
        const float4 h0 = *(const float4*)&g0T[c * 8];
        const float4 h1 = *(const float4*)&g0T[c * 8 + 4];
        acc[0] = fmaf(wv, h0.x, acc[0]); acc[1] = fmaf(wv, h0.y, acc[1]);
        acc[2] = fmaf(wv, h0.z, acc[2]); acc[3] = fmaf(wv, h0.w, acc[3]);
        acc[4] = fmaf(wv, h1.x, acc[4]); acc[5] = fmaf(wv, h1.y, acc[5]);
        acc[6] = fmaf(wv, h1.z, acc[6]); acc[7] = fmaf(wv, h1.w, acc[7]);
    }
    float bb = b1[o];
    float h[8], m = 0.f;
#pragma unroll
    for (int b = 0; b < 8; ++b) { h[b] = acc[b] + bb; m += h[b]; }
    m *= 0.125f;
    float var = 0.f;
#pragma unroll
    for (int b = 0; b < 8; ++b) { float d = h[b] - m; var = fmaf(d, d, var); }
    var *= 0.125f;
    float sc = bng[o] / sqrtf(var + EPSV);
    float t = bnb[o] - m * sc;
#pragma unroll
    for (int b = 0; b < 8; ++b) A[o * 8 + b] = fmaxf(fmaf(sc, h[b], t), 0.f);
}

// ---------------------------------------------------------------- fc2..fc4 tail (one block)
__global__ __launch_bounds__(256) void tail_kernel(const float* __restrict__ A,
                                                   const float* __restrict__ w2T, const float* __restrict__ b2,
                                                   const float* __restrict__ g2, const float* __restrict__ be2,
                                                   const float* __restrict__ w3T, const float* __restrict__ b3,
                                                   const float* __restrict__ g3, const float* __restrict__ be3,
                                                   const float* __restrict__ w4, const float* __restrict__ b4,
                                                   float* __restrict__ out) {
    __shared__ __align__(16) float B2[128 * 8];
    __shared__ __align__(16) float C3[16 * 8];
    int tid = threadIdx.x;
    if (tid < 128) {
        int o = tid;
        float acc[8] = {};
        for (int c = 0; c < 256; ++c) {
            float wv = w2T[c * 128 + o];
            const float4 a0 = *(const float4*)&A[c * 8];
            const float4 a1 = *(const float4*)&A[c * 8 + 4];
            acc[0] = fmaf(wv, a0.x, acc[0]); acc[1] = fmaf(wv, a0.y, acc[1]);
            acc[2] = fmaf(wv, a0.z, acc[2]); acc[3] = fmaf(wv, a0.w, acc[3]);
            acc[4] = fmaf(wv, a1.x, acc[4]); acc[5] = fmaf(wv, a1.y, acc[5]);
            acc[6] = fmaf(wv, a1.z, acc[6]); acc[7] = fmaf(wv, a1.w, acc[7]);
        }
        float bb = b2[o];
        float h[8], m = 0.f;
#pragma unroll
        for (int b = 0; b < 8; ++b) { h[b] = acc[b] + bb; m += h[b]; }
        m *= 0.125f;
        float var = 0.f;
#pragma unroll
        for (int b = 0; b < 8; ++b) { float d = h[b] - m; var = fmaf(d, d, var); }
        var *= 0.125f;
        float sc = g2[o] / sqrtf(var + EPSV);
        float t = be2[o] - m * sc;
#pragma unroll
        for (int b = 0; b < 8; ++b) B2[o * 8 + b] = fmaxf(fmaf(sc, h[b], t), 0.f);
    }
    __syncthreads();
    if (tid < 16) {
        int o = tid;
        float acc[8] = {};
        for (int c = 0; c < 128; ++c) {
            float wv = w3T[c * 16 + o];
            const float4 a0 = *(const float4*)&B2[c * 8];
            const float4 a1 = *(const float4*)&B2[c * 8 + 4];
            acc[0] = fmaf(wv, a0.x, acc[0]); acc[1] = fmaf(wv, a0.y, acc[1]);
            acc[2] = fmaf(wv, a0.z, acc[2]); acc[3] = fmaf(wv, a0.w, acc[3]);
            acc[4] = fmaf(wv, a1.x, acc[4]); acc[5] = fmaf(wv, a1.y, acc[5]);
            acc[6] = fmaf(wv, a1.z, acc[6]); acc[7] = fmaf(wv, a1.w, acc[7]);
        }
        float bb = b3[o];
        float h[8], m = 0.f;
#pragma unroll
        for (int b = 0; b < 8; ++b) { h[b] = acc[b] + bb; m += h[b]; }
        m *= 0.125f;
        float var = 0.f;
#pragma unroll
        for (int b = 0; b < 8; ++b) { float d = h[b] - m; var = fmaf(d, d, var); }
        var *= 0.125f;
        float sc = g3[o] / sqrtf(var + EPSV);
        float t = be3[o] - m * sc;
#pragma unroll
        for (int b = 0; b < 8; ++b) C3[o * 8 + b] = fmaxf(fmaf(sc, h[b], t), 0.f);
    }
    __syncthreads();
    if (tid < 8) {
        int b = tid;
        float acc = b4[0];
#pragma unroll
        for (int c = 0; c < 16; ++c) acc = fmaf(w4[c], C3[c * 8 + b], acc);
        out[b] = acc;
    }
}

// ================================================================ host side
struct Arena {
    char* base; size_t off, cap; bool ok;
    Arena(void* b, size_t c) : base((char*)b), off(0), cap(c), ok(true) {}
    void* get(size_t bytes) {
        char* p = base + off;
        off += (bytes + 255) & ~(size_t)255;
        if (off > cap) ok = false;
        return p;
    }
};

// one EdgeConv stage, output stored to Xout (stages 1..3)
template<int C, int O>
static void run_stage(const float* Xin, float* Xout, const float* W, const float* bias,
                      const float* g, const float* be, float* SCR, float* UVA,
                      u16* IDX, float* SQ, float* PART, float* BNP, hipStream_t s) {
    dim3 blk(256);
    sqnorm_kernel<C><<<NROWS / 256, blk, 0, s>>>(Xin, SQ);
    for (int b0 = 0; b0 < BATCH; b0 += 2) {
        dist_gemm_kernel<C><<<dim3(NPTS / 64, NPTS / 64, 2), blk, 0, s>>>(Xin, SCR, b0);
        topk_kernel<<<dim3(NPTS / 4, 1, 2), blk, 0, s>>>(SCR, SQ, IDX, b0);
    }
    uvb_gemm_kernel<C, O><<<dim3(2 * O / 64, NPTS / 64, BATCH), blk, 0, s>>>(Xin, W, bias, UVA);
    statsb_kernel<O><<<dim3(SB, 1, BATCH), blk, 0, s>>>(UVA, IDX, PART);
    bnp_kernel<O><<<1, O, 0, s>>>(PART, g, be, BNP);
    applyb_kernel<O><<<dim3(NPTS * (O / 4) / 256, 1, BATCH), blk, 0, s>>>(UVA, IDX, BNP, Xout);
}

// stage 4: point-max fused into G0T (no X4 buffer)
static void run_stage4(const float* Xin, const float* W, const float* bias,
                       const float* g, const float* be, float* SCR, float* UVA,
                       u16* IDX, float* SQ, float* PART, float* BNP, float* G0T,
                       hipStream_t s) {
    constexpr int C = 128;
    dim3 blk(256);
    sqnorm_kernel<C><<<NROWS / 256, blk, 0, s>>>(Xin, SQ);
    for (int b0 = 0; b0 < BATCH; b0 += 2) {
        dist_gemm_kernel<C><<<dim3(NPTS / 64, NPTS / 64, 2), blk, 0, s>>>(Xin, SCR, b0);
        topk_kernel<<<dim3(NPTS / 4, 1, 2), blk, 0, s>>>(SCR, SQ, IDX, b0);
    }
    uvb_gemm_kernel<C, 256><<<dim3(8, NPTS / 64, BATCH), blk, 0, s>>>(Xin, W, bias, UVA);
    statsb_kernel<256><<<dim3(SB, 1, BATCH), blk, 0, s>>>(UVA, IDX, PART);
    bnp_kernel<256><<<1, 256, 0, s>>>(PART, g, be, BNP);
    fill_zero_kernel<<<14, blk, 0, s>>>(G0T, 448 * 8);
    applyb4_kernel<<<dim3(32, 1, BATCH), blk, 0, s>>>(UVA, IDX, BNP, G0T);
}

extern "C" void kernel_launch(void* const* d_in, const int* in_sizes, int n_in,
                              void* d_out, int out_size, void* d_ws, size_t ws_size,
                              hipStream_t stream) {
    float* out = (float*)d_out;
    if (n_in < 31) { diag_kernel<<<1, 64, 0, stream>>>(out, 9000.f); return; }

    const float* x       = (const float*)d_in[0];
    const float* cw[4]   = {(const float*)d_in[1], (const float*)d_in[5], (const float*)d_in[9],  (const float*)d_in[13]};
    const float* cb[4]   = {(const float*)d_in[2], (const float*)d_in[6], (const float*)d_in[10], (const float*)d_in[14]};
    const float* bg[4]   = {(const float*)d_in[3], (const float*)d_in[7], (const float*)d_in[11], (const float*)d_in[15]};
    const float* bb[4]   = {(const float*)d_in[4], (const float*)d_in[8], (const float*)d_in[12], (const float*)d_in[16]};
    const float* fc1_w = (const float*)d_in[17]; const float* fc1_b = (const float*)d_in[18];
    const float* bnf1_g = (const float*)d_in[19]; const float* bnf1_b = (const float*)d_in[20];
    const float* fc2_w = (const float*)d_in[21]; const float* fc2_b = (const float*)d_in[22];
    const float* bnf2_g = (const float*)d_in[23]; const float* bnf2_b = (const float*)d_in[24];
    const float* fc3_w = (const float*)d_in[25]; const float* fc3_b = (const float*)d_in[26];
    const float* bnf3_g = (const float*)d_in[27]; const float* bnf3_b = (const float*)d_in[28];
    const float* fc4_w = (const float*)d_in[29]; const float* fc4_b = (const float*)d_in[30];

    Arena ar(d_ws, ws_size);
    float* X1 = (float*)ar.get((size_t)NROWS * 64 * 4);
    float* X2 = (float*)ar.get((size_t)NROWS * 64 * 4);
    float* X3 = (float*)ar.get((size_t)NROWS * 128 * 4);
    u16* IDX = (u16*)ar.get((size_t)NROWS * KNN * 2);
    float* SQ = (float*)ar.get((size_t)NROWS * 4);
    float* PART = (float*)ar.get((size_t)BATCH * SB * 512 * 4);   // 1 MB
    float* BNP = (float*)ar.get(512 * 4);
    float* G0T = (float*)ar.get(448 * 8 * 4);
    float* ABUF = (float*)ar.get(256 * 8 * 4);
    float* SCR = (float*)ar.get((size_t)2 * NPTS * NPTS * 4);     // DIST x2 batches / W-transposes (32 MB)
    float* UVA = (float*)ar.get((size_t)NROWS * 512 * 4);         // UV all batches, worst O=256 (32 MB)
    if (!ar.ok) {
        diag_kernel<<<1, 64, 0, stream>>>(out, 3000.f + (float)(ws_size >> 20));
        return;
    }

    dim3 blk(256);
    run_stage<3, 64>(x, X1, cw[0], cb[0], bg[0], bb[0], SCR, UVA, IDX, SQ, PART, BNP, stream);
    run_stage<64, 64>(X1, X2, cw[1], cb[1], bg[1], bb[1], SCR, UVA, IDX, SQ, PART, BNP, stream);
    run_stage<64, 128>(X2, X3, cw[2], cb[2], bg[2], bb[2], SCR, UVA, IDX, SQ, PART, BNP, stream);
    run_stage4(X3, cw[3], cb[3], bg[3], bb[3], SCR, UVA, IDX, SQ, PART, BNP, G0T, stream);

    gmax23_kernel<<<dim3(BATCH, 64), blk, 0, stream>>>(X2, X3, G0T);

    float* W1T = SCR;                            // head reuses SCR (DIST dead now)
    float* W2T = W1T + 448 * 256;
    float* W3T = W2T + 256 * 128;
    transpose_kernel<<<(256 * 448 + 255) / 256, blk, 0, stream>>>(fc1_w, W1T, 256, 448);
    transpose_kernel<<<(128 * 256 + 255) / 256, blk, 0, stream>>>(fc2_w, W2T, 128, 256);
    transpose_kernel<<<(16 * 128 + 255) / 256, blk, 0, stream>>>(fc3_w, W3T, 16, 128);
    fc1_kernel<<<4, 64, 0, stream>>>(G0T, W1T, fc1_b, bnf1_g, bnf1_b, ABUF);
    tail_kernel<<<1, 256, 0, stream>>>(ABUF, W2T, fc2_b, bnf2_g, bnf2_b,
                                       W3T, fc3_b, bnf3_g, bnf3_b, fc4_w, fc4_b, out);
}

// Round 10
// 1076.793 us; speedup vs baseline: 6.6973x; 1.0368x over previous
//
#include <hip/hip_runtime.h>
#include <hip/hip_bf16.h>
#include <cfloat>

constexpr int BATCH = 8, NPTS = 2048, KNN = 20;
constexpr int NROWS = BATCH * NPTS;
constexpr float EPSV = 1e-5f;
constexpr int QCAP = 512;
constexpr int SB = 64;                           // statsb blocks per batch

using u16 = unsigned short;
using u64 = unsigned long long;
typedef __attribute__((ext_vector_type(8))) short short8;
typedef __attribute__((ext_vector_type(4))) float f32x4;

// ---------------------------------------------------------------- diag / fill
__global__ void diag_kernel(float* out, float v) {
    if (threadIdx.x < 8) out[threadIdx.x] = v;
}

__global__ __launch_bounds__(256) void fill_zero_kernel(float* __restrict__ p, int n) {
    int i = blockIdx.x * 256 + threadIdx.x;
    if (i < n) p[i] = 0.f;
}

// ---------------------------------------------------------------- sqnorm over all rows
template<int C>
__global__ __launch_bounds__(256) void sqnorm_kernel(const float* __restrict__ X,
                                                     float* __restrict__ sq) {
    int r = blockIdx.x * 256 + threadIdx.x;     // grid = NROWS/256
    const float* x = X + (size_t)r * C;
    float s = 0.f;
#pragma unroll
    for (int c = 0; c < C; ++c) { float v = x[c]; s = fmaf(v, v, s); }
    sq[r] = s;
}

// ---------------------------------------------------------------- split X (f32) -> hi/lo bf16 (for MFMA dist)
template<int C>
__global__ __launch_bounds__(256) void split_kernel(const float* __restrict__ X,
                                                    u16* __restrict__ XHI,
                                                    u16* __restrict__ XLO) {
    int e = blockIdx.x * 256 + threadIdx.x;     // grid = NROWS*C/1024, float4 per thread
    const float4 v = *(const float4*)&X[(size_t)e * 4];
    float vv[4] = {v.x, v.y, v.z, v.w};
    u16 h[4], l[4];
#pragma unroll
    for (int q = 0; q < 4; ++q) {
        __hip_bfloat16 hb = __float2bfloat16(vv[q]);
        float hf = __bfloat162float(hb);
        __hip_bfloat16 lb = __float2bfloat16(vv[q] - hf);
        h[q] = *(u16*)&hb; l[q] = *(u16*)&lb;
    }
    ushort4 h4 = make_ushort4(h[0], h[1], h[2], h[3]);
    ushort4 l4 = make_ushort4(l[0], l[1], l[2], l[3]);
    *(ushort4*)&XHI[(size_t)e * 4] = h4;
    *(ushort4*)&XLO[(size_t)e * 4] = l4;
}

// ---------------------------------------------------------------- MFMA dist: D[z][i][j] = x_i · x_j via split-bf16 (hh + hl + lh)
// 16x16x32 bf16 layouts (verified): A/B row = lane&15, k = (lane>>4)*8 + e; C/D col = lane&15, row = (lane>>4)*4 + reg
template<int C>
__global__ __launch_bounds__(256) void dist_mfma_kernel(const u16* __restrict__ XHI,
                                                        const u16* __restrict__ XLO,
                                                        float* __restrict__ D, int b0) {
    constexpr int KB = C / 32;
    int b = b0 + blockIdx.z;
    int i0 = blockIdx.y * 64, j0 = blockIdx.x * 64;
    int w = threadIdx.x >> 6, lane = threadIdx.x & 63;
    int l15 = lane & 15, g = lane >> 4;
    const u16* Hb = XHI + (size_t)b * NPTS * C;
    const u16* Lb = XLO + (size_t)b * NPTS * C;
    int row_a = i0 + w * 16 + l15;
    short8 ahi[KB], alo[KB];
#pragma unroll
    for (int kb = 0; kb < KB; ++kb) {
        ahi[kb] = *(const short8*)&Hb[(size_t)row_a * C + kb * 32 + g * 8];
        alo[kb] = *(const short8*)&Lb[(size_t)row_a * C + kb * 32 + g * 8];
    }
    float* Dz = D + (size_t)blockIdx.z * NPTS * NPTS;
#pragma unroll
    for (int nt = 0; nt < 4; ++nt) {
        int row_b = j0 + nt * 16 + l15;
        f32x4 acc = {0.f, 0.f, 0.f, 0.f};
#pragma unroll
        for (int kb = 0; kb < KB; ++kb) {
            short8 bhi = *(const short8*)&Hb[(size_t)row_b * C + kb * 32 + g * 8];
            short8 blo = *(const short8*)&Lb[(size_t)row_b * C + kb * 32 + g * 8];
            acc = __builtin_amdgcn_mfma_f32_16x16x32_bf16(ahi[kb], bhi, acc, 0, 0, 0);
            acc = __builtin_amdgcn_mfma_f32_16x16x32_bf16(ahi[kb], blo, acc, 0, 0, 0);
            acc = __builtin_amdgcn_mfma_f32_16x16x32_bf16(alo[kb], bhi, acc, 0, 0, 0);
        }
        int col = j0 + nt * 16 + l15;
        int rbase = i0 + w * 16 + g * 4;
#pragma unroll
        for (int r = 0; r < 4; ++r)
            Dz[(size_t)(rbase + r) * NPTS + col] = acc[r];
    }
}

// ---------------------------------------------------------------- f32 dist GEMM (stage 1, C=3 only)
template<int C>
__global__ __launch_bounds__(256) void dist_gemm_kernel(const float* __restrict__ X,
                                                        float* __restrict__ D, int b0) {
    constexpr int KC = (C < 32) ? C : 32;
    __shared__ __align__(16) float As[KC][68];
    __shared__ __align__(16) float Bs[KC][68];
    int b = b0 + blockIdx.z;
    int i0 = blockIdx.y * 64, j0 = blockIdx.x * 64;
    const float* Xb = X + (size_t)b * NPTS * C;
    int tx = threadIdx.x & 15, ty = threadIdx.x >> 4;
    float acc[4][4] = {};
    for (int c0 = 0; c0 < C; c0 += KC) {
        for (int t = threadIdx.x; t < 64 * KC; t += 256) {
            int i = t / KC, c = t % KC;
            As[c][i] = Xb[(size_t)(i0 + i) * C + c0 + c];
            Bs[c][i] = Xb[(size_t)(j0 + i) * C + c0 + c];
        }
        __syncthreads();
#pragma unroll
        for (int c = 0; c < KC; ++c) {
            const float4 av = *(const float4*)&As[c][ty * 4];
            const float4 bv = *(const float4*)&Bs[c][tx * 4];
            float ar[4] = {av.x, av.y, av.z, av.w};
            float br[4] = {bv.x, bv.y, bv.z, bv.w};
#pragma unroll
            for (int r = 0; r < 4; ++r)
#pragma unroll
                for (int q = 0; q < 4; ++q) acc[r][q] = fmaf(ar[r], br[q], acc[r][q]);
        }
        __syncthreads();
    }
    float* Dz = D + (size_t)blockIdx.z * NPTS * NPTS;
#pragma unroll
    for (int r = 0; r < 4; ++r) {
        float4 o4 = make_float4(acc[r][0], acc[r][1], acc[r][2], acc[r][3]);
        *(float4*)&Dz[(size_t)(i0 + ty * 4 + r) * NPTS + j0 + tx * 4] = o4;
    }
}

// ---------------------------------------------------------------- wave-64 bitonic sorts (descending, lane 0 = max)
__device__ __forceinline__ float bitonic64_desc_f32(float key, int lane) {
#pragma unroll
    for (int k = 2; k <= 64; k <<= 1) {
#pragma unroll
        for (int j = k >> 1; j > 0; j >>= 1) {
            float p = __shfl_xor(key, j);
            bool keepMax = (((lane & j) == 0) == ((lane & k) == 0));
            key = ((key > p) == keepMax) ? key : p;
        }
    }
    return key;
}

__device__ __forceinline__ u64 bitonic64_desc_u64(u64 key, int lane) {
#pragma unroll
    for (int k = 2; k <= 64; k <<= 1) {
#pragma unroll
        for (int j = k >> 1; j > 0; j >>= 1) {
            u64 p = __shfl_xor(key, j);
            bool keepMax = (((lane & j) == 0) == ((lane & k) == 0));
            key = ((key > p) == keepMax) ? key : p;
        }
    }
    return key;
}

// ---------------------------------------------------------------- top-k: threshold from 20th lane-max, then exact bitonic select
__global__ __launch_bounds__(256) void topk_kernel(const float* __restrict__ D,
                                                   const float* __restrict__ sq,
                                                   u16* __restrict__ idx_out, int b0) {
    __shared__ u64 qkey[4][QCAP];
    __shared__ int qn[4];
    int b = b0 + blockIdx.z;
    int w = threadIdx.x >> 6, lane = threadIdx.x & 63;
    int i = blockIdx.x * 4 + w;
    const float* Drow = D + ((size_t)blockIdx.z * NPTS + i) * NPTS;
    const float* sqb = sq + b * NPTS;
    float sqi = sqb[i];
    if (lane == 0) qn[w] = 0;

    float vals[32];
    float mx = -FLT_MAX;
#pragma unroll
    for (int t = 0; t < 8; ++t) {
        int j = t * 256 + lane * 4;
        float4 v4 = *(const float4*)&Drow[j];
        float4 s4 = *(const float4*)&sqb[j];
        float a0 = (2.f * v4.x - sqi - s4.x) + 0.f;
        float a1 = (2.f * v4.y - sqi - s4.y) + 0.f;
        float a2 = (2.f * v4.z - sqi - s4.z) + 0.f;
        float a3 = (2.f * v4.w - sqi - s4.w) + 0.f;
        vals[t * 4 + 0] = a0; vals[t * 4 + 1] = a1;
        vals[t * 4 + 2] = a2; vals[t * 4 + 3] = a3;
        mx = fmaxf(mx, fmaxf(fmaxf(a0, a1), fmaxf(a2, a3)));
    }

    float sm = bitonic64_desc_f32(mx, lane);
    float T0 = __shfl(sm, 19);

#pragma unroll
    for (int t = 0; t < 32; ++t) {
        float v = vals[t];
        if (v >= T0) {
            unsigned j = (unsigned)((t >> 2) * 256 + lane * 4 + (t & 3));
            unsigned bu = __float_as_uint(v);
            unsigned u = (bu & 0x80000000u) ? ~bu : (bu | 0x80000000u);
            u64 key = ((u64)u << 32) | (u64)(0xFFFFFFFFu - j);
            int slot = atomicAdd(&qn[w], 1);
            if (slot < QCAP) qkey[w][slot] = key;
        }
    }
    int C = qn[w];
    if (C > QCAP) C = QCAP;

    u64 key = (lane < C) ? qkey[w][lane] : 0ull;
    key = bitonic64_desc_u64(key, lane);
    int base = 64;
    while (base < C) {
        if (lane >= 20) {
            int src = base + (lane - 20);
            key = (src < C) ? qkey[w][src] : 0ull;
        }
        key = bitonic64_desc_u64(key, lane);
        base += 44;
    }
    if (lane < 20) {
        unsigned j = 0xFFFFFFFFu - (unsigned)(key & 0xFFFFFFFFull);
        idx_out[(size_t)(b * NPTS + i) * KNN + lane] = (u16)j;
    }
}

// ---------------------------------------------------------------- all-batch UV GEMM (z = batch)
template<int C, int O>
__global__ __launch_bounds__(256) void uvb_gemm_kernel(const float* __restrict__ X,
                                                       const float* __restrict__ W,
                                                       const float* __restrict__ bias,
                                                       float* __restrict__ UVA) {
    constexpr int KC = (C < 32) ? C : 32;
    __shared__ __align__(16) float As[KC][68];
    __shared__ __align__(16) float Bs[KC][68];
    int b = blockIdx.z;
    int r0 = blockIdx.y * 64, n0 = blockIdx.x * 64;
    int tx = threadIdx.x & 15, ty = threadIdx.x >> 4;
    float acc[4][4] = {};
    for (int c0 = 0; c0 < C; c0 += KC) {
        for (int t = threadIdx.x; t < 64 * KC; t += 256) {
            int i = t / KC, c = t % KC;
            As[c][i] = X[(size_t)(b * NPTS + r0 + i) * C + c0 + c];
            int n = n0 + i;
            float wv;
            if (n < O) wv = W[(size_t)n * (2 * C) + c0 + c];
            else {
                int o = n - O;
                wv = W[(size_t)o * (2 * C) + C + c0 + c] - W[(size_t)o * (2 * C) + c0 + c];
            }
            Bs[c][i] = wv;
        }
        __syncthreads();
#pragma unroll
        for (int c = 0; c < KC; ++c) {
            const float4 av = *(const float4*)&As[c][ty * 4];
            const float4 bv = *(const float4*)&Bs[c][tx * 4];
            float ar[4] = {av.x, av.y, av.z, av.w};
            float br[4] = {bv.x, bv.y, bv.z, bv.w};
#pragma unroll
            for (int r = 0; r < 4; ++r)
#pragma unroll
                for (int q = 0; q < 4; ++q) acc[r][q] = fmaf(ar[r], br[q], acc[r][q]);
        }
        __syncthreads();
    }
    float badd[4] = {0.f, 0.f, 0.f, 0.f};
    if (n0 >= O) {
#pragma unroll
        for (int q = 0; q < 4; ++q) badd[q] = bias[n0 - O + tx * 4 + q];
    }
    float* UVb = UVA + (size_t)b * NPTS * 2 * O;
#pragma unroll
    for (int r = 0; r < 4; ++r) {
        float4 o4 = make_float4(acc[r][0] + badd[0], acc[r][1] + badd[1],
                                acc[r][2] + badd[2], acc[r][3] + badd[3]);
        *(float4*)&UVb[(size_t)(r0 + ty * 4 + r) * (2 * O) + n0 + tx * 4] = o4;
    }
}

// ---------------------------------------------------------------- stats: block-partial sum/sumsq (z = batch, NO atomics)
template<int O>
__global__ __launch_bounds__(256) void statsb_kernel(const float* __restrict__ UVA,
                                                     const u16* __restrict__ idx,
                                                     float* __restrict__ PART) {
    constexpr int TPR = O / 4;
    constexpr int RPAR = 256 / TPR;
    constexpr int RPB = NPTS / SB;
    __shared__ float sh[256 * 8];
    int b = blockIdx.z;
    const float* UVb = UVA + (size_t)b * NPTS * 2 * O;
    int otid = threadIdx.x % TPR;
    int o = otid * 4;
    int rsub = threadIdx.x / TPR;
    int rbase = blockIdx.x * RPB;
    float s0 = 0, s1 = 0, s2 = 0, s3 = 0, q0 = 0, q1 = 0, q2 = 0, q3 = 0;
    for (int r = rbase + rsub; r < rbase + RPB; r += RPAR) {
        const float4 v4 = *(const float4*)&UVb[(size_t)r * (2 * O) + O + o];
        const u16* ix = idx + (size_t)(b * NPTS + r) * KNN;
#pragma unroll
        for (int k = 0; k < KNN; ++k) {
            int j = (int)ix[k] & (NPTS - 1);
            const float4 u4 = *(const float4*)&UVb[(size_t)j * (2 * O) + o];
            float h0 = u4.x + v4.x, h1 = u4.y + v4.y, h2 = u4.z + v4.z, h3 = u4.w + v4.w;
            s0 += h0; q0 = fmaf(h0, h0, q0);
            s1 += h1; q1 = fmaf(h1, h1, q1);
            s2 += h2; q2 = fmaf(h2, h2, q2);
            s3 += h3; q3 = fmaf(h3, h3, q3);
        }
    }
    float* my = &sh[threadIdx.x * 8];
    my[0] = s0; my[1] = s1; my[2] = s2; my[3] = s3;
    my[4] = q0; my[5] = q1; my[6] = q2; my[7] = q3;
    __syncthreads();
    if (threadIdx.x < TPR) {
        float a[8];
#pragma unroll
        for (int c = 0; c < 8; ++c) a[c] = sh[threadIdx.x * 8 + c];
        for (int g = 1; g < RPAR; ++g) {
            const float* p = &sh[(g * TPR + threadIdx.x) * 8];
#pragma unroll
            for (int c = 0; c < 8; ++c) a[c] += p[c];
        }
        float* dst = &PART[((size_t)b * SB + blockIdx.x) * (2 * O)];
#pragma unroll
        for (int c = 0; c < 4; ++c) { dst[o + c] = a[c]; dst[O + o + c] = a[4 + c]; }
    }
}

template<int O>
__global__ void bnp_kernel(const float* __restrict__ PART, const float* __restrict__ g,
                           const float* __restrict__ beta, float* __restrict__ bnp) {
    int o = threadIdx.x;
    float s = 0.f, ss = 0.f;
    for (int p = 0; p < BATCH * SB; ++p) {
        s += PART[(size_t)p * (2 * O) + o];
        ss += PART[(size_t)p * (2 * O) + O + o];
    }
    const float cnt = (float)NROWS * (float)KNN;
    float m = s / cnt;
    float var = ss / cnt - m * m;
    float sc = g[o] / sqrtf(var + EPSV);
    bnp[o] = sc;
    bnp[O + o] = beta[o] - m * sc;
}

// ---------------------------------------------------------------- apply (stages 1..3, z = batch)
template<int O>
__global__ __launch_bounds__(256) void applyb_kernel(const float* __restrict__ UVA,
                                                     const u16* __restrict__ idx,
                                                     const float* __restrict__ bnp,
                                                     float* __restrict__ Xn) {
    constexpr int TPR = O / 4;
    int b = blockIdx.z;
    const float* UVb = UVA + (size_t)b * NPTS * 2 * O;
    int e = blockIdx.x * 256 + threadIdx.x;     // grid.x = NPTS*TPR/256
    int o = (e % TPR) * 4, r = e / TPR;
    const float4 v4 = *(const float4*)&UVb[(size_t)r * (2 * O) + O + o];
    const u16* ix = idx + (size_t)(b * NPTS + r) * KNN;
    float mx0 = -FLT_MAX, mx1 = -FLT_MAX, mx2 = -FLT_MAX, mx3 = -FLT_MAX;
    float mn0 = FLT_MAX, mn1 = FLT_MAX, mn2 = FLT_MAX, mn3 = FLT_MAX;
#pragma unroll
    for (int k = 0; k < KNN; ++k) {
        int j = (int)ix[k] & (NPTS - 1);
        const float4 u4 = *(const float4*)&UVb[(size_t)j * (2 * O) + o];
        float h0 = u4.x + v4.x, h1 = u4.y + v4.y, h2 = u4.z + v4.z, h3 = u4.w + v4.w;
        mx0 = fmaxf(mx0, h0); mn0 = fminf(mn0, h0);
        mx1 = fmaxf(mx1, h1); mn1 = fminf(mn1, h1);
        mx2 = fmaxf(mx2, h2); mn2 = fminf(mn2, h2);
        mx3 = fmaxf(mx3, h3); mn3 = fminf(mn3, h3);
    }
    float4 out;
    { float sc = bnp[o + 0], t = bnp[O + o + 0]; out.x = fmaxf(fmaf(sc, (sc >= 0.f) ? mx0 : mn0, t), 0.f); }
    { float sc = bnp[o + 1], t = bnp[O + o + 1]; out.y = fmaxf(fmaf(sc, (sc >= 0.f) ? mx1 : mn1, t), 0.f); }
    { float sc = bnp[o + 2], t = bnp[O + o + 2]; out.z = fmaxf(fmaf(sc, (sc >= 0.f) ? mx2 : mn2, t), 0.f); }
    { float sc = bnp[o + 3], t = bnp[O + o + 3]; out.w = fmaxf(fmaf(sc, (sc >= 0.f) ? mx3 : mn3, t), 0.f); }
    *(float4*)&Xn[(size_t)(b * NPTS + r) * O + o] = out;
}

// ---------------------------------------------------------------- stage-4 apply: point-max into G0T (z = batch)
__global__ __launch_bounds__(256) void applyb4_kernel(const float* __restrict__ UVA,
                                                      const u16* __restrict__ idx,
                                                      const float* __restrict__ bnp,
                                                      float* __restrict__ g0T) {
    constexpr int O = 256;
    constexpr int TPR = O / 4;                  // 64
    constexpr int RPAR = 256 / TPR;             // 4
    constexpr int AB = 32;                      // grid.x
    constexpr int RPB = NPTS / AB;              // 64 rows/block
    __shared__ float sh[256 * 4];
    int b = blockIdx.z;
    const float* UVb = UVA + (size_t)b * NPTS * 2 * O;
    int otid = threadIdx.x & (TPR - 1);
    int o = otid * 4;
    int rsub = threadIdx.x >> 6;
    int rbase = blockIdx.x * RPB;
    float sc0 = bnp[o + 0], t0 = bnp[O + o + 0];
    float sc1 = bnp[o + 1], t1 = bnp[O + o + 1];
    float sc2 = bnp[o + 2], t2 = bnp[O + o + 2];
    float sc3 = bnp[o + 3], t3 = bnp[O + o + 3];
    float ym0 = 0.f, ym1 = 0.f, ym2 = 0.f, ym3 = 0.f;
    for (int r = rbase + rsub; r < rbase + RPB; r += RPAR) {
        const float4 v4 = *(const float4*)&UVb[(size_t)r * (2 * O) + O + o];
        const u16* ix = idx + (size_t)(b * NPTS + r) * KNN;
        float mx0 = -FLT_MAX, mx1 = -FLT_MAX, mx2 = -FLT_MAX, mx3 = -FLT_MAX;
        float mn0 = FLT_MAX, mn1 = FLT_MAX, mn2 = FLT_MAX, mn3 = FLT_MAX;
#pragma unroll
        for (int k = 0; k < KNN; ++k) {
            int j = (int)ix[k] & (NPTS - 1);
            const float4 u4 = *(const float4*)&UVb[(size_t)j * (2 * O) + o];
            float h0 = u4.x + v4.x, h1 = u4.y + v4.y, h2 = u4.z + v4.z, h3 = u4.w + v4.w;
            mx0 = fmaxf(mx0, h0); mn0 = fminf(mn0, h0);
            mx1 = fmaxf(mx1, h1); mn1 = fminf(mn1, h1);
            mx2 = fmaxf(mx2, h2); mn2 = fminf(mn2, h2);
            mx3 = fmaxf(mx3, h3); mn3 = fminf(mn3, h3);
        }
        ym0 = fmaxf(ym0, fmaf(sc0, (sc0 >= 0.f) ? mx0 : mn0, t0));
        ym1 = fmaxf(ym1, fmaf(sc1, (sc1 >= 0.f) ? mx1 : mn1, t1));
        ym2 = fmaxf(ym2, fmaf(sc2, (sc2 >= 0.f) ? mx2 : mn2, t2));
        ym3 = fmaxf(ym3, fmaf(sc3, (sc3 >= 0.f) ? mx3 : mn3, t3));
    }
    float* my = &sh[threadIdx.x * 4];
    my[0] = ym0; my[1] = ym1; my[2] = ym2; my[3] = ym3;
    __syncthreads();
    if (threadIdx.x < TPR) {
        float a0 = ym0, a1 = ym1, a2 = ym2, a3 = ym3;
        for (int g = 1; g < RPAR; ++g) {
            const float* p = &sh[(g * TPR + threadIdx.x) * 4];
            a0 = fmaxf(a0, p[0]); a1 = fmaxf(a1, p[1]);
            a2 = fmaxf(a2, p[2]); a3 = fmaxf(a3, p[3]);
        }
        a0 = fmaxf(a0, 0.f); a1 = fmaxf(a1, 0.f);
        a2 = fmaxf(a2, 0.f); a3 = fmaxf(a3, 0.f);
        atomicMax((int*)&g0T[(o + 0) * 8 + b], __float_as_int(a0));
        atomicMax((int*)&g0T[(o + 1) * 8 + b], __float_as_int(a1));
        atomicMax((int*)&g0T[(o + 2) * 8 + b], __float_as_int(a2));
        atomicMax((int*)&g0T[(o + 3) * 8 + b], __float_as_int(a3));
    }
}

// ---------------------------------------------------------------- point-max of X2/X3 into G0T channels [256,448)
__global__ __launch_bounds__(256) void gmax23_kernel(const float* __restrict__ X2,
                                                     const float* __restrict__ X3,
                                                     float* __restrict__ g0T) {
    int b = blockIdx.x;
    int n0 = blockIdx.y * 32;                   // grid.y = 64 -> 32 rows per block
    int o = threadIdx.x;
    if (o >= 192) return;
    const float* src; int col, stride, ch;
    if (o < 128) { src = X3; col = o;       stride = 128; ch = 256 + o; }
    else         { src = X2; col = o - 128; stride = 64;  ch = 384 + (o - 128); }
    float m = 0.f;
#pragma unroll 8
    for (int n = n0; n < n0 + 32; ++n)
        m = fmaxf(m, src[((size_t)(b * NPTS + n)) * stride + col]);
    atomicMax((int*)&g0T[ch * 8 + b], __float_as_int(m));
}

// ---------------------------------------------------------------- fc weight transpose ([o][c] -> [c][o])
__global__ __launch_bounds__(256) void transpose_kernel(const float* __restrict__ w,
                                                        float* __restrict__ wT, int O, int Cc) {
    int e = blockIdx.x * 256 + threadIdx.x;
    if (e >= O * Cc) return;
    int o = e / Cc, c = e - o * Cc;
    wT[c * O + o] = w[e];
}

// ---------------------------------------------------------------- fc1 + bnf1 + relu
__global__ __launch_bounds__(64) void fc1_kernel(const float* __restrict__ g0T,
                                                 const float* __restrict__ w1T,
                                                 const float* __restrict__ b1,
                                                 const float* __restrict__ bng,
                                                 const float* __restrict__ bnb,
                                                 float* __restrict__ A) {
    int o = blockIdx.x * 64 + threadIdx.x;
    float acc[8] = {};
    for (int c = 0; c < 448; ++c) {
        float wv = w1T[c * 256 + o];
        const float4 h0 = *(const float4*)&g0T[c * 8];
        const float4 h1 = *(const float4*)&g0T[c * 8 + 4];
        acc[0] = fmaf(wv, h0.x, acc[0]); acc[1] = fmaf(wv, h0.y, acc[1]);
        acc[2] = fmaf(wv, h0.z, acc[2]); acc[3] = fmaf(wv, h0.w, acc[3]);
        acc[4] = fmaf(wv, h1.x, acc[4]); acc[5] = fmaf(wv, h1.y, acc[5]);
        acc[6] = fmaf(wv, h1.z, acc[6]); acc[7] = fmaf(wv, h1.w, acc[7]);
    }
    float bb = b1[o];
    float h[8], m = 0.f;
#pragma unroll
    for (int b = 0; b < 8; ++b) { h[b] = acc[b] + bb; m += h[b]; }
    m *= 0.125f;
    float var = 0.f;
#pragma unroll
    for (int b = 0; b < 8; ++b) { float d = h[b] - m; var = fmaf(d, d, var); }
    var *= 0.125f;
    float sc = bng[o] / sqrtf(var + EPSV);
    float t = bnb[o] - m * sc;
#pragma unroll
    for (int b = 0; b < 8; ++b) A[o * 8 + b] = fmaxf(fmaf(sc, h[b], t), 0.f);
}

// ---------------------------------------------------------------- fc2..fc4 tail (one block)
__global__ __launch_bounds__(256) void tail_kernel(const float* __restrict__ A,
                                                   const float* __restrict__ w2T, const float* __restrict__ b2,
                                                   const float* __restrict__ g2, const float* __restrict__ be2,
                                                   const float* __restrict__ w3T, const float* __restrict__ b3,
                                                   const float* __restrict__ g3, const float* __restrict__ be3,
                                                   const float* __restrict__ w4, const float* __restrict__ b4,
                                                   float* __restrict__ out) {
    __shared__ __align__(16) float B2[128 * 8];
    __shared__ __align__(16) float C3[16 * 8];
    int tid = threadIdx.x;
    if (tid < 128) {
        int o = tid;
        float acc[8] = {};
        for (int c = 0; c < 256; ++c) {
            float wv = w2T[c * 128 + o];
            const float4 a0 = *(const float4*)&A[c * 8];
            const float4 a1 = *(const float4*)&A[c * 8 + 4];
            acc[0] = fmaf(wv, a0.x, acc[0]); acc[1] = fmaf(wv, a0.y, acc[1]);
            acc[2] = fmaf(wv, a0.z, acc[2]); acc[3] = fmaf(wv, a0.w, acc[3]);
            acc[4] = fmaf(wv, a1.x, acc[4]); acc[5] = fmaf(wv, a1.y, acc[5]);
            acc[6] = fmaf(wv, a1.z, acc[6]); acc[7] = fmaf(wv, a1.w, acc[7]);
        }
        float bb = b2[o];
        float h[8], m = 0.f;
#pragma unroll
        for (int b = 0; b < 8; ++b) { h[b] = acc[b] + bb; m += h[b]; }
        m *= 0.125f;
        float var = 0.f;
#pragma unroll
        for (int b = 0; b < 8; ++b) { float d = h[b] - m; var = fmaf(d, d, var); }
        var *= 0.125f;
        float sc = g2[o] / sqrtf(var + EPSV);
        float t = be2[o] - m * sc;
#pragma unroll
        for (int b = 0; b < 8; ++b) B2[o * 8 + b] = fmaxf(fmaf(sc, h[b], t), 0.f);
    }
    __syncthreads();
    if (tid < 16) {
        int o = tid;
        float acc[8] = {};
        for (int c = 0; c < 128; ++c) {
            float wv = w3T[c * 16 + o];
            const float4 a0 = *(const float4*)&B2[c * 8];
            const float4 a1 = *(const float4*)&B2[c * 8 + 4];
            acc[0] = fmaf(wv, a0.x, acc[0]); acc[1] = fmaf(wv, a0.y, acc[1]);
            acc[2] = fmaf(wv, a0.z, acc[2]); acc[3] = fmaf(wv, a0.w, acc[3]);
            acc[4] = fmaf(wv, a1.x, acc[4]); acc[5] = fmaf(wv, a1.y, acc[5]);
            acc[6] = fmaf(wv, a1.z, acc[6]); acc[7] = fmaf(wv, a1.w, acc[7]);
        }
        float bb = b3[o];
        float h[8], m = 0.f;
#pragma unroll
        for (int b = 0; b < 8; ++b) { h[b] = acc[b] + bb; m += h[b]; }
        m *= 0.125f;
        float var = 0.f;
#pragma unroll
        for (int b = 0; b < 8; ++b) { float d = h[b] - m; var = fmaf(d, d, var); }
        var *= 0.125f;
        float sc = g3[o] / sqrtf(var + EPSV);
        float t = be3[o] - m * sc;
#pragma unroll
        for (int b = 0; b < 8; ++b) C3[o * 8 + b] = fmaxf(fmaf(sc, h[b], t), 0.f);
    }
    __syncthreads();
    if (tid < 8) {
        int b = tid;
        float acc = b4[0];
#pragma unroll
        for (int c = 0; c < 16; ++c) acc = fmaf(w4[c], C3[c * 8 + b], acc);
        out[b] = acc;
    }
}

// ================================================================ host side
struct Arena {
    char* base; size_t off, cap; bool ok;
    Arena(void* b, size_t c) : base((char*)b), off(0), cap(c), ok(true) {}
    void* get(size_t bytes) {
        char* p = base + off;
        off += (bytes + 255) & ~(size_t)255;
        if (off > cap) ok = false;
        return p;
    }
};

// one EdgeConv stage, output stored to Xout (stages 1..3)
template<int C, int O>
static void run_stage(const float* Xin, float* Xout, const float* W, const float* bias,
                      const float* g, const float* be, float* SCR, float* UVA,
                      u16* XHI, u16* XLO,
                      u16* IDX, float* SQ, float* PART, float* BNP, hipStream_t s) {
    dim3 blk(256);
    sqnorm_kernel<C><<<NROWS / 256, blk, 0, s>>>(Xin, SQ);
    if constexpr (C >= 32) {
        split_kernel<C><<<NROWS * C / 1024, blk, 0, s>>>(Xin, XHI, XLO);
        for (int b0 = 0; b0 < BATCH; b0 += 2) {
            dist_mfma_kernel<C><<<dim3(NPTS / 64, NPTS / 64, 2), blk, 0, s>>>(XHI, XLO, SCR, b0);
            topk_kernel<<<dim3(NPTS / 4, 1, 2), blk, 0, s>>>(SCR, SQ, IDX, b0);
        }
    } else {
        for (int b0 = 0; b0 < BATCH; b0 += 2) {
            dist_gemm_kernel<C><<<dim3(NPTS / 64, NPTS / 64, 2), blk, 0, s>>>(Xin, SCR, b0);
            topk_kernel<<<dim3(NPTS / 4, 1, 2), blk, 0, s>>>(SCR, SQ, IDX, b0);
        }
    }
    uvb_gemm_kernel<C, O><<<dim3(2 * O / 64, NPTS / 64, BATCH), blk, 0, s>>>(Xin, W, bias, UVA);
    statsb_kernel<O><<<dim3(SB, 1, BATCH), blk, 0, s>>>(UVA, IDX, PART);
    bnp_kernel<O><<<1, O, 0, s>>>(PART, g, be, BNP);
    applyb_kernel<O><<<dim3(NPTS * (O / 4) / 256, 1, BATCH), blk, 0, s>>>(UVA, IDX, BNP, Xout);
}

// stage 4: point-max fused into G0T (no X4 buffer)
static void run_stage4(const float* Xin, const float* W, const float* bias,
                       const float* g, const float* be, float* SCR, float* UVA,
                       u16* XHI, u16* XLO,
                       u16* IDX, float* SQ, float* PART, float* BNP, float* G0T,
                       hipStream_t s) {
    constexpr int C = 128;
    dim3 blk(256);
    sqnorm_kernel<C><<<NROWS / 256, blk, 0, s>>>(Xin, SQ);
    split_kernel<C><<<NROWS * C / 1024, blk, 0, s>>>(Xin, XHI, XLO);
    for (int b0 = 0; b0 < BATCH; b0 += 2) {
        dist_mfma_kernel<C><<<dim3(NPTS / 64, NPTS / 64, 2), blk, 0, s>>>(XHI, XLO, SCR, b0);
        topk_kernel<<<dim3(NPTS / 4, 1, 2), blk, 0, s>>>(SCR, SQ, IDX, b0);
    }
    uvb_gemm_kernel<C, 256><<<dim3(8, NPTS / 64, BATCH), blk, 0, s>>>(Xin, W, bias, UVA);
    statsb_kernel<256><<<dim3(SB, 1, BATCH), blk, 0, s>>>(UVA, IDX, PART);
    bnp_kernel<256><<<1, 256, 0, s>>>(PART, g, be, BNP);
    fill_zero_kernel<<<14, blk, 0, s>>>(G0T, 448 * 8);
    applyb4_kernel<<<dim3(32, 1, BATCH), blk, 0, s>>>(UVA, IDX, BNP, G0T);
}

extern "C" void kernel_launch(void* const* d_in, const int* in_sizes, int n_in,
                              void* d_out, int out_size, void* d_ws, size_t ws_size,
                              hipStream_t stream) {
    float* out = (float*)d_out;
    if (n_in < 31) { diag_kernel<<<1, 64, 0, stream>>>(out, 9000.f); return; }

    const float* x       = (const float*)d_in[0];
    const float* cw[4]   = {(const float*)d_in[1], (const float*)d_in[5], (const float*)d_in[9],  (const float*)d_in[13]};
    const float* cb[4]   = {(const float*)d_in[2], (const float*)d_in[6], (const float*)d_in[10], (const float*)d_in[14]};
    const float* bg[4]   = {(const float*)d_in[3], (const float*)d_in[7], (const float*)d_in[11], (const float*)d_in[15]};
    const float* bb[4]   = {(const float*)d_in[4], (const float*)d_in[8], (const float*)d_in[12], (const float*)d_in[16]};
    const float* fc1_w = (const float*)d_in[17]; const float* fc1_b = (const float*)d_in[18];
    const float* bnf1_g = (const float*)d_in[19]; const float* bnf1_b = (const float*)d_in[20];
    const float* fc2_w = (const float*)d_in[21]; const float* fc2_b = (const float*)d_in[22];
    const float* bnf2_g = (const float*)d_in[23]; const float* bnf2_b = (const float*)d_in[24];
    const float* fc3_w = (const float*)d_in[25]; const float* fc3_b = (const float*)d_in[26];
    const float* bnf3_g = (const float*)d_in[27]; const float* bnf3_b = (const float*)d_in[28];
    const float* fc4_w = (const float*)d_in[29]; const float* fc4_b = (const float*)d_in[30];

    Arena ar(d_ws, ws_size);
    float* X1 = (float*)ar.get((size_t)NROWS * 64 * 4);
    float* X2 = (float*)ar.get((size_t)NROWS * 64 * 4);
    float* X3 = (float*)ar.get((size_t)NROWS * 128 * 4);
    u16* IDX = (u16*)ar.get((size_t)NROWS * KNN * 2);
    float* SQ = (float*)ar.get((size_t)NROWS * 4);
    float* PART = (float*)ar.get((size_t)BATCH * SB * 512 * 4);   // 1 MB
    float* BNP = (float*)ar.get(512 * 4);
    float* G0T = (float*)ar.get(448 * 8 * 4);
    float* ABUF = (float*)ar.get(256 * 8 * 4);
    u16* XHI = (u16*)ar.get((size_t)NROWS * 128 * 2);             // 4 MB (max C = 128)
    u16* XLO = (u16*)ar.get((size_t)NROWS * 128 * 2);             // 4 MB
    float* SCR = (float*)ar.get((size_t)2 * NPTS * NPTS * 4);     // DIST x2 batches / W-transposes (32 MB)
    float* UVA = (float*)ar.get((size_t)NROWS * 512 * 4);         // UV all batches, worst O=256 (32 MB)
    if (!ar.ok) {
        diag_kernel<<<1, 64, 0, stream>>>(out, 3000.f + (float)(ws_size >> 20));
        return;
    }

    dim3 blk(256);
    run_stage<3, 64>(x, X1, cw[0], cb[0], bg[0], bb[0], SCR, UVA, XHI, XLO, IDX, SQ, PART, BNP, stream);
    run_stage<64, 64>(X1, X2, cw[1], cb[1], bg[1], bb[1], SCR, UVA, XHI, XLO, IDX, SQ, PART, BNP, stream);
    run_stage<64, 128>(X2, X3, cw[2], cb[2], bg[2], bb[2], SCR, UVA, XHI, XLO, IDX, SQ, PART, BNP, stream);
    run_stage4(X3, cw[3], cb[3], bg[3], bb[3], SCR, UVA, XHI, XLO, IDX, SQ, PART, BNP, G0T, stream);

    gmax23_kernel<<<dim3(BATCH, 64), blk, 0, stream>>>(X2, X3, G0T);

    float* W1T = SCR;                            // head reuses SCR (DIST dead now)
    float* W2T = W1T + 448 * 256;
    float* W3T = W2T + 256 * 128;
    transpose_kernel<<<(256 * 448 + 255) / 256, blk, 0, stream>>>(fc1_w, W1T, 256, 448);
    transpose_kernel<<<(128 * 256 + 255) / 256, blk, 0, stream>>>(fc2_w, W2T, 128, 256);
    transpose_kernel<<<(16 * 128 + 255) / 256, blk, 0, stream>>>(fc3_w, W3T, 16, 128);
    fc1_kernel<<<4, 64, 0, stream>>>(G0T, W1T, fc1_b, bnf1_g, bnf1_b, ABUF);
    tail_kernel<<<1, 256, 0, stream>>>(ABUF, W2T, fc2_b, bnf2_g, bnf2_b,
                                       W3T, fc3_b, bnf3_g, bnf3_b, fc4_w, fc4_b, out);
}

// Round 11
// 1027.242 us; speedup vs baseline: 7.0203x; 1.0482x over previous
//
#include <hip/hip_runtime.h>
#include <hip/hip_bf16.h>
#include <cfloat>

constexpr int BATCH = 8, NPTS = 2048, KNN = 20;
constexpr int NROWS = BATCH * NPTS;
constexpr float EPSV = 1e-5f;
constexpr int QCAP = 512;
constexpr int SB = 64;                           // statsb blocks per batch

using u16 = unsigned short;
using u64 = unsigned long long;
typedef __attribute__((ext_vector_type(8))) short short8;
typedef __attribute__((ext_vector_type(4))) float f32x4;

// ---------------------------------------------------------------- diag / fill
__global__ void diag_kernel(float* out, float v) {
    if (threadIdx.x < 8) out[threadIdx.x] = v;
}

__global__ __launch_bounds__(256) void fill_zero_kernel(float* __restrict__ p, int n) {
    int i = blockIdx.x * 256 + threadIdx.x;
    if (i < n) p[i] = 0.f;
}

// ---------------------------------------------------------------- sqnorm over all rows
template<int C>
__global__ __launch_bounds__(256) void sqnorm_kernel(const float* __restrict__ X,
                                                     float* __restrict__ sq) {
    int r = blockIdx.x * 256 + threadIdx.x;     // grid = NROWS/256
    const float* x = X + (size_t)r * C;
    float s = 0.f;
#pragma unroll
    for (int c = 0; c < C; ++c) { float v = x[c]; s = fmaf(v, v, s); }
    sq[r] = s;
}

// ---------------------------------------------------------------- split X (f32) -> hi/lo bf16
template<int C>
__global__ __launch_bounds__(256) void split_kernel(const float* __restrict__ X,
                                                    u16* __restrict__ XHI,
                                                    u16* __restrict__ XLO) {
    int e = blockIdx.x * 256 + threadIdx.x;     // grid = NROWS*C/1024, float4 per thread
    const float4 v = *(const float4*)&X[(size_t)e * 4];
    float vv[4] = {v.x, v.y, v.z, v.w};
    u16 h[4], l[4];
#pragma unroll
    for (int q = 0; q < 4; ++q) {
        __hip_bfloat16 hb = __float2bfloat16(vv[q]);
        float hf = __bfloat162float(hb);
        __hip_bfloat16 lb = __float2bfloat16(vv[q] - hf);
        h[q] = *(u16*)&hb; l[q] = *(u16*)&lb;
    }
    *(ushort4*)&XHI[(size_t)e * 4] = make_ushort4(h[0], h[1], h[2], h[3]);
    *(ushort4*)&XLO[(size_t)e * 4] = make_ushort4(l[0], l[1], l[2], l[3]);
}

// ---------------------------------------------------------------- split W -> WB[n][c] hi/lo (n<O: W1; n>=O: W2-W1), bf16
template<int C, int O>
__global__ __launch_bounds__(256) void wsplit_kernel(const float* __restrict__ W,
                                                     u16* __restrict__ WHI,
                                                     u16* __restrict__ WLO) {
    int e = blockIdx.x * 256 + threadIdx.x;
    if (e >= 2 * O * C) return;
    int n = e / C, c = e - n * C;
    float wv = (n < O) ? W[(size_t)n * (2 * C) + c]
                       : W[(size_t)(n - O) * (2 * C) + C + c] - W[(size_t)(n - O) * (2 * C) + c];
    __hip_bfloat16 hb = __float2bfloat16(wv);
    float hf = __bfloat162float(hb);
    __hip_bfloat16 lb = __float2bfloat16(wv - hf);
    WHI[e] = *(u16*)&hb;
    WLO[e] = *(u16*)&lb;
}

// ---------------------------------------------------------------- MFMA dist: D[z][i][j] = x_i · x_j via split-bf16 (hh + hl + lh)
template<int C>
__global__ __launch_bounds__(256) void dist_mfma_kernel(const u16* __restrict__ XHI,
                                                        const u16* __restrict__ XLO,
                                                        float* __restrict__ D, int b0) {
    constexpr int KB = C / 32;
    int b = b0 + blockIdx.z;
    int i0 = blockIdx.y * 64, j0 = blockIdx.x * 64;
    int w = threadIdx.x >> 6, lane = threadIdx.x & 63;
    int l15 = lane & 15, g = lane >> 4;
    const u16* Hb = XHI + (size_t)b * NPTS * C;
    const u16* Lb = XLO + (size_t)b * NPTS * C;
    int row_a = i0 + w * 16 + l15;
    short8 ahi[KB], alo[KB];
#pragma unroll
    for (int kb = 0; kb < KB; ++kb) {
        ahi[kb] = *(const short8*)&Hb[(size_t)row_a * C + kb * 32 + g * 8];
        alo[kb] = *(const short8*)&Lb[(size_t)row_a * C + kb * 32 + g * 8];
    }
    float* Dz = D + (size_t)blockIdx.z * NPTS * NPTS;
#pragma unroll
    for (int nt = 0; nt < 4; ++nt) {
        int row_b = j0 + nt * 16 + l15;
        f32x4 acc = {0.f, 0.f, 0.f, 0.f};
#pragma unroll
        for (int kb = 0; kb < KB; ++kb) {
            short8 bhi = *(const short8*)&Hb[(size_t)row_b * C + kb * 32 + g * 8];
            short8 blo = *(const short8*)&Lb[(size_t)row_b * C + kb * 32 + g * 8];
            acc = __builtin_amdgcn_mfma_f32_16x16x32_bf16(ahi[kb], bhi, acc, 0, 0, 0);
            acc = __builtin_amdgcn_mfma_f32_16x16x32_bf16(ahi[kb], blo, acc, 0, 0, 0);
            acc = __builtin_amdgcn_mfma_f32_16x16x32_bf16(alo[kb], bhi, acc, 0, 0, 0);
        }
        int col = j0 + nt * 16 + l15;
        int rbase = i0 + w * 16 + g * 4;
#pragma unroll
        for (int r = 0; r < 4; ++r)
            Dz[(size_t)(rbase + r) * NPTS + col] = acc[r];
    }
}

// ---------------------------------------------------------------- f32 dist GEMM (stage 1, C=3 only)
template<int C>
__global__ __launch_bounds__(256) void dist_gemm_kernel(const float* __restrict__ X,
                                                        float* __restrict__ D, int b0) {
    constexpr int KC = (C < 32) ? C : 32;
    __shared__ __align__(16) float As[KC][68];
    __shared__ __align__(16) float Bs[KC][68];
    int b = b0 + blockIdx.z;
    int i0 = blockIdx.y * 64, j0 = blockIdx.x * 64;
    const float* Xb = X + (size_t)b * NPTS * C;
    int tx = threadIdx.x & 15, ty = threadIdx.x >> 4;
    float acc[4][4] = {};
    for (int c0 = 0; c0 < C; c0 += KC) {
        for (int t = threadIdx.x; t < 64 * KC; t += 256) {
            int i = t / KC, c = t % KC;
            As[c][i] = Xb[(size_t)(i0 + i) * C + c0 + c];
            Bs[c][i] = Xb[(size_t)(j0 + i) * C + c0 + c];
        }
        __syncthreads();
#pragma unroll
        for (int c = 0; c < KC; ++c) {
            const float4 av = *(const float4*)&As[c][ty * 4];
            const float4 bv = *(const float4*)&Bs[c][tx * 4];
            float ar[4] = {av.x, av.y, av.z, av.w};
            float br[4] = {bv.x, bv.y, bv.z, bv.w};
#pragma unroll
            for (int r = 0; r < 4; ++r)
#pragma unroll
                for (int q = 0; q < 4; ++q) acc[r][q] = fmaf(ar[r], br[q], acc[r][q]);
        }
        __syncthreads();
    }
    float* Dz = D + (size_t)blockIdx.z * NPTS * NPTS;
#pragma unroll
    for (int r = 0; r < 4; ++r) {
        float4 o4 = make_float4(acc[r][0], acc[r][1], acc[r][2], acc[r][3]);
        *(float4*)&Dz[(size_t)(i0 + ty * 4 + r) * NPTS + j0 + tx * 4] = o4;
    }
}

// ---------------------------------------------------------------- wave-64 bitonic sorts
__device__ __forceinline__ float bitonic64_desc_f32(float key, int lane) {
#pragma unroll
    for (int k = 2; k <= 64; k <<= 1) {
#pragma unroll
        for (int j = k >> 1; j > 0; j >>= 1) {
            float p = __shfl_xor(key, j);
            bool keepMax = (((lane & j) == 0) == ((lane & k) == 0));
            key = ((key > p) == keepMax) ? key : p;
        }
    }
    return key;
}

__device__ __forceinline__ u64 bitonic64_desc_u64(u64 key, int lane) {
#pragma unroll
    for (int k = 2; k <= 64; k <<= 1) {
#pragma unroll
        for (int j = k >> 1; j > 0; j >>= 1) {
            u64 p = __shfl_xor(key, j);
            bool keepMax = (((lane & j) == 0) == ((lane & k) == 0));
            key = ((key > p) == keepMax) ? key : p;
        }
    }
    return key;
}

// ---------------------------------------------------------------- top-k
__global__ __launch_bounds__(256) void topk_kernel(const float* __restrict__ D,
                                                   const float* __restrict__ sq,
                                                   u16* __restrict__ idx_out, int b0) {
    __shared__ u64 qkey[4][QCAP];
    __shared__ int qn[4];
    int b = b0 + blockIdx.z;
    int w = threadIdx.x >> 6, lane = threadIdx.x & 63;
    int i = blockIdx.x * 4 + w;
    const float* Drow = D + ((size_t)blockIdx.z * NPTS + i) * NPTS;
    const float* sqb = sq + b * NPTS;
    float sqi = sqb[i];
    if (lane == 0) qn[w] = 0;

    float vals[32];
    float mx = -FLT_MAX;
#pragma unroll
    for (int t = 0; t < 8; ++t) {
        int j = t * 256 + lane * 4;
        float4 v4 = *(const float4*)&Drow[j];
        float4 s4 = *(const float4*)&sqb[j];
        float a0 = (2.f * v4.x - sqi - s4.x) + 0.f;
        float a1 = (2.f * v4.y - sqi - s4.y) + 0.f;
        float a2 = (2.f * v4.z - sqi - s4.z) + 0.f;
        float a3 = (2.f * v4.w - sqi - s4.w) + 0.f;
        vals[t * 4 + 0] = a0; vals[t * 4 + 1] = a1;
        vals[t * 4 + 2] = a2; vals[t * 4 + 3] = a3;
        mx = fmaxf(mx, fmaxf(fmaxf(a0, a1), fmaxf(a2, a3)));
    }

    float sm = bitonic64_desc_f32(mx, lane);
    float T0 = __shfl(sm, 19);

#pragma unroll
    for (int t = 0; t < 32; ++t) {
        float v = vals[t];
        if (v >= T0) {
            unsigned j = (unsigned)((t >> 2) * 256 + lane * 4 + (t & 3));
            unsigned bu = __float_as_uint(v);
            unsigned u = (bu & 0x80000000u) ? ~bu : (bu | 0x80000000u);
            u64 key = ((u64)u << 32) | (u64)(0xFFFFFFFFu - j);
            int slot = atomicAdd(&qn[w], 1);
            if (slot < QCAP) qkey[w][slot] = key;
        }
    }
    int C = qn[w];
    if (C > QCAP) C = QCAP;

    u64 key = (lane < C) ? qkey[w][lane] : 0ull;
    key = bitonic64_desc_u64(key, lane);
    int base = 64;
    while (base < C) {
        if (lane >= 20) {
            int src = base + (lane - 20);
            key = (src < C) ? qkey[w][src] : 0ull;
        }
        key = bitonic64_desc_u64(key, lane);
        base += 44;
    }
    if (lane < 20) {
        unsigned j = 0xFFFFFFFFu - (unsigned)(key & 0xFFFFFFFFull);
        idx_out[(size_t)(b * NPTS + i) * KNN + lane] = (u16)j;
    }
}

// ---------------------------------------------------------------- uvb via MFMA split-bf16: UVb[r][n] = X_r · WB_n (+bias for n>=O)
template<int C, int O>
__global__ __launch_bounds__(256) void uvb_mfma_kernel(const u16* __restrict__ XHI,
                                                       const u16* __restrict__ XLO,
                                                       const u16* __restrict__ WHI,
                                                       const u16* __restrict__ WLO,
                                                       const float* __restrict__ bias,
                                                       float* __restrict__ UVA) {
    constexpr int KB = C / 32;
    int b = blockIdx.z;
    int r0 = blockIdx.y * 64, n0 = blockIdx.x * 64;
    int w = threadIdx.x >> 6, lane = threadIdx.x & 63;
    int l15 = lane & 15, g = lane >> 4;
    const u16* Hx = XHI + (size_t)b * NPTS * C;
    const u16* Lx = XLO + (size_t)b * NPTS * C;
    int row_a = r0 + w * 16 + l15;
    short8 ahi[KB], alo[KB];
#pragma unroll
    for (int kb = 0; kb < KB; ++kb) {
        ahi[kb] = *(const short8*)&Hx[(size_t)row_a * C + kb * 32 + g * 8];
        alo[kb] = *(const short8*)&Lx[(size_t)row_a * C + kb * 32 + g * 8];
    }
    float* UVb = UVA + (size_t)b * NPTS * 2 * O;
#pragma unroll
    for (int nt = 0; nt < 4; ++nt) {
        int n = n0 + nt * 16 + l15;
        f32x4 acc = {0.f, 0.f, 0.f, 0.f};
#pragma unroll
        for (int kb = 0; kb < KB; ++kb) {
            short8 bhi = *(const short8*)&WHI[(size_t)n * C + kb * 32 + g * 8];
            short8 blo = *(const short8*)&WLO[(size_t)n * C + kb * 32 + g * 8];
            acc = __builtin_amdgcn_mfma_f32_16x16x32_bf16(ahi[kb], bhi, acc, 0, 0, 0);
            acc = __builtin_amdgcn_mfma_f32_16x16x32_bf16(ahi[kb], blo, acc, 0, 0, 0);
            acc = __builtin_amdgcn_mfma_f32_16x16x32_bf16(alo[kb], bhi, acc, 0, 0, 0);
        }
        float badd = (n >= O) ? bias[n - O] : 0.f;
        int rbase = r0 + w * 16 + g * 4;
#pragma unroll
        for (int r = 0; r < 4; ++r)
            UVb[(size_t)(rbase + r) * (2 * O) + n] = acc[r] + badd;
    }
}

// ---------------------------------------------------------------- f32 uvb (stage 1, C=3)
template<int C, int O>
__global__ __launch_bounds__(256) void uvb_gemm_kernel(const float* __restrict__ X,
                                                       const float* __restrict__ W,
                                                       const float* __restrict__ bias,
                                                       float* __restrict__ UVA) {
    constexpr int KC = (C < 32) ? C : 32;
    __shared__ __align__(16) float As[KC][68];
    __shared__ __align__(16) float Bs[KC][68];
    int b = blockIdx.z;
    int r0 = blockIdx.y * 64, n0 = blockIdx.x * 64;
    int tx = threadIdx.x & 15, ty = threadIdx.x >> 4;
    float acc[4][4] = {};
    for (int c0 = 0; c0 < C; c0 += KC) {
        for (int t = threadIdx.x; t < 64 * KC; t += 256) {
            int i = t / KC, c = t % KC;
            As[c][i] = X[(size_t)(b * NPTS + r0 + i) * C + c0 + c];
            int n = n0 + i;
            float wv;
            if (n < O) wv = W[(size_t)n * (2 * C) + c0 + c];
            else {
                int o = n - O;
                wv = W[(size_t)o * (2 * C) + C + c0 + c] - W[(size_t)o * (2 * C) + c0 + c];
            }
            Bs[c][i] = wv;
        }
        __syncthreads();
#pragma unroll
        for (int c = 0; c < KC; ++c) {
            const float4 av = *(const float4*)&As[c][ty * 4];
            const float4 bv = *(const float4*)&Bs[c][tx * 4];
            float ar[4] = {av.x, av.y, av.z, av.w};
            float br[4] = {bv.x, bv.y, bv.z, bv.w};
#pragma unroll
            for (int r = 0; r < 4; ++r)
#pragma unroll
                for (int q = 0; q < 4; ++q) acc[r][q] = fmaf(ar[r], br[q], acc[r][q]);
        }
        __syncthreads();
    }
    float badd[4] = {0.f, 0.f, 0.f, 0.f};
    if (n0 >= O) {
#pragma unroll
        for (int q = 0; q < 4; ++q) badd[q] = bias[n0 - O + tx * 4 + q];
    }
    float* UVb = UVA + (size_t)b * NPTS * 2 * O;
#pragma unroll
    for (int r = 0; r < 4; ++r) {
        float4 o4 = make_float4(acc[r][0] + badd[0], acc[r][1] + badd[1],
                                acc[r][2] + badd[2], acc[r][3] + badd[3]);
        *(float4*)&UVb[(size_t)(r0 + ty * 4 + r) * (2 * O) + n0 + tx * 4] = o4;
    }
}

// ---------------------------------------------------------------- stats: ONE gather pass -> sums (block partials) + dense HMAX/HMIN
template<int O>
__global__ __launch_bounds__(256) void statsb_kernel(const float* __restrict__ UVA,
                                                     const u16* __restrict__ idx,
                                                     float* __restrict__ PART,
                                                     float* __restrict__ HMAX,
                                                     float* __restrict__ HMIN) {
    constexpr int TPR = O / 4;
    constexpr int RPAR = 256 / TPR;
    constexpr int RPB = NPTS / SB;
    __shared__ float sh[256 * 8];
    int b = blockIdx.z;
    const float* UVb = UVA + (size_t)b * NPTS * 2 * O;
    int otid = threadIdx.x % TPR;
    int o = otid * 4;
    int rsub = threadIdx.x / TPR;
    int rbase = blockIdx.x * RPB;
    float s0 = 0, s1 = 0, s2 = 0, s3 = 0, q0 = 0, q1 = 0, q2 = 0, q3 = 0;
    for (int r = rbase + rsub; r < rbase + RPB; r += RPAR) {
        const float4 v4 = *(const float4*)&UVb[(size_t)r * (2 * O) + O + o];
        const u16* ix = idx + (size_t)(b * NPTS + r) * KNN;
        float mx0 = -FLT_MAX, mx1 = -FLT_MAX, mx2 = -FLT_MAX, mx3 = -FLT_MAX;
        float mn0 = FLT_MAX, mn1 = FLT_MAX, mn2 = FLT_MAX, mn3 = FLT_MAX;
#pragma unroll
        for (int k = 0; k < KNN; ++k) {
            int j = (int)ix[k] & (NPTS - 1);
            const float4 u4 = *(const float4*)&UVb[(size_t)j * (2 * O) + o];
            float h0 = u4.x + v4.x, h1 = u4.y + v4.y, h2 = u4.z + v4.z, h3 = u4.w + v4.w;
            s0 += h0; q0 = fmaf(h0, h0, q0); mx0 = fmaxf(mx0, h0); mn0 = fminf(mn0, h0);
            s1 += h1; q1 = fmaf(h1, h1, q1); mx1 = fmaxf(mx1, h1); mn1 = fminf(mn1, h1);
            s2 += h2; q2 = fmaf(h2, h2, q2); mx2 = fmaxf(mx2, h2); mn2 = fminf(mn2, h2);
            s3 += h3; q3 = fmaf(h3, h3, q3); mx3 = fmaxf(mx3, h3); mn3 = fminf(mn3, h3);
        }
        size_t R = (size_t)(b * NPTS + r) * O + o;
        *(float4*)&HMAX[R] = make_float4(mx0, mx1, mx2, mx3);
        *(float4*)&HMIN[R] = make_float4(mn0, mn1, mn2, mn3);
    }
    float* my = &sh[threadIdx.x * 8];
    my[0] = s0; my[1] = s1; my[2] = s2; my[3] = s3;
    my[4] = q0; my[5] = q1; my[6] = q2; my[7] = q3;
    __syncthreads();
    if (threadIdx.x < TPR) {
        float a[8];
#pragma unroll
        for (int c = 0; c < 8; ++c) a[c] = sh[threadIdx.x * 8 + c];
        for (int g = 1; g < RPAR; ++g) {
            const float* p = &sh[(g * TPR + threadIdx.x) * 8];
#pragma unroll
            for (int c = 0; c < 8; ++c) a[c] += p[c];
        }
        float* dst = &PART[((size_t)b * SB + blockIdx.x) * (2 * O)];
#pragma unroll
        for (int c = 0; c < 4; ++c) { dst[o + c] = a[c]; dst[O + o + c] = a[4 + c]; }
    }
}

template<int O>
__global__ void bnp_kernel(const float* __restrict__ PART, const float* __restrict__ g,
                           const float* __restrict__ beta, float* __restrict__ bnp) {
    int o = threadIdx.x;
    float s = 0.f, ss = 0.f;
    for (int p = 0; p < BATCH * SB; ++p) {
        s += PART[(size_t)p * (2 * O) + o];
        ss += PART[(size_t)p * (2 * O) + O + o];
    }
    const float cnt = (float)NROWS * (float)KNN;
    float m = s / cnt;
    float var = ss / cnt - m * m;
    float sc = g[o] / sqrtf(var + EPSV);
    bnp[o] = sc;
    bnp[O + o] = beta[o] - m * sc;
}

// ---------------------------------------------------------------- apply (stages 1..3): dense elementwise from HMAX/HMIN
template<int O>
__global__ __launch_bounds__(256) void applyb_kernel(const float* __restrict__ HMAX,
                                                     const float* __restrict__ HMIN,
                                                     const float* __restrict__ bnp,
                                                     float* __restrict__ Xn) {
    constexpr int TPR = O / 4;
    int e = blockIdx.x * 256 + threadIdx.x;     // grid = NROWS*TPR/256
    int o = (e % TPR) * 4;
    size_t R = (size_t)(e / TPR) * O + o;
    const float4 hx = *(const float4*)&HMAX[R];
    const float4 hn = *(const float4*)&HMIN[R];
    float4 out;
    { float sc = bnp[o + 0], t = bnp[O + o + 0]; out.x = fmaxf(fmaf(sc, (sc >= 0.f) ? hx.x : hn.x, t), 0.f); }
    { float sc = bnp[o + 1], t = bnp[O + o + 1]; out.y = fmaxf(fmaf(sc, (sc >= 0.f) ? hx.y : hn.y, t), 0.f); }
    { float sc = bnp[o + 2], t = bnp[O + o + 2]; out.z = fmaxf(fmaf(sc, (sc >= 0.f) ? hx.z : hn.z, t), 0.f); }
    { float sc = bnp[o + 3], t = bnp[O + o + 3]; out.w = fmaxf(fmaf(sc, (sc >= 0.f) ? hx.w : hn.w, t), 0.f); }
    *(float4*)&Xn[R] = out;
}

// ---------------------------------------------------------------- stage-4 apply: dense HMAX/HMIN -> point-max -> G0T
__global__ __launch_bounds__(256) void applyb4_kernel(const float* __restrict__ HMAX,
                                                      const float* __restrict__ HMIN,
                                                      const float* __restrict__ bnp,
                                                      float* __restrict__ g0T) {
    constexpr int O = 256;
    constexpr int TPR = O / 4;                  // 64
    constexpr int RPAR = 256 / TPR;             // 4
    constexpr int AB = 32;                      // grid.x
    constexpr int RPB = NPTS / AB;              // 64 rows/block
    __shared__ float sh[256 * 4];
    int b = blockIdx.z;
    int otid = threadIdx.x & (TPR - 1);
    int o = otid * 4;
    int rsub = threadIdx.x >> 6;
    int rbase = blockIdx.x * RPB;
    float sc0 = bnp[o + 0], t0 = bnp[O + o + 0];
    float sc1 = bnp[o + 1], t1 = bnp[O + o + 1];
    float sc2 = bnp[o + 2], t2 = bnp[O + o + 2];
    float sc3 = bnp[o + 3], t3 = bnp[O + o + 3];
    float ym0 = 0.f, ym1 = 0.f, ym2 = 0.f, ym3 = 0.f;
    for (int r = rbase + rsub; r < rbase + RPB; r += RPAR) {
        size_t R = (size_t)(b * NPTS + r) * O + o;
        const float4 hx = *(const float4*)&HMAX[R];
        const float4 hn = *(const float4*)&HMIN[R];
        ym0 = fmaxf(ym0, fmaf(sc0, (sc0 >= 0.f) ? hx.x : hn.x, t0));
        ym1 = fmaxf(ym1, fmaf(sc1, (sc1 >= 0.f) ? hx.y : hn.y, t1));
        ym2 = fmaxf(ym2, fmaf(sc2, (sc2 >= 0.f) ? hx.z : hn.z, t2));
        ym3 = fmaxf(ym3, fmaf(sc3, (sc3 >= 0.f) ? hx.w : hn.w, t3));
    }
    float* my = &sh[threadIdx.x * 4];
    my[0] = ym0; my[1] = ym1; my[2] = ym2; my[3] = ym3;
    __syncthreads();
    if (threadIdx.x < TPR) {
        float a0 = ym0, a1 = ym1, a2 = ym2, a3 = ym3;
        for (int g = 1; g < RPAR; ++g) {
            const float* p = &sh[(g * TPR + threadIdx.x) * 4];
            a0 = fmaxf(a0, p[0]); a1 = fmaxf(a1, p[1]);
            a2 = fmaxf(a2, p[2]); a3 = fmaxf(a3, p[3]);
        }
        a0 = fmaxf(a0, 0.f); a1 = fmaxf(a1, 0.f);
        a2 = fmaxf(a2, 0.f); a3 = fmaxf(a3, 0.f);
        atomicMax((int*)&g0T[(o + 0) * 8 + b], __float_as_int(a0));
        atomicMax((int*)&g0T[(o + 1) * 8 + b], __float_as_int(a1));
        atomicMax((int*)&g0T[(o + 2) * 8 + b], __float_as_int(a2));
        atomicMax((int*)&g0T[(o + 3) * 8 + b], __float_as_int(a3));
    }
}

// ---------------------------------------------------------------- point-max of X2/X3 into G0T channels [256,448)
__global__ __launch_bounds__(256) void gmax23_kernel(const float* __restrict__ X2,
                                                     const float* __restrict__ X3,
                                                     float* __restrict__ g0T) {
    int b = blockIdx.x;
    int n0 = blockIdx.y * 32;                   // grid.y = 64
    int o = threadIdx.x;
    if (o >= 192) return;
    const float* src; int col, stride, ch;
    if (o < 128) { src = X3; col = o;       stride = 128; ch = 256 + o; }
    else         { src = X2; col = o - 128; stride = 64;  ch = 384 + (o - 128); }
    float m = 0.f;
#pragma unroll 8
    for (int n = n0; n < n0 + 32; ++n)
        m = fmaxf(m, src[((size_t)(b * NPTS + n)) * stride + col]);
    atomicMax((int*)&g0T[ch * 8 + b], __float_as_int(m));
}

// ---------------------------------------------------------------- fc weight transpose ([o][c] -> [c][o])
__global__ __launch_bounds__(256) void transpose_kernel(const float* __restrict__ w,
                                                        float* __restrict__ wT, int O, int Cc) {
    int e = blockIdx.x * 256 + threadIdx.x;
    if (e >= O * Cc) return;
    int o = e / Cc, c = e - o * Cc;
    wT[c * O + o] = w[e];
}

// ---------------------------------------------------------------- fc1 + bnf1 + relu
__global__ __launch_bounds__(64) void fc1_kernel(const float* __restrict__ g0T,
                                                 const float* __restrict__ w1T,
                                                 const float* __restrict__ b1,
                                                 const float* __restrict__ bng,
                                                 const float* __restrict__ bnb,
                                                 float* __restrict__ A) {
    int o = blockIdx.x * 64 + threadIdx.x;
    float acc[8] = {};
    for (int c = 0; c < 448; ++c) {
        float wv = w1T[c * 256 + o];
        const float4 h0 = *(const float4*)&g0T[c * 8];
        const float4 h1 = *(const float4*)&g0T[c * 8 + 4];
        acc[0] = fmaf(wv, h0.x, acc[0]); acc[1] = fmaf(wv, h0.y, acc[1]);
        acc[2] = fmaf(wv, h0.z, acc[2]); acc[3] = fmaf(wv, h0.w, acc[3]);
        acc[4] = fmaf(wv, h1.x, acc[4]); acc[5] = fmaf(wv, h1.y, acc[5]);
        acc[6] = fmaf(wv, h1.z, acc[6]); acc[7] = fmaf(wv, h1.w, acc[7]);
    }
    float bb = b1[o];
    float h[8], m = 0.f;
#pragma unroll
    for (int b = 0; b < 8; ++b) { h[b] = acc[b] + bb; m += h[b]; }
    m *= 0.125f;
    float var = 0.f;
#pragma unroll
    for (int b = 0; b < 8; ++b) { float d = h[b] - m; var = fmaf(d, d, var); }
    var *= 0.125f;
    float sc = bng[o] / sqrtf(var + EPSV);
    float t = bnb[o] - m * sc;
#pragma unroll
    for (int b = 0; b < 8; ++b) A[o * 8 + b] = fmaxf(fmaf(sc, h[b], t), 0.f);
}

// ---------------------------------------------------------------- fc2..fc4 tail (one block)
__global__ __launch_bounds__(256) void tail_kernel(const float* __restrict__ A,
                                                   const float* __restrict__ w2T, const float* __restrict__ b2,
                                                   const float* __restrict__ g2, const float* __restrict__ be2,
                                                   const float* __restrict__ w3T, const float* __restrict__ b3,
                                                   const float* __restrict__ g3, const float* __restrict__ be3,
                                                   const float* __restrict__ w4, const float* __restrict__ b4,
                                                   float* __restrict__ out) {
    __shared__ __align__(16) float B2[128 * 8];
    __shared__ __align__(16) float C3[16 * 8];
    int tid = threadIdx.x;
    if (tid < 128) {
        int o = tid;
        float acc[8] = {};
        for (int c = 0; c < 256; ++c) {
            float wv = w2T[c * 128 + o];
            const float4 a0 = *(const float4*)&A[c * 8];
            const float4 a1 = *(const float4*)&A[c * 8 + 4];
            acc[0] = fmaf(wv, a0.x, acc[0]); acc[1] = fmaf(wv, a0.y, acc[1]);
            acc[2] = fmaf(wv, a0.z, acc[2]); acc[3] = fmaf(wv, a0.w, acc[3]);
            acc[4] = fmaf(wv, a1.x, acc[4]); acc[5] = fmaf(wv, a1.y, acc[5]);
            acc[6] = fmaf(wv, a1.z, acc[6]); acc[7] = fmaf(wv, a1.w, acc[7]);
        }
        float bb = b2[o];
        float h[8], m = 0.f;
#pragma unroll
        for (int b = 0; b < 8; ++b) { h[b] = acc[b] + bb; m += h[b]; }
        m *= 0.125f;
        float var = 0.f;
#pragma unroll
        for (int b = 0; b < 8; ++b) { float d = h[b] - m; var = fmaf(d, d, var); }
        var *= 0.125f;
        float sc = g2[o] / sqrtf(var + EPSV);
        float t = be2[o] - m * sc;
#pragma unroll
        for (int b = 0; b < 8; ++b) B2[o * 8 + b] = fmaxf(fmaf(sc, h[b], t), 0.f);
    }
    __syncthreads();
    if (tid < 16) {
        int o = tid;
        float acc[8] = {};
        for (int c = 0; c < 128; ++c) {
            float wv = w3T[c * 16 + o];
            const float4 a0 = *(const float4*)&B2[c * 8];
            const float4 a1 = *(const float4*)&B2[c * 8 + 4];
            acc[0] = fmaf(wv, a0.x, acc[0]); acc[1] = fmaf(wv, a0.y, acc[1]);
            acc[2] = fmaf(wv, a0.z, acc[2]); acc[3] = fmaf(wv, a0.w, acc[3]);
            acc[4] = fmaf(wv, a1.x, acc[4]); acc[5] = fmaf(wv, a1.y, acc[5]);
            acc[6] = fmaf(wv, a1.z, acc[6]); acc[7] = fmaf(wv, a1.w, acc[7]);
        }
        float bb = b3[o];
        float h[8], m = 0.f;
#pragma unroll
        for (int b = 0; b < 8; ++b) { h[b] = acc[b] + bb; m += h[b]; }
        m *= 0.125f;
        float var = 0.f;
#pragma unroll
        for (int b = 0; b < 8; ++b) { float d = h[b] - m; var = fmaf(d, d, var); }
        var *= 0.125f;
        float sc = g3[o] / sqrtf(var + EPSV);
        float t = be3[o] - m * sc;
#pragma unroll
        for (int b = 0; b < 8; ++b) C3[o * 8 + b] = fmaxf(fmaf(sc, h[b], t), 0.f);
    }
    __syncthreads();
    if (tid < 8) {
        int b = tid;
        float acc = b4[0];
#pragma unroll
        for (int c = 0; c < 16; ++c) acc = fmaf(w4[c], C3[c * 8 + b], acc);
        out[b] = acc;
    }
}

// ================================================================ host side
struct Arena {
    char* base; size_t off, cap; bool ok;
    Arena(void* b, size_t c) : base((char*)b), off(0), cap(c), ok(true) {}
    void* get(size_t bytes) {
        char* p = base + off;
        off += (bytes + 255) & ~(size_t)255;
        if (off > cap) ok = false;
        return p;
    }
};

// one EdgeConv stage, output stored to Xout (stages 1..3)
template<int C, int O>
static void run_stage(const float* Xin, float* Xout, const float* W, const float* bias,
                      const float* g, const float* be, float* SCR, float* UVA,
                      u16* XHI, u16* XLO, u16* WHI, u16* WLO,
                      u16* IDX, float* SQ, float* PART, float* BNP, hipStream_t s) {
    dim3 blk(256);
    float* HMAX = SCR;
    float* HMIN = SCR + (size_t)NROWS * O;
    sqnorm_kernel<C><<<NROWS / 256, blk, 0, s>>>(Xin, SQ);
    if constexpr (C >= 32) {
        split_kernel<C><<<NROWS * C / 1024, blk, 0, s>>>(Xin, XHI, XLO);
        for (int b0 = 0; b0 < BATCH; b0 += 2) {
            dist_mfma_kernel<C><<<dim3(NPTS / 64, NPTS / 64, 2), blk, 0, s>>>(XHI, XLO, SCR, b0);
            topk_kernel<<<dim3(NPTS / 4, 1, 2), blk, 0, s>>>(SCR, SQ, IDX, b0);
        }
        wsplit_kernel<C, O><<<(2 * O * C + 255) / 256, blk, 0, s>>>(W, WHI, WLO);
        uvb_mfma_kernel<C, O><<<dim3(2 * O / 64, NPTS / 64, BATCH), blk, 0, s>>>(XHI, XLO, WHI, WLO, bias, UVA);
    } else {
        for (int b0 = 0; b0 < BATCH; b0 += 2) {
            dist_gemm_kernel<C><<<dim3(NPTS / 64, NPTS / 64, 2), blk, 0, s>>>(Xin, SCR, b0);
            topk_kernel<<<dim3(NPTS / 4, 1, 2), blk, 0, s>>>(SCR, SQ, IDX, b0);
        }
        uvb_gemm_kernel<C, O><<<dim3(2 * O / 64, NPTS / 64, BATCH), blk, 0, s>>>(Xin, W, bias, UVA);
    }
    statsb_kernel<O><<<dim3(SB, 1, BATCH), blk, 0, s>>>(UVA, IDX, PART, HMAX, HMIN);
    bnp_kernel<O><<<1, O, 0, s>>>(PART, g, be, BNP);
    applyb_kernel<O><<<NROWS * (O / 4) / 256, blk, 0, s>>>(HMAX, HMIN, BNP, Xout);
}

// stage 4: point-max fused into G0T (no X4 buffer)
static void run_stage4(const float* Xin, const float* W, const float* bias,
                       const float* g, const float* be, float* SCR, float* UVA,
                       u16* XHI, u16* XLO, u16* WHI, u16* WLO,
                       u16* IDX, float* SQ, float* PART, float* BNP, float* G0T,
                       hipStream_t s) {
    constexpr int C = 128;
    dim3 blk(256);
    float* HMAX = SCR;
    float* HMIN = SCR + (size_t)NROWS * 256;
    sqnorm_kernel<C><<<NROWS / 256, blk, 0, s>>>(Xin, SQ);
    split_kernel<C><<<NROWS * C / 1024, blk, 0, s>>>(Xin, XHI, XLO);
    for (int b0 = 0; b0 < BATCH; b0 += 2) {
        dist_mfma_kernel<C><<<dim3(NPTS / 64, NPTS / 64, 2), blk, 0, s>>>(XHI, XLO, SCR, b0);
        topk_kernel<<<dim3(NPTS / 4, 1, 2), blk, 0, s>>>(SCR, SQ, IDX, b0);
    }
    wsplit_kernel<C, 256><<<(512 * C + 255) / 256, blk, 0, s>>>(W, WHI, WLO);
    uvb_mfma_kernel<C, 256><<<dim3(8, NPTS / 64, BATCH), blk, 0, s>>>(XHI, XLO, WHI, WLO, bias, UVA);
    statsb_kernel<256><<<dim3(SB, 1, BATCH), blk, 0, s>>>(UVA, IDX, PART, HMAX, HMIN);
    bnp_kernel<256><<<1, 256, 0, s>>>(PART, g, be, BNP);
    fill_zero_kernel<<<14, blk, 0, s>>>(G0T, 448 * 8);
    applyb4_kernel<<<dim3(32, 1, BATCH), blk, 0, s>>>(HMAX, HMIN, BNP, G0T);
}

extern "C" void kernel_launch(void* const* d_in, const int* in_sizes, int n_in,
                              void* d_out, int out_size, void* d_ws, size_t ws_size,
                              hipStream_t stream) {
    float* out = (float*)d_out;
    if (n_in < 31) { diag_kernel<<<1, 64, 0, stream>>>(out, 9000.f); return; }

    const float* x       = (const float*)d_in[0];
    const float* cw[4]   = {(const float*)d_in[1], (const float*)d_in[5], (const float*)d_in[9],  (const float*)d_in[13]};
    const float* cb[4]   = {(const float*)d_in[2], (const float*)d_in[6], (const float*)d_in[10], (const float*)d_in[14]};
    const float* bg[4]   = {(const float*)d_in[3], (const float*)d_in[7], (const float*)d_in[11], (const float*)d_in[15]};
    const float* bb[4]   = {(const float*)d_in[4], (const float*)d_in[8], (const float*)d_in[12], (const float*)d_in[16]};
    const float* fc1_w = (const float*)d_in[17]; const float* fc1_b = (const float*)d_in[18];
    const float* bnf1_g = (const float*)d_in[19]; const float* bnf1_b = (const float*)d_in[20];
    const float* fc2_w = (const float*)d_in[21]; const float* fc2_b = (const float*)d_in[22];
    const float* bnf2_g = (const float*)d_in[23]; const float* bnf2_b = (const float*)d_in[24];
    const float* fc3_w = (const float*)d_in[25]; const float* fc3_b = (const float*)d_in[26];
    const float* bnf3_g = (const float*)d_in[27]; const float* bnf3_b = (const float*)d_in[28];
    const float* fc4_w = (const float*)d_in[29]; const float* fc4_b = (const float*)d_in[30];

    Arena ar(d_ws, ws_size);
    float* X1 = (float*)ar.get((size_t)NROWS * 64 * 4);
    float* X2 = (float*)ar.get((size_t)NROWS * 64 * 4);
    float* X3 = (float*)ar.get((size_t)NROWS * 128 * 4);
    u16* IDX = (u16*)ar.get((size_t)NROWS * KNN * 2);
    float* SQ = (float*)ar.get((size_t)NROWS * 4);
    float* PART = (float*)ar.get((size_t)BATCH * SB * 512 * 4);   // 1 MB
    float* BNP = (float*)ar.get(512 * 4);
    float* G0T = (float*)ar.get(448 * 8 * 4);
    float* ABUF = (float*)ar.get(256 * 8 * 4);
    u16* XHI = (u16*)ar.get((size_t)NROWS * 128 * 2);             // 4 MB (max C = 128)
    u16* XLO = (u16*)ar.get((size_t)NROWS * 128 * 2);             // 4 MB
    u16* WHI = (u16*)ar.get(512 * 128 * 2);                       // 128 KB (max 2O x C)
    u16* WLO = (u16*)ar.get(512 * 128 * 2);
    float* SCR = (float*)ar.get((size_t)2 * NPTS * NPTS * 4);     // DIST x2 / HMAX+HMIN / W-transposes (32 MB)
    float* UVA = (float*)ar.get((size_t)NROWS * 512 * 4);         // UV all batches, worst O=256 (32 MB)
    if (!ar.ok) {
        diag_kernel<<<1, 64, 0, stream>>>(out, 3000.f + (float)(ws_size >> 20));
        return;
    }

    dim3 blk(256);
    run_stage<3, 64>(x, X1, cw[0], cb[0], bg[0], bb[0], SCR, UVA, XHI, XLO, WHI, WLO, IDX, SQ, PART, BNP, stream);
    run_stage<64, 64>(X1, X2, cw[1], cb[1], bg[1], bb[1], SCR, UVA, XHI, XLO, WHI, WLO, IDX, SQ, PART, BNP, stream);
    run_stage<64, 128>(X2, X3, cw[2], cb[2], bg[2], bb[2], SCR, UVA, XHI, XLO, WHI, WLO, IDX, SQ, PART, BNP, stream);
    run_stage4(X3, cw[3], cb[3], bg[3], bb[3], SCR, UVA, XHI, XLO, WHI, WLO, IDX, SQ, PART, BNP, G0T, stream);

    gmax23_kernel<<<dim3(BATCH, 64), blk, 0, stream>>>(X2, X3, G0T);

    float* W1T = SCR;                            // head reuses SCR (HMAX/HMIN dead now)
    float* W2T = W1T + 448 * 256;
    float* W3T = W2T + 256 * 128;
    transpose_kernel<<<(256 * 448 + 255) / 256, blk, 0, stream>>>(fc1_w, W1T, 256, 448);
    transpose_kernel<<<(128 * 256 + 255) / 256, blk, 0, stream>>>(fc2_w, W2T, 128, 256);
    transpose_kernel<<<(16 * 128 + 255) / 256, blk, 0, stream>>>(fc3_w, W3T, 16, 128);
    fc1_kernel<<<4, 64, 0, stream>>>(G0T, W1T, fc1_b, bnf1_g, bnf1_b, ABUF);
    tail_kernel<<<1, 256, 0, stream>>>(ABUF, W2T, fc2_b, bnf2_g, bnf2_b,
                                       W3T, fc3_b, bnf3_g, bnf3_b, fc4_w, fc4_b, out);
}

// Round 12
// 892.735 us; speedup vs baseline: 8.0781x; 1.1507x over previous
//
#include <hip/hip_runtime.h>
#include <hip/hip_bf16.h>
#include <cfloat>

constexpr int BATCH = 8, NPTS = 2048, KNN = 20;
constexpr int NROWS = BATCH * NPTS;
constexpr float EPSV = 1e-5f;
constexpr int QCAP = 512;
constexpr int SB = 256;                          // statsb blocks per batch (2048 total = full fill)
constexpr int PR = 64;                           // reduced partials

using u16 = unsigned short;
using u64 = unsigned long long;
typedef __attribute__((ext_vector_type(8))) short short8;
typedef __attribute__((ext_vector_type(4))) float f32x4;

// ---------------------------------------------------------------- diag / fill
__global__ void diag_kernel(float* out, float v) {
    if (threadIdx.x < 8) out[threadIdx.x] = v;
}

__global__ __launch_bounds__(256) void fill_zero_kernel(float* __restrict__ p, int n) {
    int i = blockIdx.x * 256 + threadIdx.x;
    if (i < n) p[i] = 0.f;
}

// ---------------------------------------------------------------- sqnorm over all rows
template<int C>
__global__ __launch_bounds__(256) void sqnorm_kernel(const float* __restrict__ X,
                                                     float* __restrict__ sq) {
    int r = blockIdx.x * 256 + threadIdx.x;     // grid = NROWS/256
    const float* x = X + (size_t)r * C;
    float s = 0.f;
#pragma unroll
    for (int c = 0; c < C; ++c) { float v = x[c]; s = fmaf(v, v, s); }
    sq[r] = s;
}

// ---------------------------------------------------------------- split X (f32) -> hi/lo bf16
template<int C>
__global__ __launch_bounds__(256) void split_kernel(const float* __restrict__ X,
                                                    u16* __restrict__ XHI,
                                                    u16* __restrict__ XLO) {
    int e = blockIdx.x * 256 + threadIdx.x;     // grid = NROWS*C/1024, float4 per thread
    const float4 v = *(const float4*)&X[(size_t)e * 4];
    float vv[4] = {v.x, v.y, v.z, v.w};
    u16 h[4], l[4];
#pragma unroll
    for (int q = 0; q < 4; ++q) {
        __hip_bfloat16 hb = __float2bfloat16(vv[q]);
        float hf = __bfloat162float(hb);
        __hip_bfloat16 lb = __float2bfloat16(vv[q] - hf);
        h[q] = *(u16*)&hb; l[q] = *(u16*)&lb;
    }
    *(ushort4*)&XHI[(size_t)e * 4] = make_ushort4(h[0], h[1], h[2], h[3]);
    *(ushort4*)&XLO[(size_t)e * 4] = make_ushort4(l[0], l[1], l[2], l[3]);
}

// ---------------------------------------------------------------- split W -> WB[n][c] hi/lo (n<O: W1; n>=O: W2-W1), bf16
template<int C, int O>
__global__ __launch_bounds__(256) void wsplit_kernel(const float* __restrict__ W,
                                                     u16* __restrict__ WHI,
                                                     u16* __restrict__ WLO) {
    int e = blockIdx.x * 256 + threadIdx.x;
    if (e >= 2 * O * C) return;
    int n = e / C, c = e - n * C;
    float wv = (n < O) ? W[(size_t)n * (2 * C) + c]
                       : W[(size_t)(n - O) * (2 * C) + C + c] - W[(size_t)(n - O) * (2 * C) + c];
    __hip_bfloat16 hb = __float2bfloat16(wv);
    float hf = __bfloat162float(hb);
    __hip_bfloat16 lb = __float2bfloat16(wv - hf);
    WHI[e] = *(u16*)&hb;
    WLO[e] = *(u16*)&lb;
}

// ---------------------------------------------------------------- MFMA dist: D[z][i][j] = x_i · x_j via split-bf16 (hh + hl + lh)
template<int C>
__global__ __launch_bounds__(256) void dist_mfma_kernel(const u16* __restrict__ XHI,
                                                        const u16* __restrict__ XLO,
                                                        float* __restrict__ D, int b0) {
    constexpr int KB = C / 32;
    int b = b0 + blockIdx.z;
    int i0 = blockIdx.y * 64, j0 = blockIdx.x * 64;
    int w = threadIdx.x >> 6, lane = threadIdx.x & 63;
    int l15 = lane & 15, g = lane >> 4;
    const u16* Hb = XHI + (size_t)b * NPTS * C;
    const u16* Lb = XLO + (size_t)b * NPTS * C;
    int row_a = i0 + w * 16 + l15;
    short8 ahi[KB], alo[KB];
#pragma unroll
    for (int kb = 0; kb < KB; ++kb) {
        ahi[kb] = *(const short8*)&Hb[(size_t)row_a * C + kb * 32 + g * 8];
        alo[kb] = *(const short8*)&Lb[(size_t)row_a * C + kb * 32 + g * 8];
    }
    float* Dz = D + (size_t)blockIdx.z * NPTS * NPTS;
#pragma unroll
    for (int nt = 0; nt < 4; ++nt) {
        int row_b = j0 + nt * 16 + l15;
        f32x4 acc = {0.f, 0.f, 0.f, 0.f};
#pragma unroll
        for (int kb = 0; kb < KB; ++kb) {
            short8 bhi = *(const short8*)&Hb[(size_t)row_b * C + kb * 32 + g * 8];
            short8 blo = *(const short8*)&Lb[(size_t)row_b * C + kb * 32 + g * 8];
            acc = __builtin_amdgcn_mfma_f32_16x16x32_bf16(ahi[kb], bhi, acc, 0, 0, 0);
            acc = __builtin_amdgcn_mfma_f32_16x16x32_bf16(ahi[kb], blo, acc, 0, 0, 0);
            acc = __builtin_amdgcn_mfma_f32_16x16x32_bf16(alo[kb], bhi, acc, 0, 0, 0);
        }
        int col = j0 + nt * 16 + l15;
        int rbase = i0 + w * 16 + g * 4;
#pragma unroll
        for (int r = 0; r < 4; ++r)
            Dz[(size_t)(rbase + r) * NPTS + col] = acc[r];
    }
}

// ---------------------------------------------------------------- f32 dist GEMM (stage 1, C=3 only)
template<int C>
__global__ __launch_bounds__(256) void dist_gemm_kernel(const float* __restrict__ X,
                                                        float* __restrict__ D, int b0) {
    constexpr int KC = (C < 32) ? C : 32;
    __shared__ __align__(16) float As[KC][68];
    __shared__ __align__(16) float Bs[KC][68];
    int b = b0 + blockIdx.z;
    int i0 = blockIdx.y * 64, j0 = blockIdx.x * 64;
    const float* Xb = X + (size_t)b * NPTS * C;
    int tx = threadIdx.x & 15, ty = threadIdx.x >> 4;
    float acc[4][4] = {};
    for (int c0 = 0; c0 < C; c0 += KC) {
        for (int t = threadIdx.x; t < 64 * KC; t += 256) {
            int i = t / KC, c = t % KC;
            As[c][i] = Xb[(size_t)(i0 + i) * C + c0 + c];
            Bs[c][i] = Xb[(size_t)(j0 + i) * C + c0 + c];
        }
        __syncthreads();
#pragma unroll
        for (int c = 0; c < KC; ++c) {
            const float4 av = *(const float4*)&As[c][ty * 4];
            const float4 bv = *(const float4*)&Bs[c][tx * 4];
            float ar[4] = {av.x, av.y, av.z, av.w};
            float br[4] = {bv.x, bv.y, bv.z, bv.w};
#pragma unroll
            for (int r = 0; r < 4; ++r)
#pragma unroll
                for (int q = 0; q < 4; ++q) acc[r][q] = fmaf(ar[r], br[q], acc[r][q]);
        }
        __syncthreads();
    }
    float* Dz = D + (size_t)blockIdx.z * NPTS * NPTS;
#pragma unroll
    for (int r = 0; r < 4; ++r) {
        float4 o4 = make_float4(acc[r][0], acc[r][1], acc[r][2], acc[r][3]);
        *(float4*)&Dz[(size_t)(i0 + ty * 4 + r) * NPTS + j0 + tx * 4] = o4;
    }
}

// ---------------------------------------------------------------- wave-64 bitonic sorts
__device__ __forceinline__ float bitonic64_desc_f32(float key, int lane) {
#pragma unroll
    for (int k = 2; k <= 64; k <<= 1) {
#pragma unroll
        for (int j = k >> 1; j > 0; j >>= 1) {
            float p = __shfl_xor(key, j);
            bool keepMax = (((lane & j) == 0) == ((lane & k) == 0));
            key = ((key > p) == keepMax) ? key : p;
        }
    }
    return key;
}

__device__ __forceinline__ u64 bitonic64_desc_u64(u64 key, int lane) {
#pragma unroll
    for (int k = 2; k <= 64; k <<= 1) {
#pragma unroll
        for (int j = k >> 1; j > 0; j >>= 1) {
            u64 p = __shfl_xor(key, j);
            bool keepMax = (((lane & j) == 0) == ((lane & k) == 0));
            key = ((key > p) == keepMax) ? key : p;
        }
    }
    return key;
}

// ---------------------------------------------------------------- top-k
__global__ __launch_bounds__(256) void topk_kernel(const float* __restrict__ D,
                                                   const float* __restrict__ sq,
                                                   u16* __restrict__ idx_out, int b0) {
    __shared__ u64 qkey[4][QCAP];
    __shared__ int qn[4];
    int b = b0 + blockIdx.z;
    int w = threadIdx.x >> 6, lane = threadIdx.x & 63;
    int i = blockIdx.x * 4 + w;
    const float* Drow = D + ((size_t)blockIdx.z * NPTS + i) * NPTS;
    const float* sqb = sq + b * NPTS;
    float sqi = sqb[i];
    if (lane == 0) qn[w] = 0;

    float vals[32];
    float mx = -FLT_MAX;
#pragma unroll
    for (int t = 0; t < 8; ++t) {
        int j = t * 256 + lane * 4;
        float4 v4 = *(const float4*)&Drow[j];
        float4 s4 = *(const float4*)&sqb[j];
        float a0 = (2.f * v4.x - sqi - s4.x) + 0.f;
        float a1 = (2.f * v4.y - sqi - s4.y) + 0.f;
        float a2 = (2.f * v4.z - sqi - s4.z) + 0.f;
        float a3 = (2.f * v4.w - sqi - s4.w) + 0.f;
        vals[t * 4 + 0] = a0; vals[t * 4 + 1] = a1;
        vals[t * 4 + 2] = a2; vals[t * 4 + 3] = a3;
        mx = fmaxf(mx, fmaxf(fmaxf(a0, a1), fmaxf(a2, a3)));
    }

    float sm = bitonic64_desc_f32(mx, lane);
    float T0 = __shfl(sm, 19);

#pragma unroll
    for (int t = 0; t < 32; ++t) {
        float v = vals[t];
        if (v >= T0) {
            unsigned j = (unsigned)((t >> 2) * 256 + lane * 4 + (t & 3));
            unsigned bu = __float_as_uint(v);
            unsigned u = (bu & 0x80000000u) ? ~bu : (bu | 0x80000000u);
            u64 key = ((u64)u << 32) | (u64)(0xFFFFFFFFu - j);
            int slot = atomicAdd(&qn[w], 1);
            if (slot < QCAP) qkey[w][slot] = key;
        }
    }
    int C = qn[w];
    if (C > QCAP) C = QCAP;

    u64 key = (lane < C) ? qkey[w][lane] : 0ull;
    key = bitonic64_desc_u64(key, lane);
    int base = 64;
    while (base < C) {
        if (lane >= 20) {
            int src = base + (lane - 20);
            key = (src < C) ? qkey[w][src] : 0ull;
        }
        key = bitonic64_desc_u64(key, lane);
        base += 44;
    }
    if (lane < 20) {
        unsigned j = 0xFFFFFFFFu - (unsigned)(key & 0xFFFFFFFFull);
        idx_out[(size_t)(b * NPTS + i) * KNN + lane] = (u16)j;
    }
}

// ---------------------------------------------------------------- uvb via MFMA split-bf16
template<int C, int O>
__global__ __launch_bounds__(256) void uvb_mfma_kernel(const u16* __restrict__ XHI,
                                                       const u16* __restrict__ XLO,
                                                       const u16* __restrict__ WHI,
                                                       const u16* __restrict__ WLO,
                                                       const float* __restrict__ bias,
                                                       float* __restrict__ UVA) {
    constexpr int KB = C / 32;
    int b = blockIdx.z;
    int r0 = blockIdx.y * 64, n0 = blockIdx.x * 64;
    int w = threadIdx.x >> 6, lane = threadIdx.x & 63;
    int l15 = lane & 15, g = lane >> 4;
    const u16* Hx = XHI + (size_t)b * NPTS * C;
    const u16* Lx = XLO + (size_t)b * NPTS * C;
    int row_a = r0 + w * 16 + l15;
    short8 ahi[KB], alo[KB];
#pragma unroll
    for (int kb = 0; kb < KB; ++kb) {
        ahi[kb] = *(const short8*)&Hx[(size_t)row_a * C + kb * 32 + g * 8];
        alo[kb] = *(const short8*)&Lx[(size_t)row_a * C + kb * 32 + g * 8];
    }
    float* UVb = UVA + (size_t)b * NPTS * 2 * O;
#pragma unroll
    for (int nt = 0; nt < 4; ++nt) {
        int n = n0 + nt * 16 + l15;
        f32x4 acc = {0.f, 0.f, 0.f, 0.f};
#pragma unroll
        for (int kb = 0; kb < KB; ++kb) {
            short8 bhi = *(const short8*)&WHI[(size_t)n * C + kb * 32 + g * 8];
            short8 blo = *(const short8*)&WLO[(size_t)n * C + kb * 32 + g * 8];
            acc = __builtin_amdgcn_mfma_f32_16x16x32_bf16(ahi[kb], bhi, acc, 0, 0, 0);
            acc = __builtin_amdgcn_mfma_f32_16x16x32_bf16(ahi[kb], blo, acc, 0, 0, 0);
            acc = __builtin_amdgcn_mfma_f32_16x16x32_bf16(alo[kb], bhi, acc, 0, 0, 0);
        }
        float badd = (n >= O) ? bias[n - O] : 0.f;
        int rbase = r0 + w * 16 + g * 4;
#pragma unroll
        for (int r = 0; r < 4; ++r)
            UVb[(size_t)(rbase + r) * (2 * O) + n] = acc[r] + badd;
    }
}

// ---------------------------------------------------------------- f32 uvb (stage 1, C=3)
template<int C, int O>
__global__ __launch_bounds__(256) void uvb_gemm_kernel(const float* __restrict__ X,
                                                       const float* __restrict__ W,
                                                       const float* __restrict__ bias,
                                                       float* __restrict__ UVA) {
    constexpr int KC = (C < 32) ? C : 32;
    __shared__ __align__(16) float As[KC][68];
    __shared__ __align__(16) float Bs[KC][68];
    int b = blockIdx.z;
    int r0 = blockIdx.y * 64, n0 = blockIdx.x * 64;
    int tx = threadIdx.x & 15, ty = threadIdx.x >> 4;
    float acc[4][4] = {};
    for (int c0 = 0; c0 < C; c0 += KC) {
        for (int t = threadIdx.x; t < 64 * KC; t += 256) {
            int i = t / KC, c = t % KC;
            As[c][i] = X[(size_t)(b * NPTS + r0 + i) * C + c0 + c];
            int n = n0 + i;
            float wv;
            if (n < O) wv = W[(size_t)n * (2 * C) + c0 + c];
            else {
                int o = n - O;
                wv = W[(size_t)o * (2 * C) + C + c0 + c] - W[(size_t)o * (2 * C) + c0 + c];
            }
            Bs[c][i] = wv;
        }
        __syncthreads();
#pragma unroll
        for (int c = 0; c < KC; ++c) {
            const float4 av = *(const float4*)&As[c][ty * 4];
            const float4 bv = *(const float4*)&Bs[c][tx * 4];
            float ar[4] = {av.x, av.y, av.z, av.w};
            float br[4] = {bv.x, bv.y, bv.z, bv.w};
#pragma unroll
            for (int r = 0; r < 4; ++r)
#pragma unroll
                for (int q = 0; q < 4; ++q) acc[r][q] = fmaf(ar[r], br[q], acc[r][q]);
        }
        __syncthreads();
    }
    float badd[4] = {0.f, 0.f, 0.f, 0.f};
    if (n0 >= O) {
#pragma unroll
        for (int q = 0; q < 4; ++q) badd[q] = bias[n0 - O + tx * 4 + q];
    }
    float* UVb = UVA + (size_t)b * NPTS * 2 * O;
#pragma unroll
    for (int r = 0; r < 4; ++r) {
        float4 o4 = make_float4(acc[r][0] + badd[0], acc[r][1] + badd[1],
                                acc[r][2] + badd[2], acc[r][3] + badd[3]);
        *(float4*)&UVb[(size_t)(r0 + ty * 4 + r) * (2 * O) + n0 + tx * 4] = o4;
    }
}

// ---------------------------------------------------------------- stats: ONE gather pass -> block partials + dense HMAX/HMIN
template<int O>
__global__ __launch_bounds__(256) void statsb_kernel(const float* __restrict__ UVA,
                                                     const u16* __restrict__ idx,
                                                     float* __restrict__ PART,
                                                     float* __restrict__ HMAX,
                                                     float* __restrict__ HMIN) {
    constexpr int TPR = O / 4;
    constexpr int RPAR = 256 / TPR;
    constexpr int RPB = NPTS / SB;              // 8 rows/block
    __shared__ float sh[256 * 8];
    int b = blockIdx.z;
    const float* UVb = UVA + (size_t)b * NPTS * 2 * O;
    int otid = threadIdx.x % TPR;
    int o = otid * 4;
    int rsub = threadIdx.x / TPR;
    int rbase = blockIdx.x * RPB;
    float s0 = 0, s1 = 0, s2 = 0, s3 = 0, q0 = 0, q1 = 0, q2 = 0, q3 = 0;
    for (int r = rbase + rsub; r < rbase + RPB; r += RPAR) {
        const float4 v4 = *(const float4*)&UVb[(size_t)r * (2 * O) + O + o];
        const u16* ix = idx + (size_t)(b * NPTS + r) * KNN;
        float mx0 = -FLT_MAX, mx1 = -FLT_MAX, mx2 = -FLT_MAX, mx3 = -FLT_MAX;
        float mn0 = FLT_MAX, mn1 = FLT_MAX, mn2 = FLT_MAX, mn3 = FLT_MAX;
#pragma unroll
        for (int k = 0; k < KNN; ++k) {
            int j = (int)ix[k] & (NPTS - 1);
            const float4 u4 = *(const float4*)&UVb[(size_t)j * (2 * O) + o];
            float h0 = u4.x + v4.x, h1 = u4.y + v4.y, h2 = u4.z + v4.z, h3 = u4.w + v4.w;
            s0 += h0; q0 = fmaf(h0, h0, q0); mx0 = fmaxf(mx0, h0); mn0 = fminf(mn0, h0);
            s1 += h1; q1 = fmaf(h1, h1, q1); mx1 = fmaxf(mx1, h1); mn1 = fminf(mn1, h1);
            s2 += h2; q2 = fmaf(h2, h2, q2); mx2 = fmaxf(mx2, h2); mn2 = fminf(mn2, h2);
            s3 += h3; q3 = fmaf(h3, h3, q3); mx3 = fmaxf(mx3, h3); mn3 = fminf(mn3, h3);
        }
        size_t R = (size_t)(b * NPTS + r) * O + o;
        *(float4*)&HMAX[R] = make_float4(mx0, mx1, mx2, mx3);
        *(float4*)&HMIN[R] = make_float4(mn0, mn1, mn2, mn3);
    }
    float* my = &sh[threadIdx.x * 8];
    my[0] = s0; my[1] = s1; my[2] = s2; my[3] = s3;
    my[4] = q0; my[5] = q1; my[6] = q2; my[7] = q3;
    __syncthreads();
    if (threadIdx.x < TPR) {
        float a[8];
#pragma unroll
        for (int c = 0; c < 8; ++c) a[c] = sh[threadIdx.x * 8 + c];
        for (int g = 1; g < RPAR; ++g) {
            const float* p = &sh[(g * TPR + threadIdx.x) * 8];
#pragma unroll
            for (int c = 0; c < 8; ++c) a[c] += p[c];
        }
        float* dst = &PART[((size_t)b * SB + blockIdx.x) * (2 * O)];
#pragma unroll
        for (int c = 0; c < 4; ++c) { dst[o + c] = a[c]; dst[O + o + c] = a[4 + c]; }
    }
}

// ---------------------------------------------------------------- PART (BATCH*SB rows) -> PART2 (PR rows)
template<int O>
__global__ __launch_bounds__(256) void part_reduce_kernel(const float* __restrict__ PART,
                                                          float* __restrict__ PART2) {
    constexpr int ROWS = BATCH * SB;            // 2048
    constexpr int RPG = ROWS / PR;              // 32 rows per output
    int g = blockIdx.x;                          // grid = PR
    for (int col = threadIdx.x; col < 2 * O; col += 256) {
        float s = 0.f;
        for (int r = 0; r < RPG; ++r)
            s += PART[(size_t)(g * RPG + r) * (2 * O) + col];
        PART2[(size_t)g * (2 * O) + col] = s;
    }
}

template<int O>
__global__ void bnp_kernel(const float* __restrict__ PART2, const float* __restrict__ g,
                           const float* __restrict__ beta, float* __restrict__ bnp) {
    int o = threadIdx.x;
    float s = 0.f, ss = 0.f;
    for (int p = 0; p < PR; ++p) {
        s += PART2[(size_t)p * (2 * O) + o];
        ss += PART2[(size_t)p * (2 * O) + O + o];
    }
    const float cnt = (float)NROWS * (float)KNN;
    float m = s / cnt;
    float var = ss / cnt - m * m;
    float sc = g[o] / sqrtf(var + EPSV);
    bnp[o] = sc;
    bnp[O + o] = beta[o] - m * sc;
}

// ---------------------------------------------------------------- apply (stages 1..3): dense elementwise from HMAX/HMIN
template<int O>
__global__ __launch_bounds__(256) void applyb_kernel(const float* __restrict__ HMAX,
                                                     const float* __restrict__ HMIN,
                                                     const float* __restrict__ bnp,
                                                     float* __restrict__ Xn) {
    constexpr int TPR = O / 4;
    int e = blockIdx.x * 256 + threadIdx.x;     // grid = NROWS*TPR/256
    int o = (e % TPR) * 4;
    size_t R = (size_t)(e / TPR) * O + o;
    const float4 hx = *(const float4*)&HMAX[R];
    const float4 hn = *(const float4*)&HMIN[R];
    float4 out;
    { float sc = bnp[o + 0], t = bnp[O + o + 0]; out.x = fmaxf(fmaf(sc, (sc >= 0.f) ? hx.x : hn.x, t), 0.f); }
    { float sc = bnp[o + 1], t = bnp[O + o + 1]; out.y = fmaxf(fmaf(sc, (sc >= 0.f) ? hx.y : hn.y, t), 0.f); }
    { float sc = bnp[o + 2], t = bnp[O + o + 2]; out.z = fmaxf(fmaf(sc, (sc >= 0.f) ? hx.z : hn.z, t), 0.f); }
    { float sc = bnp[o + 3], t = bnp[O + o + 3]; out.w = fmaxf(fmaf(sc, (sc >= 0.f) ? hx.w : hn.w, t), 0.f); }
    *(float4*)&Xn[R] = out;
}

// ---------------------------------------------------------------- stage-4 apply: dense HMAX/HMIN -> point-max -> G0T
__global__ __launch_bounds__(256) void applyb4_kernel(const float* __restrict__ HMAX,
                                                      const float* __restrict__ HMIN,
                                                      const float* __restrict__ bnp,
                                                      float* __restrict__ g0T) {
    constexpr int O = 256;
    constexpr int TPR = O / 4;                  // 64
    constexpr int RPAR = 256 / TPR;             // 4
    constexpr int AB = 32;                      // grid.x
    constexpr int RPB = NPTS / AB;              // 64 rows/block
    __shared__ float sh[256 * 4];
    int b = blockIdx.z;
    int otid = threadIdx.x & (TPR - 1);
    int o = otid * 4;
    int rsub = threadIdx.x >> 6;
    int rbase = blockIdx.x * RPB;
    float sc0 = bnp[o + 0], t0 = bnp[O + o + 0];
    float sc1 = bnp[o + 1], t1 = bnp[O + o + 1];
    float sc2 = bnp[o + 2], t2 = bnp[O + o + 2];
    float sc3 = bnp[o + 3], t3 = bnp[O + o + 3];
    float ym0 = 0.f, ym1 = 0.f, ym2 = 0.f, ym3 = 0.f;
    for (int r = rbase + rsub; r < rbase + RPB; r += RPAR) {
        size_t R = (size_t)(b * NPTS + r) * O + o;
        const float4 hx = *(const float4*)&HMAX[R];
        const float4 hn = *(const float4*)&HMIN[R];
        ym0 = fmaxf(ym0, fmaf(sc0, (sc0 >= 0.f) ? hx.x : hn.x, t0));
        ym1 = fmaxf(ym1, fmaf(sc1, (sc1 >= 0.f) ? hx.y : hn.y, t1));
        ym2 = fmaxf(ym2, fmaf(sc2, (sc2 >= 0.f) ? hx.z : hn.z, t2));
        ym3 = fmaxf(ym3, fmaf(sc3, (sc3 >= 0.f) ? hx.w : hn.w, t3));
    }
    float* my = &sh[threadIdx.x * 4];
    my[0] = ym0; my[1] = ym1; my[2] = ym2; my[3] = ym3;
    __syncthreads();
    if (threadIdx.x < TPR) {
        float a0 = ym0, a1 = ym1, a2 = ym2, a3 = ym3;
        for (int g = 1; g < RPAR; ++g) {
            const float* p = &sh[(g * TPR + threadIdx.x) * 4];
            a0 = fmaxf(a0, p[0]); a1 = fmaxf(a1, p[1]);
            a2 = fmaxf(a2, p[2]); a3 = fmaxf(a3, p[3]);
        }
        a0 = fmaxf(a0, 0.f); a1 = fmaxf(a1, 0.f);
        a2 = fmaxf(a2, 0.f); a3 = fmaxf(a3, 0.f);
        atomicMax((int*)&g0T[(o + 0) * 8 + b], __float_as_int(a0));
        atomicMax((int*)&g0T[(o + 1) * 8 + b], __float_as_int(a1));
        atomicMax((int*)&g0T[(o + 2) * 8 + b], __float_as_int(a2));
        atomicMax((int*)&g0T[(o + 3) * 8 + b], __float_as_int(a3));
    }
}

// ---------------------------------------------------------------- point-max of X2/X3 into G0T channels [256,448)
__global__ __launch_bounds__(256) void gmax23_kernel(const float* __restrict__ X2,
                                                     const float* __restrict__ X3,
                                                     float* __restrict__ g0T) {
    int b = blockIdx.x;
    int n0 = blockIdx.y * 32;                   // grid.y = 64
    int o = threadIdx.x;
    if (o >= 192) return;
    const float* src; int col, stride, ch;
    if (o < 128) { src = X3; col = o;       stride = 128; ch = 256 + o; }
    else         { src = X2; col = o - 128; stride = 64;  ch = 384 + (o - 128); }
    float m = 0.f;
#pragma unroll 8
    for (int n = n0; n < n0 + 32; ++n)
        m = fmaxf(m, src[((size_t)(b * NPTS + n)) * stride + col]);
    atomicMax((int*)&g0T[ch * 8 + b], __float_as_int(m));
}

// ---------------------------------------------------------------- fc weight transpose ([o][c] -> [c][o])
__global__ __launch_bounds__(256) void transpose_kernel(const float* __restrict__ w,
                                                        float* __restrict__ wT, int O, int Cc) {
    int e = blockIdx.x * 256 + threadIdx.x;
    if (e >= O * Cc) return;
    int o = e / Cc, c = e - o * Cc;
    wT[c * O + o] = w[e];
}

// ---------------------------------------------------------------- fc1 + bnf1 + relu
__global__ __launch_bounds__(64) void fc1_kernel(const float* __restrict__ g0T,
                                                 const float* __restrict__ w1T,
                                                 const float* __restrict__ b1,
                                                 const float* __restrict__ bng,
                                                 const float* __restrict__ bnb,
                                                 float* __restrict__ A) {
    int o = blockIdx.x * 64 + threadIdx.x;
    float acc[8] = {};
    for (int c = 0; c < 448; ++c) {
        float wv = w1T[c * 256 + o];
        const float4 h0 = *(const float4*)&g0T[c * 8];
        const float4 h1 = *(const float4*)&g0T[c * 8 + 4];
        acc[0] = fmaf(wv, h0.x, acc[0]); acc[1] = fmaf(wv, h0.y, acc[1]);
        acc[2] = fmaf(wv, h0.z, acc[2]); acc[3] = fmaf(wv, h0.w, acc[3]);
        acc[4] = fmaf(wv, h1.x, acc[4]); acc[5] = fmaf(wv, h1.y, acc[5]);
        acc[6] = fmaf(wv, h1.z, acc[6]); acc[7] = fmaf(wv, h1.w, acc[7]);
    }
    float bb = b1[o];
    float h[8], m = 0.f;
#pragma unroll
    for (int b = 0; b < 8; ++b) { h[b] = acc[b] + bb; m += h[b]; }
    m *= 0.125f;
    float var = 0.f;
#pragma unroll
    for (int b = 0; b < 8; ++b) { float d = h[b] - m; var = fmaf(d, d, var); }
    var *= 0.125f;
    float sc = bng[o] / sqrtf(var + EPSV);
    float t = bnb[o] - m * sc;
#pragma unroll
    for (int b = 0; b < 8; ++b) A[o * 8 + b] = fmaxf(fmaf(sc, h[b], t), 0.f);
}

// ---------------------------------------------------------------- fc2..fc4 tail (one block)
__global__ __launch_bounds__(256) void tail_kernel(const float* __restrict__ A,
                                                   const float* __restrict__ w2T, const float* __restrict__ b2,
                                                   const float* __restrict__ g2, const float* __restrict__ be2,
                                                   const float* __restrict__ w3T, const float* __restrict__ b3,
                                                   const float* __restrict__ g3, const float* __restrict__ be3,
                                                   const float* __restrict__ w4, const float* __restrict__ b4,
                                                   float* __restrict__ out) {
    __shared__ __align__(16) float B2[128 * 8];
    __shared__ __align__(16) float C3[16 * 8];
    int tid = threadIdx.x;
    if (tid < 128) {
        int o = tid;
        float acc[8] = {};
        for (int c = 0; c < 256; ++c) {
            float wv = w2T[c * 128 + o];
            const float4 a0 = *(const float4*)&A[c * 8];
            const float4 a1 = *(const float4*)&A[c * 8 + 4];
            acc[0] = fmaf(wv, a0.x, acc[0]); acc[1] = fmaf(wv, a0.y, acc[1]);
            acc[2] = fmaf(wv, a0.z, acc[2]); acc[3] = fmaf(wv, a0.w, acc[3]);
            acc[4] = fmaf(wv, a1.x, acc[4]); acc[5] = fmaf(wv, a1.y, acc[5]);
            acc[6] = fmaf(wv, a1.z, acc[6]); acc[7] = fmaf(wv, a1.w, acc[7]);
        }
        float bb = b2[o];
        float h[8], m = 0.f;
#pragma unroll
        for (int b = 0; b < 8; ++b) { h[b] = acc[b] + bb; m += h[b]; }
        m *= 0.125f;
        float var = 0.f;
#pragma unroll
        for (int b = 0; b < 8; ++b) { float d = h[b] - m; var = fmaf(d, d, var); }
        var *= 0.125f;
        float sc = g2[o] / sqrtf(var + EPSV);
        float t = be2[o] - m * sc;
#pragma unroll
        for (int b = 0; b < 8; ++b) B2[o * 8 + b] = fmaxf(fmaf(sc, h[b], t), 0.f);
    }
    __syncthreads();
    if (tid < 16) {
        int o = tid;
        float acc[8] = {};
        for (int c = 0; c < 128; ++c) {
            float wv = w3T[c * 16 + o];
            const float4 a0 = *(const float4*)&B2[c * 8];
            const float4 a1 = *(const float4*)&B2[c * 8 + 4];
            acc[0] = fmaf(wv, a0.x, acc[0]); acc[1] = fmaf(wv, a0.y, acc[1]);
            acc[2] = fmaf(wv, a0.z, acc[2]); acc[3] = fmaf(wv, a0.w, acc[3]);
            acc[4] = fmaf(wv, a1.x, acc[4]); acc[5] = fmaf(wv, a1.y, acc[5]);
            acc[6] = fmaf(wv, a1.z, acc[6]); acc[7] = fmaf(wv, a1.w, acc[7]);
        }
        float bb = b3[o];
        float h[8], m = 0.f;
#pragma unroll
        for (int b = 0; b < 8; ++b) { h[b] = acc[b] + bb; m += h[b]; }
        m *= 0.125f;
        float var = 0.f;
#pragma unroll
        for (int b = 0; b < 8; ++b) { float d = h[b] - m; var = fmaf(d, d, var); }
        var *= 0.125f;
        float sc = g3[o] / sqrtf(var + EPSV);
        float t = be3[o] - m * sc;
#pragma unroll
        for (int b = 0; b < 8; ++b) C3[o * 8 + b] = fmaxf(fmaf(sc, h[b], t), 0.f);
    }
    __syncthreads();
    if (tid < 8) {
        int b = tid;
        float acc = b4[0];
#pragma unroll
        for (int c = 0; c < 16; ++c) acc = fmaf(w4[c], C3[c * 8 + b], acc);
        out[b] = acc;
    }
}

// ================================================================ host side
struct Arena {
    char* base; size_t off, cap; bool ok;
    Arena(void* b, size_t c) : base((char*)b), off(0), cap(c), ok(true) {}
    void* get(size_t bytes) {
        char* p = base + off;
        off += (bytes + 255) & ~(size_t)255;
        if (off > cap) ok = false;
        return p;
    }
};

// one EdgeConv stage, output stored to Xout (stages 1..3)
template<int C, int O>
static void run_stage(const float* Xin, float* Xout, const float* W, const float* bias,
                      const float* g, const float* be, float* SCRBIG, float* UVA,
                      u16* XHI, u16* XLO, u16* WHI, u16* WLO,
                      u16* IDX, float* SQ, float* PART, float* PART2, float* BNP, hipStream_t s) {
    dim3 blk(256);
    float* HMAX = SCRBIG;
    float* HMIN = SCRBIG + (size_t)NROWS * O;
    sqnorm_kernel<C><<<NROWS / 256, blk, 0, s>>>(Xin, SQ);
    if constexpr (C >= 32) {
        split_kernel<C><<<NROWS * C / 1024, blk, 0, s>>>(Xin, XHI, XLO);
        for (int b0 = 0; b0 < BATCH; b0 += 4) {
            dist_mfma_kernel<C><<<dim3(NPTS / 64, NPTS / 64, 4), blk, 0, s>>>(XHI, XLO, SCRBIG, b0);
            topk_kernel<<<dim3(NPTS / 4, 1, 4), blk, 0, s>>>(SCRBIG, SQ, IDX, b0);
        }
        wsplit_kernel<C, O><<<(2 * O * C + 255) / 256, blk, 0, s>>>(W, WHI, WLO);
        uvb_mfma_kernel<C, O><<<dim3(2 * O / 64, NPTS / 64, BATCH), blk, 0, s>>>(XHI, XLO, WHI, WLO, bias, UVA);
    } else {
        for (int b0 = 0; b0 < BATCH; b0 += 4) {
            dist_gemm_kernel<C><<<dim3(NPTS / 64, NPTS / 64, 4), blk, 0, s>>>(Xin, SCRBIG, b0);
            topk_kernel<<<dim3(NPTS / 4, 1, 4), blk, 0, s>>>(SCRBIG, SQ, IDX, b0);
        }
        uvb_gemm_kernel<C, O><<<dim3(2 * O / 64, NPTS / 64, BATCH), blk, 0, s>>>(Xin, W, bias, UVA);
    }
    statsb_kernel<O><<<dim3(SB, 1, BATCH), blk, 0, s>>>(UVA, IDX, PART, HMAX, HMIN);
    part_reduce_kernel<O><<<PR, blk, 0, s>>>(PART, PART2);
    bnp_kernel<O><<<1, O, 0, s>>>(PART2, g, be, BNP);
    applyb_kernel<O><<<NROWS * (O / 4) / 256, blk, 0, s>>>(HMAX, HMIN, BNP, Xout);
}

// stage 4: point-max fused into G0T (no X4 buffer)
static void run_stage4(const float* Xin, const float* W, const float* bias,
                       const float* g, const float* be, float* SCRBIG, float* UVA,
                       u16* XHI, u16* XLO, u16* WHI, u16* WLO,
                       u16* IDX, float* SQ, float* PART, float* PART2, float* BNP, float* G0T,
                       hipStream_t s) {
    constexpr int C = 128;
    dim3 blk(256);
    float* HMAX = SCRBIG;
    float* HMIN = SCRBIG + (size_t)NROWS * 256;
    sqnorm_kernel<C><<<NROWS / 256, blk, 0, s>>>(Xin, SQ);
    split_kernel<C><<<NROWS * C / 1024, blk, 0, s>>>(Xin, XHI, XLO);
    for (int b0 = 0; b0 < BATCH; b0 += 4) {
        dist_mfma_kernel<C><<<dim3(NPTS / 64, NPTS / 64, 4), blk, 0, s>>>(XHI, XLO, SCRBIG, b0);
        topk_kernel<<<dim3(NPTS / 4, 1, 4), blk, 0, s>>>(SCRBIG, SQ, IDX, b0);
    }
    wsplit_kernel<C, 256><<<(512 * C + 255) / 256, blk, 0, s>>>(W, WHI, WLO);
    uvb_mfma_kernel<C, 256><<<dim3(8, NPTS / 64, BATCH), blk, 0, s>>>(XHI, XLO, WHI, WLO, bias, UVA);
    statsb_kernel<256><<<dim3(SB, 1, BATCH), blk, 0, s>>>(UVA, IDX, PART, HMAX, HMIN);
    part_reduce_kernel<256><<<PR, blk, 0, s>>>(PART, PART2);
    bnp_kernel<256><<<1, 256, 0, s>>>(PART2, g, be, BNP);
    fill_zero_kernel<<<14, blk, 0, s>>>(G0T, 448 * 8);
    applyb4_kernel<<<dim3(32, 1, BATCH), blk, 0, s>>>(HMAX, HMIN, BNP, G0T);
}

extern "C" void kernel_launch(void* const* d_in, const int* in_sizes, int n_in,
                              void* d_out, int out_size, void* d_ws, size_t ws_size,
                              hipStream_t stream) {
    float* out = (float*)d_out;
    if (n_in < 31) { diag_kernel<<<1, 64, 0, stream>>>(out, 9000.f); return; }

    const float* x       = (const float*)d_in[0];
    const float* cw[4]   = {(const float*)d_in[1], (const float*)d_in[5], (const float*)d_in[9],  (const float*)d_in[13]};
    const float* cb[4]   = {(const float*)d_in[2], (const float*)d_in[6], (const float*)d_in[10], (const float*)d_in[14]};
    const float* bg[4]   = {(const float*)d_in[3], (const float*)d_in[7], (const float*)d_in[11], (const float*)d_in[15]};
    const float* bb[4]   = {(const float*)d_in[4], (const float*)d_in[8], (const float*)d_in[12], (const float*)d_in[16]};
    const float* fc1_w = (const float*)d_in[17]; const float* fc1_b = (const float*)d_in[18];
    const float* bnf1_g = (const float*)d_in[19]; const float* bnf1_b = (const float*)d_in[20];
    const float* fc2_w = (const float*)d_in[21]; const float* fc2_b = (const float*)d_in[22];
    const float* bnf2_g = (const float*)d_in[23]; const float* bnf2_b = (const float*)d_in[24];
    const float* fc3_w = (const float*)d_in[25]; const float* fc3_b = (const float*)d_in[26];
    const float* bnf3_g = (const float*)d_in[27]; const float* bnf3_b = (const float*)d_in[28];
    const float* fc4_w = (const float*)d_in[29]; const float* fc4_b = (const float*)d_in[30];

    Arena ar(d_ws, ws_size);
    float* X1 = (float*)ar.get((size_t)NROWS * 64 * 4);
    float* X2 = (float*)ar.get((size_t)NROWS * 64 * 4);
    float* X3 = (float*)ar.get((size_t)NROWS * 128 * 4);
    u16* IDX = (u16*)ar.get((size_t)NROWS * KNN * 2);
    float* SQ = (float*)ar.get((size_t)NROWS * 4);
    float* PART = (float*)ar.get((size_t)BATCH * SB * 512 * 4);   // 4 MB
    float* PART2 = (float*)ar.get((size_t)PR * 512 * 4);          // 128 KB
    float* BNP = (float*)ar.get(512 * 4);
    float* G0T = (float*)ar.get(448 * 8 * 4);
    float* ABUF = (float*)ar.get(256 * 8 * 4);
    u16* XHI = (u16*)ar.get((size_t)NROWS * 128 * 2);             // 4 MB
    u16* XLO = (u16*)ar.get((size_t)NROWS * 128 * 2);             // 4 MB
    u16* WHI = (u16*)ar.get(512 * 128 * 2);
    u16* WLO = (u16*)ar.get(512 * 128 * 2);
    float* SCRBIG = (float*)ar.get((size_t)4 * NPTS * NPTS * 4);  // 67 MB: DIST x4 / HMAX+HMIN+UVA / W-transposes
    if (!ar.ok) {
        diag_kernel<<<1, 64, 0, stream>>>(out, 3000.f + (float)(ws_size >> 20));
        return;
    }
    float* UVA = SCRBIG + (size_t)2 * NPTS * NPTS;                // second half (33.5 MB), disjoint from HMAX/HMIN

    dim3 blk(256);
    run_stage<3, 64>(x, X1, cw[0], cb[0], bg[0], bb[0], SCRBIG, UVA, XHI, XLO, WHI, WLO, IDX, SQ, PART, PART2, BNP, stream);
    run_stage<64, 64>(X1, X2, cw[1], cb[1], bg[1], bb[1], SCRBIG, UVA, XHI, XLO, WHI, WLO, IDX, SQ, PART, PART2, BNP, stream);
    run_stage<64, 128>(X2, X3, cw[2], cb[2], bg[2], bb[2], SCRBIG, UVA, XHI, XLO, WHI, WLO, IDX, SQ, PART, PART2, BNP, stream);
    run_stage4(X3, cw[3], cb[3], bg[3], bb[3], SCRBIG, UVA, XHI, XLO, WHI, WLO, IDX, SQ, PART, PART2, BNP, G0T, stream);

    gmax23_kernel<<<dim3(BATCH, 64), blk, 0, stream>>>(X2, X3, G0T);

    float* W1T = SCRBIG;                         // head reuses SCRBIG (HMAX/HMIN/UVA dead now)
    float* W2T = W1T + 448 * 256;
    float* W3T = W2T + 256 * 128;
    transpose_kernel<<<(256 * 448 + 255) / 256, blk, 0, stream>>>(fc1_w, W1T, 256, 448);
    transpose_kernel<<<(128 * 256 + 255) / 256, blk, 0, stream>>>(fc2_w, W2T, 128, 256);
    transpose_kernel<<<(16 * 128 + 255) / 256, blk, 0, stream>>>(fc3_w, W3T, 16, 128);
    fc1_kernel<<<4, 64, 0, stream>>>(G0T, W1T, fc1_b, bnf1_g, bnf1_b, ABUF);
    tail_kernel<<<1, 256, 0, stream>>>(ABUF, W2T, fc2_b, bnf2_g, bnf2_b,
                                       W3T, fc3_b, bnf3_g, bnf3_b, fc4_w, fc4_b, out);
}

// Round 13
// 682.683 us; speedup vs baseline: 10.5636x; 1.3077x over previous
//
#include <hip/hip_runtime.h>
#include <hip/hip_bf16.h>
#include <cfloat>

constexpr int BATCH = 8, NPTS = 2048, KNN = 20;
constexpr int NROWS = BATCH * NPTS;
constexpr float EPSV = 1e-5f;
constexpr int QCAP = 512;
constexpr int SB = 256;                          // statsb blocks per batch
constexpr int PR = 64;                           // reduced partials
constexpr int RBB = NPTS / 16;                   // row-blocks per batch (128)

using u16 = unsigned short;
using u64 = unsigned long long;
typedef __attribute__((ext_vector_type(8))) short short8;
typedef __attribute__((ext_vector_type(4))) float f32x4;

// ---------------------------------------------------------------- diag / fill
__global__ void diag_kernel(float* out, float v) {
    if (threadIdx.x < 8) out[threadIdx.x] = v;
}

__global__ __launch_bounds__(256) void fill_zero_kernel(float* __restrict__ p, int n) {
    int i = blockIdx.x * 256 + threadIdx.x;
    if (i < n) p[i] = 0.f;
}

// ---------------------------------------------------------------- sqnorm over all rows
template<int C>
__global__ __launch_bounds__(256) void sqnorm_kernel(const float* __restrict__ X,
                                                     float* __restrict__ sq) {
    int r = blockIdx.x * 256 + threadIdx.x;
    const float* x = X + (size_t)r * C;
    float s = 0.f;
#pragma unroll
    for (int c = 0; c < C; ++c) { float v = x[c]; s = fmaf(v, v, s); }
    sq[r] = s;
}

// ---------------------------------------------------------------- split X -> hi/lo bf16 in PACKED MFMA-fragment layout
// PACK[((Rb*KB + kb) * 64 + lane) * 8 + e] = X[Rb*16 + (lane&15)][kb*32 + (lane>>4)*8 + e]
template<int C>
__global__ __launch_bounds__(256) void split_pack_kernel(const float* __restrict__ X,
                                                         u16* __restrict__ XPH,
                                                         u16* __restrict__ XPL) {
    constexpr int KB = C / 32;
    int e = blockIdx.x * 256 + threadIdx.x;     // one short8 fragment per thread; grid = NROWS*C/8/256
    int lane = e & 63;
    int rest = e >> 6;
    int kb = rest % KB;
    int Rb = rest / KB;                          // global row-block (batches contiguous)
    int row = Rb * 16 + (lane & 15);
    int col = kb * 32 + (lane >> 4) * 8;
    const float* src = &X[(size_t)row * C + col];
    u16 h[8], l[8];
#pragma unroll
    for (int q = 0; q < 8; ++q) {
        float v = src[q];
        __hip_bfloat16 hb = __float2bfloat16(v);
        float hf = __bfloat162float(hb);
        __hip_bfloat16 lb = __float2bfloat16(v - hf);
        h[q] = *(u16*)&hb; l[q] = *(u16*)&lb;
    }
    u16* dh = &XPH[(size_t)e * 8];
    u16* dl = &XPL[(size_t)e * 8];
#pragma unroll
    for (int q = 0; q < 8; ++q) { dh[q] = h[q]; dl[q] = l[q]; }
}

// ---------------------------------------------------------------- split W -> packed hi/lo (rows: n<O: W1; n>=O: W2-W1)
template<int C, int O>
__global__ __launch_bounds__(256) void wsplit_pack_kernel(const float* __restrict__ W,
                                                          u16* __restrict__ WPH,
                                                          u16* __restrict__ WPL) {
    constexpr int KB = C / 32;
    constexpr int NFRAG = (2 * O / 16) * KB * 64;
    int e = blockIdx.x * 256 + threadIdx.x;
    if (e >= NFRAG) return;
    int lane = e & 63;
    int rest = e >> 6;
    int kb = rest % KB;
    int Nb = rest / KB;
    int n = Nb * 16 + (lane & 15);
    int col = kb * 32 + (lane >> 4) * 8;
    u16 h[8], l[8];
#pragma unroll
    for (int q = 0; q < 8; ++q) {
        int c = col + q;
        float wv = (n < O) ? W[(size_t)n * (2 * C) + c]
                           : W[(size_t)(n - O) * (2 * C) + C + c] - W[(size_t)(n - O) * (2 * C) + c];
        __hip_bfloat16 hb = __float2bfloat16(wv);
        float hf = __bfloat162float(hb);
        __hip_bfloat16 lb = __float2bfloat16(wv - hf);
        h[q] = *(u16*)&hb; l[q] = *(u16*)&lb;
    }
    u16* dh = &WPH[(size_t)e * 8];
    u16* dl = &WPL[(size_t)e * 8];
#pragma unroll
    for (int q = 0; q < 8; ++q) { dh[q] = h[q]; dl[q] = l[q]; }
}

// ---------------------------------------------------------------- MFMA dist from packed fragments (hh + hl + lh)
template<int C>
__global__ __launch_bounds__(256) void dist_mfma_kernel(const u16* __restrict__ XPH,
                                                        const u16* __restrict__ XPL,
                                                        float* __restrict__ D, int b0) {
    constexpr int KB = C / 32;
    int b = b0 + blockIdx.z;
    int i0 = blockIdx.y * 64, j0 = blockIdx.x * 64;
    int w = threadIdx.x >> 6, lane = threadIdx.x & 63;
    int l15 = lane & 15, g = lane >> 4;
    size_t base = (size_t)b * RBB * KB * 512;    // batch offset in packed elements
    int Rba = i0 / 16 + w;
    short8 ahi[KB], alo[KB];
#pragma unroll
    for (int kb = 0; kb < KB; ++kb) {
        size_t ia = base + ((size_t)(Rba * KB + kb) * 64 + lane) * 8;
        ahi[kb] = *(const short8*)&XPH[ia];
        alo[kb] = *(const short8*)&XPL[ia];
    }
    float* Dz = D + (size_t)blockIdx.z * NPTS * NPTS;
#pragma unroll
    for (int nt = 0; nt < 4; ++nt) {
        int Rbb = j0 / 16 + nt;
        f32x4 acc = {0.f, 0.f, 0.f, 0.f};
#pragma unroll
        for (int kb = 0; kb < KB; ++kb) {
            size_t ib = base + ((size_t)(Rbb * KB + kb) * 64 + lane) * 8;
            short8 bhi = *(const short8*)&XPH[ib];
            short8 blo = *(const short8*)&XPL[ib];
            acc = __builtin_amdgcn_mfma_f32_16x16x32_bf16(ahi[kb], bhi, acc, 0, 0, 0);
            acc = __builtin_amdgcn_mfma_f32_16x16x32_bf16(ahi[kb], blo, acc, 0, 0, 0);
            acc = __builtin_amdgcn_mfma_f32_16x16x32_bf16(alo[kb], bhi, acc, 0, 0, 0);
        }
        int col = j0 + nt * 16 + l15;
        int rbase = i0 + w * 16 + g * 4;
#pragma unroll
        for (int r = 0; r < 4; ++r)
            Dz[(size_t)(rbase + r) * NPTS + col] = acc[r];
    }
}

// ---------------------------------------------------------------- f32 dist GEMM (stage 1, C=3 only)
template<int C>
__global__ __launch_bounds__(256) void dist_gemm_kernel(const float* __restrict__ X,
                                                        float* __restrict__ D, int b0) {
    constexpr int KC = (C < 32) ? C : 32;
    __shared__ __align__(16) float As[KC][68];
    __shared__ __align__(16) float Bs[KC][68];
    int b = b0 + blockIdx.z;
    int i0 = blockIdx.y * 64, j0 = blockIdx.x * 64;
    const float* Xb = X + (size_t)b * NPTS * C;
    int tx = threadIdx.x & 15, ty = threadIdx.x >> 4;
    float acc[4][4] = {};
    for (int c0 = 0; c0 < C; c0 += KC) {
        for (int t = threadIdx.x; t < 64 * KC; t += 256) {
            int i = t / KC, c = t % KC;
            As[c][i] = Xb[(size_t)(i0 + i) * C + c0 + c];
            Bs[c][i] = Xb[(size_t)(j0 + i) * C + c0 + c];
        }
        __syncthreads();
#pragma unroll
        for (int c = 0; c < KC; ++c) {
            const float4 av = *(const float4*)&As[c][ty * 4];
            const float4 bv = *(const float4*)&Bs[c][tx * 4];
            float ar[4] = {av.x, av.y, av.z, av.w};
            float br[4] = {bv.x, bv.y, bv.z, bv.w};
#pragma unroll
            for (int r = 0; r < 4; ++r)
#pragma unroll
                for (int q = 0; q < 4; ++q) acc[r][q] = fmaf(ar[r], br[q], acc[r][q]);
        }
        __syncthreads();
    }
    float* Dz = D + (size_t)blockIdx.z * NPTS * NPTS;
#pragma unroll
    for (int r = 0; r < 4; ++r) {
        float4 o4 = make_float4(acc[r][0], acc[r][1], acc[r][2], acc[r][3]);
        *(float4*)&Dz[(size_t)(i0 + ty * 4 + r) * NPTS + j0 + tx * 4] = o4;
    }
}

// ---------------------------------------------------------------- wave-64 bitonic sorts
__device__ __forceinline__ float bitonic64_desc_f32(float key, int lane) {
#pragma unroll
    for (int k = 2; k <= 64; k <<= 1) {
#pragma unroll
        for (int j = k >> 1; j > 0; j >>= 1) {
            float p = __shfl_xor(key, j);
            bool keepMax = (((lane & j) == 0) == ((lane & k) == 0));
            key = ((key > p) == keepMax) ? key : p;
        }
    }
    return key;
}

__device__ __forceinline__ u64 bitonic64_desc_u64(u64 key, int lane) {
#pragma unroll
    for (int k = 2; k <= 64; k <<= 1) {
#pragma unroll
        for (int j = k >> 1; j > 0; j >>= 1) {
            u64 p = __shfl_xor(key, j);
            bool keepMax = (((lane & j) == 0) == ((lane & k) == 0));
            key = ((key > p) == keepMax) ? key : p;
        }
    }
    return key;
}

// ---------------------------------------------------------------- top-k
__global__ __launch_bounds__(256) void topk_kernel(const float* __restrict__ D,
                                                   const float* __restrict__ sq,
                                                   u16* __restrict__ idx_out, int b0) {
    __shared__ u64 qkey[4][QCAP];
    __shared__ int qn[4];
    int b = b0 + blockIdx.z;
    int w = threadIdx.x >> 6, lane = threadIdx.x & 63;
    int i = blockIdx.x * 4 + w;
    const float* Drow = D + ((size_t)blockIdx.z * NPTS + i) * NPTS;
    const float* sqb = sq + b * NPTS;
    float sqi = sqb[i];
    if (lane == 0) qn[w] = 0;

    float vals[32];
    float mx = -FLT_MAX;
#pragma unroll
    for (int t = 0; t < 8; ++t) {
        int j = t * 256 + lane * 4;
        float4 v4 = *(const float4*)&Drow[j];
        float4 s4 = *(const float4*)&sqb[j];
        float a0 = (2.f * v4.x - sqi - s4.x) + 0.f;
        float a1 = (2.f * v4.y - sqi - s4.y) + 0.f;
        float a2 = (2.f * v4.z - sqi - s4.z) + 0.f;
        float a3 = (2.f * v4.w - sqi - s4.w) + 0.f;
        vals[t * 4 + 0] = a0; vals[t * 4 + 1] = a1;
        vals[t * 4 + 2] = a2; vals[t * 4 + 3] = a3;
        mx = fmaxf(mx, fmaxf(fmaxf(a0, a1), fmaxf(a2, a3)));
    }

    float sm = bitonic64_desc_f32(mx, lane);
    float T0 = __shfl(sm, 19);

#pragma unroll
    for (int t = 0; t < 32; ++t) {
        float v = vals[t];
        if (v >= T0) {
            unsigned j = (unsigned)((t >> 2) * 256 + lane * 4 + (t & 3));
            unsigned bu = __float_as_uint(v);
            unsigned u = (bu & 0x80000000u) ? ~bu : (bu | 0x80000000u);
            u64 key = ((u64)u << 32) | (u64)(0xFFFFFFFFu - j);
            int slot = atomicAdd(&qn[w], 1);
            if (slot < QCAP) qkey[w][slot] = key;
        }
    }
    int C = qn[w];
    if (C > QCAP) C = QCAP;

    u64 key = (lane < C) ? qkey[w][lane] : 0ull;
    key = bitonic64_desc_u64(key, lane);
    int base = 64;
    while (base < C) {
        if (lane >= 20) {
            int src = base + (lane - 20);
            key = (src < C) ? qkey[w][src] : 0ull;
        }
        key = bitonic64_desc_u64(key, lane);
        base += 44;
    }
    if (lane < 20) {
        unsigned j = 0xFFFFFFFFu - (unsigned)(key & 0xFFFFFFFFull);
        idx_out[(size_t)(b * NPTS + i) * KNN + lane] = (u16)j;
    }
}

// ---------------------------------------------------------------- uvb via MFMA from packed fragments
template<int C, int O>
__global__ __launch_bounds__(256) void uvb_mfma_kernel(const u16* __restrict__ XPH,
                                                       const u16* __restrict__ XPL,
                                                       const u16* __restrict__ WPH,
                                                       const u16* __restrict__ WPL,
                                                       const float* __restrict__ bias,
                                                       float* __restrict__ UVA) {
    constexpr int KB = C / 32;
    int b = blockIdx.z;
    int r0 = blockIdx.y * 64, n0 = blockIdx.x * 64;
    int w = threadIdx.x >> 6, lane = threadIdx.x & 63;
    int l15 = lane & 15, g = lane >> 4;
    size_t base = (size_t)b * RBB * KB * 512;
    int Rba = r0 / 16 + w;
    short8 ahi[KB], alo[KB];
#pragma unroll
    for (int kb = 0; kb < KB; ++kb) {
        size_t ia = base + ((size_t)(Rba * KB + kb) * 64 + lane) * 8;
        ahi[kb] = *(const short8*)&XPH[ia];
        alo[kb] = *(const short8*)&XPL[ia];
    }
    float* UVb = UVA + (size_t)b * NPTS * 2 * O;
#pragma unroll
    for (int nt = 0; nt < 4; ++nt) {
        int Nb = n0 / 16 + nt;
        f32x4 acc = {0.f, 0.f, 0.f, 0.f};
#pragma unroll
        for (int kb = 0; kb < KB; ++kb) {
            size_t ib = ((size_t)(Nb * KB + kb) * 64 + lane) * 8;
            short8 bhi = *(const short8*)&WPH[ib];
            short8 blo = *(const short8*)&WPL[ib];
            acc = __builtin_amdgcn_mfma_f32_16x16x32_bf16(ahi[kb], bhi, acc, 0, 0, 0);
            acc = __builtin_amdgcn_mfma_f32_16x16x32_bf16(ahi[kb], blo, acc, 0, 0, 0);
            acc = __builtin_amdgcn_mfma_f32_16x16x32_bf16(alo[kb], bhi, acc, 0, 0, 0);
        }
        int n = n0 + nt * 16 + l15;
        float badd = (n >= O) ? bias[n - O] : 0.f;
        int rbase = r0 + w * 16 + g * 4;
#pragma unroll
        for (int r = 0; r < 4; ++r)
            UVb[(size_t)(rbase + r) * (2 * O) + n] = acc[r] + badd;
    }
}

// ---------------------------------------------------------------- f32 uvb (stage 1, C=3)
template<int C, int O>
__global__ __launch_bounds__(256) void uvb_gemm_kernel(const float* __restrict__ X,
                                                       const float* __restrict__ W,
                                                       const float* __restrict__ bias,
                                                       float* __restrict__ UVA) {
    constexpr int KC = (C < 32) ? C : 32;
    __shared__ __align__(16) float As[KC][68];
    __shared__ __align__(16) float Bs[KC][68];
    int b = blockIdx.z;
    int r0 = blockIdx.y * 64, n0 = blockIdx.x * 64;
    int tx = threadIdx.x & 15, ty = threadIdx.x >> 4;
    float acc[4][4] = {};
    for (int c0 = 0; c0 < C; c0 += KC) {
        for (int t = threadIdx.x; t < 64 * KC; t += 256) {
            int i = t / KC, c = t % KC;
            As[c][i] = X[(size_t)(b * NPTS + r0 + i) * C + c0 + c];
            int n = n0 + i;
            float wv;
            if (n < O) wv = W[(size_t)n * (2 * C) + c0 + c];
            else {
                int o = n - O;
                wv = W[(size_t)o * (2 * C) + C + c0 + c] - W[(size_t)o * (2 * C) + c0 + c];
            }
            Bs[c][i] = wv;
        }
        __syncthreads();
#pragma unroll
        for (int c = 0; c < KC; ++c) {
            const float4 av = *(const float4*)&As[c][ty * 4];
            const float4 bv = *(const float4*)&Bs[c][tx * 4];
            float ar[4] = {av.x, av.y, av.z, av.w};
            float br[4] = {bv.x, bv.y, bv.z, bv.w};
#pragma unroll
            for (int r = 0; r < 4; ++r)
#pragma unroll
                for (int q = 0; q < 4; ++q) acc[r][q] = fmaf(ar[r], br[q], acc[r][q]);
        }
        __syncthreads();
    }
    float badd[4] = {0.f, 0.f, 0.f, 0.f};
    if (n0 >= O) {
#pragma unroll
        for (int q = 0; q < 4; ++q) badd[q] = bias[n0 - O + tx * 4 + q];
    }
    float* UVb = UVA + (size_t)b * NPTS * 2 * O;
#pragma unroll
    for (int r = 0; r < 4; ++r) {
        float4 o4 = make_float4(acc[r][0] + badd[0], acc[r][1] + badd[1],
                                acc[r][2] + badd[2], acc[r][3] + badd[3]);
        *(float4*)&UVb[(size_t)(r0 + ty * 4 + r) * (2 * O) + n0 + tx * 4] = o4;
    }
}

// ---------------------------------------------------------------- stats: ONE gather pass -> block partials + dense HMAX/HMIN
template<int O>
__global__ __launch_bounds__(256) void statsb_kernel(const float* __restrict__ UVA,
                                                     const u16* __restrict__ idx,
                                                     float* __restrict__ PART,
                                                     float* __restrict__ HMAX,
                                                     float* __restrict__ HMIN) {
    constexpr int TPR = O / 4;
    constexpr int RPAR = 256 / TPR;
    constexpr int RPB = NPTS / SB;
    __shared__ float sh[256 * 8];
    int b = blockIdx.z;
    const float* UVb = UVA + (size_t)b * NPTS * 2 * O;
    int otid = threadIdx.x % TPR;
    int o = otid * 4;
    int rsub = threadIdx.x / TPR;
    int rbase = blockIdx.x * RPB;
    float s0 = 0, s1 = 0, s2 = 0, s3 = 0, q0 = 0, q1 = 0, q2 = 0, q3 = 0;
    for (int r = rbase + rsub; r < rbase + RPB; r += RPAR) {
        const float4 v4 = *(const float4*)&UVb[(size_t)r * (2 * O) + O + o];
        const u16* ix = idx + (size_t)(b * NPTS + r) * KNN;
        float mx0 = -FLT_MAX, mx1 = -FLT_MAX, mx2 = -FLT_MAX, mx3 = -FLT_MAX;
        float mn0 = FLT_MAX, mn1 = FLT_MAX, mn2 = FLT_MAX, mn3 = FLT_MAX;
#pragma unroll
        for (int k = 0; k < KNN; ++k) {
            int j = (int)ix[k] & (NPTS - 1);
            const float4 u4 = *(const float4*)&UVb[(size_t)j * (2 * O) + o];
            float h0 = u4.x + v4.x, h1 = u4.y + v4.y, h2 = u4.z + v4.z, h3 = u4.w + v4.w;
            s0 += h0; q0 = fmaf(h0, h0, q0); mx0 = fmaxf(mx0, h0); mn0 = fminf(mn0, h0);
            s1 += h1; q1 = fmaf(h1, h1, q1); mx1 = fmaxf(mx1, h1); mn1 = fminf(mn1, h1);
            s2 += h2; q2 = fmaf(h2, h2, q2); mx2 = fmaxf(mx2, h2); mn2 = fminf(mn2, h2);
            s3 += h3; q3 = fmaf(h3, h3, q3); mx3 = fmaxf(mx3, h3); mn3 = fminf(mn3, h3);
        }
        size_t R = (size_t)(b * NPTS + r) * O + o;
        *(float4*)&HMAX[R] = make_float4(mx0, mx1, mx2, mx3);
        *(float4*)&HMIN[R] = make_float4(mn0, mn1, mn2, mn3);
    }
    float* my = &sh[threadIdx.x * 8];
    my[0] = s0; my[1] = s1; my[2] = s2; my[3] = s3;
    my[4] = q0; my[5] = q1; my[6] = q2; my[7] = q3;
    __syncthreads();
    if (threadIdx.x < TPR) {
        float a[8];
#pragma unroll
        for (int c = 0; c < 8; ++c) a[c] = sh[threadIdx.x * 8 + c];
        for (int g = 1; g < RPAR; ++g) {
            const float* p = &sh[(g * TPR + threadIdx.x) * 8];
#pragma unroll
            for (int c = 0; c < 8; ++c) a[c] += p[c];
        }
        float* dst = &PART[((size_t)b * SB + blockIdx.x) * (2 * O)];
#pragma unroll
        for (int c = 0; c < 4; ++c) { dst[o + c] = a[c]; dst[O + o + c] = a[4 + c]; }
    }
}

// ---------------------------------------------------------------- PART -> PART2
template<int O>
__global__ __launch_bounds__(256) void part_reduce_kernel(const float* __restrict__ PART,
                                                          float* __restrict__ PART2) {
    constexpr int ROWS = BATCH * SB;
    constexpr int RPG = ROWS / PR;
    int g = blockIdx.x;
    for (int col = threadIdx.x; col < 2 * O; col += 256) {
        float s = 0.f;
        for (int r = 0; r < RPG; ++r)
            s += PART[(size_t)(g * RPG + r) * (2 * O) + col];
        PART2[(size_t)g * (2 * O) + col] = s;
    }
}

template<int O>
__global__ void bnp_kernel(const float* __restrict__ PART2, const float* __restrict__ g,
                           const float* __restrict__ beta, float* __restrict__ bnp) {
    int o = threadIdx.x;
    float s = 0.f, ss = 0.f;
    for (int p = 0; p < PR; ++p) {
        s += PART2[(size_t)p * (2 * O) + o];
        ss += PART2[(size_t)p * (2 * O) + O + o];
    }
    const float cnt = (float)NROWS * (float)KNN;
    float m = s / cnt;
    float var = ss / cnt - m * m;
    float sc = g[o] / sqrtf(var + EPSV);
    bnp[o] = sc;
    bnp[O + o] = beta[o] - m * sc;
}

// ---------------------------------------------------------------- apply (stages 1..3)
template<int O>
__global__ __launch_bounds__(256) void applyb_kernel(const float* __restrict__ HMAX,
                                                     const float* __restrict__ HMIN,
                                                     const float* __restrict__ bnp,
                                                     float* __restrict__ Xn) {
    constexpr int TPR = O / 4;
    int e = blockIdx.x * 256 + threadIdx.x;
    int o = (e % TPR) * 4;
    size_t R = (size_t)(e / TPR) * O + o;
    const float4 hx = *(const float4*)&HMAX[R];
    const float4 hn = *(const float4*)&HMIN[R];
    float4 out;
    { float sc = bnp[o + 0], t = bnp[O + o + 0]; out.x = fmaxf(fmaf(sc, (sc >= 0.f) ? hx.x : hn.x, t), 0.f); }
    { float sc = bnp[o + 1], t = bnp[O + o + 1]; out.y = fmaxf(fmaf(sc, (sc >= 0.f) ? hx.y : hn.y, t), 0.f); }
    { float sc = bnp[o + 2], t = bnp[O + o + 2]; out.z = fmaxf(fmaf(sc, (sc >= 0.f) ? hx.z : hn.z, t), 0.f); }
    { float sc = bnp[o + 3], t = bnp[O + o + 3]; out.w = fmaxf(fmaf(sc, (sc >= 0.f) ? hx.w : hn.w, t), 0.f); }
    *(float4*)&Xn[R] = out;
}

// ---------------------------------------------------------------- stage-4 apply: dense -> point-max -> G0T
__global__ __launch_bounds__(256) void applyb4_kernel(const float* __restrict__ HMAX,
                                                      const float* __restrict__ HMIN,
                                                      const float* __restrict__ bnp,
                                                      float* __restrict__ g0T) {
    constexpr int O = 256;
    constexpr int TPR = O / 4;
    constexpr int RPAR = 256 / TPR;
    constexpr int AB = 32;
    constexpr int RPB = NPTS / AB;
    __shared__ float sh[256 * 4];
    int b = blockIdx.z;
    int otid = threadIdx.x & (TPR - 1);
    int o = otid * 4;
    int rsub = threadIdx.x >> 6;
    int rbase = blockIdx.x * RPB;
    float sc0 = bnp[o + 0], t0 = bnp[O + o + 0];
    float sc1 = bnp[o + 1], t1 = bnp[O + o + 1];
    float sc2 = bnp[o + 2], t2 = bnp[O + o + 2];
    float sc3 = bnp[o + 3], t3 = bnp[O + o + 3];
    float ym0 = 0.f, ym1 = 0.f, ym2 = 0.f, ym3 = 0.f;
    for (int r = rbase + rsub; r < rbase + RPB; r += RPAR) {
        size_t R = (size_t)(b * NPTS + r) * O + o;
        const float4 hx = *(const float4*)&HMAX[R];
        const float4 hn = *(const float4*)&HMIN[R];
        ym0 = fmaxf(ym0, fmaf(sc0, (sc0 >= 0.f) ? hx.x : hn.x, t0));
        ym1 = fmaxf(ym1, fmaf(sc1, (sc1 >= 0.f) ? hx.y : hn.y, t1));
        ym2 = fmaxf(ym2, fmaf(sc2, (sc2 >= 0.f) ? hx.z : hn.z, t2));
        ym3 = fmaxf(ym3, fmaf(sc3, (sc3 >= 0.f) ? hx.w : hn.w, t3));
    }
    float* my = &sh[threadIdx.x * 4];
    my[0] = ym0; my[1] = ym1; my[2] = ym2; my[3] = ym3;
    __syncthreads();
    if (threadIdx.x < TPR) {
        float a0 = ym0, a1 = ym1, a2 = ym2, a3 = ym3;
        for (int g = 1; g < RPAR; ++g) {
            const float* p = &sh[(g * TPR + threadIdx.x) * 4];
            a0 = fmaxf(a0, p[0]); a1 = fmaxf(a1, p[1]);
            a2 = fmaxf(a2, p[2]); a3 = fmaxf(a3, p[3]);
        }
        a0 = fmaxf(a0, 0.f); a1 = fmaxf(a1, 0.f);
        a2 = fmaxf(a2, 0.f); a3 = fmaxf(a3, 0.f);
        atomicMax((int*)&g0T[(o + 0) * 8 + b], __float_as_int(a0));
        atomicMax((int*)&g0T[(o + 1) * 8 + b], __float_as_int(a1));
        atomicMax((int*)&g0T[(o + 2) * 8 + b], __float_as_int(a2));
        atomicMax((int*)&g0T[(o + 3) * 8 + b], __float_as_int(a3));
    }
}

// ---------------------------------------------------------------- point-max of X2/X3 into G0T channels [256,448)
__global__ __launch_bounds__(256) void gmax23_kernel(const float* __restrict__ X2,
                                                     const float* __restrict__ X3,
                                                     float* __restrict__ g0T) {
    int b = blockIdx.x;
    int n0 = blockIdx.y * 32;
    int o = threadIdx.x;
    if (o >= 192) return;
    const float* src; int col, stride, ch;
    if (o < 128) { src = X3; col = o;       stride = 128; ch = 256 + o; }
    else         { src = X2; col = o - 128; stride = 64;  ch = 384 + (o - 128); }
    float m = 0.f;
#pragma unroll 8
    for (int n = n0; n < n0 + 32; ++n)
        m = fmaxf(m, src[((size_t)(b * NPTS + n)) * stride + col]);
    atomicMax((int*)&g0T[ch * 8 + b], __float_as_int(m));
}

// ---------------------------------------------------------------- fc weight transpose
__global__ __launch_bounds__(256) void transpose_kernel(const float* __restrict__ w,
                                                        float* __restrict__ wT, int O, int Cc) {
    int e = blockIdx.x * 256 + threadIdx.x;
    if (e >= O * Cc) return;
    int o = e / Cc, c = e - o * Cc;
    wT[c * O + o] = w[e];
}

// ---------------------------------------------------------------- fc1 + bnf1 + relu
__global__ __launch_bounds__(64) void fc1_kernel(const float* __restrict__ g0T,
                                                 const float* __restrict__ w1T,
                                                 const float* __restrict__ b1,
                                                 const float* __restrict__ bng,
                                                 const float* __restrict__ bnb,
                                                 float* __restrict__ A) {
    int o = blockIdx.x * 64 + threadIdx.x;
    float acc[8] = {};
    for (int c = 0; c < 448; ++c) {
        float wv = w1T[c * 256 + o];
        const float4 h0 = *(const float4*)&g0T[c * 8];
        const float4 h1 = *(const float4*)&g0T[c * 8 + 4];
        acc[0] = fmaf(wv, h0.x, acc[0]); acc[1] = fmaf(wv, h0.y, acc[1]);
        acc[2] = fmaf(wv, h0.z, acc[2]); acc[3] = fmaf(wv, h0.w, acc[3]);
        acc[4] = fmaf(wv, h1.x, acc[4]); acc[5] = fmaf(wv, h1.y, acc[5]);
        acc[6] = fmaf(wv, h1.z, acc[6]); acc[7] = fmaf(wv, h1.w, acc[7]);
    }
    float bb = b1[o];
    float h[8], m = 0.f;
#pragma unroll
    for (int b = 0; b < 8; ++b) { h[b] = acc[b] + bb; m += h[b]; }
    m *= 0.125f;
    float var = 0.f;
#pragma unroll
    for (int b = 0; b < 8; ++b) { float d = h[b] - m; var = fmaf(d, d, var); }
    var *= 0.125f;
    float sc = bng[o] / sqrtf(var + EPSV);
    float t = bnb[o] - m * sc;
#pragma unroll
    for (int b = 0; b < 8; ++b) A[o * 8 + b] = fmaxf(fmaf(sc, h[b], t), 0.f);
}

// ---------------------------------------------------------------- fc2..fc4 tail (one block)
__global__ __launch_bounds__(256) void tail_kernel(const float* __restrict__ A,
                                                   const float* __restrict__ w2T, const float* __restrict__ b2,
                                                   const float* __restrict__ g2, const float* __restrict__ be2,
                                                   const float* __restrict__ w3T, const float* __restrict__ b3,
                                                   const float* __restrict__ g3, const float* __restrict__ be3,
                                                   const float* __restrict__ w4, const float* __restrict__ b4,
                                                   float* __restrict__ out) {
    __shared__ __align__(16) float B2[128 * 8];
    __shared__ __align__(16) float C3[16 * 8];
    int tid = threadIdx.x;
    if (tid < 128) {
        int o = tid;
        float acc[8] = {};
        for (int c = 0; c < 256; ++c) {
            float wv = w2T[c * 128 + o];
            const float4 a0 = *(const float4*)&A[c * 8];
            const float4 a1 = *(const float4*)&A[c * 8 + 4];
            acc[0] = fmaf(wv, a0.x, acc[0]); acc[1] = fmaf(wv, a0.y, acc[1]);
            acc[2] = fmaf(wv, a0.z, acc[2]); acc[3] = fmaf(wv, a0.w, acc[3]);
            acc[4] = fmaf(wv, a1.x, acc[4]); acc[5] = fmaf(wv, a1.y, acc[5]);
            acc[6] = fmaf(wv, a1.z, acc[6]); acc[7] = fmaf(wv, a1.w, acc[7]);
        }
        float bb = b2[o];
        float h[8], m = 0.f;
#pragma unroll
        for (int b = 0; b < 8; ++b) { h[b] = acc[b] + bb; m += h[b]; }
        m *= 0.125f;
        float var = 0.f;
#pragma unroll
        for (int b = 0; b < 8; ++b) { float d = h[b] - m; var = fmaf(d, d, var); }
        var *= 0.125f;
        float sc = g2[o] / sqrtf(var + EPSV);
        float t = be2[o] - m * sc;
#pragma unroll
        for (int b = 0; b < 8; ++b) B2[o * 8 + b] = fmaxf(fmaf(sc, h[b], t), 0.f);
    }
    __syncthreads();
    if (tid < 16) {
        int o = tid;
        float acc[8] = {};
        for (int c = 0; c < 128; ++c) {
            float wv = w3T[c * 16 + o];
            const float4 a0 = *(const float4*)&B2[c * 8];
            const float4 a1 = *(const float4*)&B2[c * 8 + 4];
            acc[0] = fmaf(wv, a0.x, acc[0]); acc[1] = fmaf(wv, a0.y, acc[1]);
            acc[2] = fmaf(wv, a0.z, acc[2]); acc[3] = fmaf(wv, a0.w, acc[3]);
            acc[4] = fmaf(wv, a1.x, acc[4]); acc[5] = fmaf(wv, a1.y, acc[5]);
            acc[6] = fmaf(wv, a1.z, acc[6]); acc[7] = fmaf(wv, a1.w, acc[7]);
        }
        float bb = b3[o];
        float h[8], m = 0.f;
#pragma unroll
        for (int b = 0; b < 8; ++b) { h[b] = acc[b] + bb; m += h[b]; }
        m *= 0.125f;
        float var = 0.f;
#pragma unroll
        for (int b = 0; b < 8; ++b) { float d = h[b] - m; var = fmaf(d, d, var); }
        var *= 0.125f;
        float sc = g3[o] / sqrtf(var + EPSV);
        float t = be3[o] - m * sc;
#pragma unroll
        for (int b = 0; b < 8; ++b) C3[o * 8 + b] = fmaxf(fmaf(sc, h[b], t), 0.f);
    }
    __syncthreads();
    if (tid < 8) {
        int b = tid;
        float acc = b4[0];
#pragma unroll
        for (int c = 0; c < 16; ++c) acc = fmaf(w4[c], C3[c * 8 + b], acc);
        out[b] = acc;
    }
}

// ================================================================ host side
struct Arena {
    char* base; size_t off, cap; bool ok;
    Arena(void* b, size_t c) : base((char*)b), off(0), cap(c), ok(true) {}
    void* get(size_t bytes) {
        char* p = base + off;
        off += (bytes + 255) & ~(size_t)255;
        if (off > cap) ok = false;
        return p;
    }
};

// one EdgeConv stage, output stored to Xout (stages 1..3)
template<int C, int O>
static void run_stage(const float* Xin, float* Xout, const float* W, const float* bias,
                      const float* g, const float* be, float* SCRBIG, float* UVA,
                      u16* XPH, u16* XPL, u16* WPH, u16* WPL,
                      u16* IDX, float* SQ, float* PART, float* PART2, float* BNP, hipStream_t s) {
    dim3 blk(256);
    float* HMAX = SCRBIG;
    float* HMIN = SCRBIG + (size_t)NROWS * O;
    sqnorm_kernel<C><<<NROWS / 256, blk, 0, s>>>(Xin, SQ);
    if constexpr (C >= 32) {
        split_pack_kernel<C><<<NROWS * C / 8 / 256, blk, 0, s>>>(Xin, XPH, XPL);
        for (int b0 = 0; b0 < BATCH; b0 += 4) {
            dist_mfma_kernel<C><<<dim3(NPTS / 64, NPTS / 64, 4), blk, 0, s>>>(XPH, XPL, SCRBIG, b0);
            topk_kernel<<<dim3(NPTS / 4, 1, 4), blk, 0, s>>>(SCRBIG, SQ, IDX, b0);
        }
        wsplit_pack_kernel<C, O><<<(2 * O * C / 8 + 255) / 256, blk, 0, s>>>(W, WPH, WPL);
        uvb_mfma_kernel<C, O><<<dim3(2 * O / 64, NPTS / 64, BATCH), blk, 0, s>>>(XPH, XPL, WPH, WPL, bias, UVA);
    } else {
        for (int b0 = 0; b0 < BATCH; b0 += 4) {
            dist_gemm_kernel<C><<<dim3(NPTS / 64, NPTS / 64, 4), blk, 0, s>>>(Xin, SCRBIG, b0);
            topk_kernel<<<dim3(NPTS / 4, 1, 4), blk, 0, s>>>(SCRBIG, SQ, IDX, b0);
        }
        uvb_gemm_kernel<C, O><<<dim3(2 * O / 64, NPTS / 64, BATCH), blk, 0, s>>>(Xin, W, bias, UVA);
    }
    statsb_kernel<O><<<dim3(SB, 1, BATCH), blk, 0, s>>>(UVA, IDX, PART, HMAX, HMIN);
    part_reduce_kernel<O><<<PR, blk, 0, s>>>(PART, PART2);
    bnp_kernel<O><<<1, O, 0, s>>>(PART2, g, be, BNP);
    applyb_kernel<O><<<NROWS * (O / 4) / 256, blk, 0, s>>>(HMAX, HMIN, BNP, Xout);
}

// stage 4
static void run_stage4(const float* Xin, const float* W, const float* bias,
                       const float* g, const float* be, float* SCRBIG, float* UVA,
                       u16* XPH, u16* XPL, u16* WPH, u16* WPL,
                       u16* IDX, float* SQ, float* PART, float* PART2, float* BNP, float* G0T,
                       hipStream_t s) {
    constexpr int C = 128;
    dim3 blk(256);
    float* HMAX = SCRBIG;
    float* HMIN = SCRBIG + (size_t)NROWS * 256;
    sqnorm_kernel<C><<<NROWS / 256, blk, 0, s>>>(Xin, SQ);
    split_pack_kernel<C><<<NROWS * C / 8 / 256, blk, 0, s>>>(Xin, XPH, XPL);
    for (int b0 = 0; b0 < BATCH; b0 += 4) {
        dist_mfma_kernel<C><<<dim3(NPTS / 64, NPTS / 64, 4), blk, 0, s>>>(XPH, XPL, SCRBIG, b0);
        topk_kernel<<<dim3(NPTS / 4, 1, 4), blk, 0, s>>>(SCRBIG, SQ, IDX, b0);
    }
    wsplit_pack_kernel<C, 256><<<(512 * C / 8 + 255) / 256, blk, 0, s>>>(W, WPH, WPL);
    uvb_mfma_kernel<C, 256><<<dim3(8, NPTS / 64, BATCH), blk, 0, s>>>(XPH, XPL, WPH, WPL, bias, UVA);
    statsb_kernel<256><<<dim3(SB, 1, BATCH), blk, 0, s>>>(UVA, IDX, PART, HMAX, HMIN);
    part_reduce_kernel<256><<<PR, blk, 0, s>>>(PART, PART2);
    bnp_kernel<256><<<1, 256, 0, s>>>(PART2, g, be, BNP);
    fill_zero_kernel<<<14, blk, 0, s>>>(G0T, 448 * 8);
    applyb4_kernel<<<dim3(32, 1, BATCH), blk, 0, s>>>(HMAX, HMIN, BNP, G0T);
}

extern "C" void kernel_launch(void* const* d_in, const int* in_sizes, int n_in,
                              void* d_out, int out_size, void* d_ws, size_t ws_size,
                              hipStream_t stream) {
    float* out = (float*)d_out;
    if (n_in < 31) { diag_kernel<<<1, 64, 0, stream>>>(out, 9000.f); return; }

    const float* x       = (const float*)d_in[0];
    const float* cw[4]   = {(const float*)d_in[1], (const float*)d_in[5], (const float*)d_in[9],  (const float*)d_in[13]};
    const float* cb[4]   = {(const float*)d_in[2], (const float*)d_in[6], (const float*)d_in[10], (const float*)d_in[14]};
    const float* bg[4]   = {(const float*)d_in[3], (const float*)d_in[7], (const float*)d_in[11], (const float*)d_in[15]};
    const float* bb[4]   = {(const float*)d_in[4], (const float*)d_in[8], (const float*)d_in[12], (const float*)d_in[16]};
    const float* fc1_w = (const float*)d_in[17]; const float* fc1_b = (const float*)d_in[18];
    const float* bnf1_g = (const float*)d_in[19]; const float* bnf1_b = (const float*)d_in[20];
    const float* fc2_w = (const float*)d_in[21]; const float* fc2_b = (const float*)d_in[22];
    const float* bnf2_g = (const float*)d_in[23]; const float* bnf2_b = (const float*)d_in[24];
    const float* fc3_w = (const float*)d_in[25]; const float* fc3_b = (const float*)d_in[26];
    const float* bnf3_g = (const float*)d_in[27]; const float* bnf3_b = (const float*)d_in[28];
    const float* fc4_w = (const float*)d_in[29]; const float* fc4_b = (const float*)d_in[30];

    Arena ar(d_ws, ws_size);
    float* X1 = (float*)ar.get((size_t)NROWS * 64 * 4);
    float* X2 = (float*)ar.get((size_t)NROWS * 64 * 4);
    float* X3 = (float*)ar.get((size_t)NROWS * 128 * 4);
    u16* IDX = (u16*)ar.get((size_t)NROWS * KNN * 2);
    float* SQ = (float*)ar.get((size_t)NROWS * 4);
    float* PART = (float*)ar.get((size_t)BATCH * SB * 512 * 4);
    float* PART2 = (float*)ar.get((size_t)PR * 512 * 4);
    float* BNP = (float*)ar.get(512 * 4);
    float* G0T = (float*)ar.get(448 * 8 * 4);
    float* ABUF = (float*)ar.get(256 * 8 * 4);
    u16* XPH = (u16*)ar.get((size_t)NROWS * 128 * 2);
    u16* XPL = (u16*)ar.get((size_t)NROWS * 128 * 2);
    u16* WPH = (u16*)ar.get(512 * 128 * 2);
    u16* WPL = (u16*)ar.get(512 * 128 * 2);
    float* SCRBIG = (float*)ar.get((size_t)4 * NPTS * NPTS * 4);
    if (!ar.ok) {
        diag_kernel<<<1, 64, 0, stream>>>(out, 3000.f + (float)(ws_size >> 20));
        return;
    }
    float* UVA = SCRBIG + (size_t)2 * NPTS * NPTS;

    dim3 blk(256);
    run_stage<3, 64>(x, X1, cw[0], cb[0], bg[0], bb[0], SCRBIG, UVA, XPH, XPL, WPH, WPL, IDX, SQ, PART, PART2, BNP, stream);
    run_stage<64, 64>(X1, X2, cw[1], cb[1], bg[1], bb[1], SCRBIG, UVA, XPH, XPL, WPH, WPL, IDX, SQ, PART, PART2, BNP, stream);
    run_stage<64, 128>(X2, X3, cw[2], cb[2], bg[2], bb[2], SCRBIG, UVA, XPH, XPL, WPH, WPL, IDX, SQ, PART, PART2, BNP, stream);
    run_stage4(X3, cw[3], cb[3], bg[3], bb[3], SCRBIG, UVA, XPH, XPL, WPH, WPL, IDX, SQ, PART, PART2, BNP, G0T, stream);

    gmax23_kernel<<<dim3(BATCH, 64), blk, 0, stream>>>(X2, X3, G0T);

    float* W1T = SCRBIG;
    float* W2T = W1T + 448 * 256;
    float* W3T = W2T + 256 * 128;
    transpose_kernel<<<(256 * 448 + 255) / 256, blk, 0, stream>>>(fc1_w, W1T, 256, 448);
    transpose_kernel<<<(128 * 256 + 255) / 256, blk, 0, stream>>>(fc2_w, W2T, 128, 256);
    transpose_kernel<<<(16 * 128 + 255) / 256, blk, 0, stream>>>(fc3_w, W3T, 16, 128);
    fc1_kernel<<<4, 64, 0, stream>>>(G0T, W1T, fc1_b, bnf1_g, bnf1_b, ABUF);
    tail_kernel<<<1, 256, 0, stream>>>(ABUF, W2T, fc2_b, bnf2_g, bnf2_b,
                                       W3T, fc3_b, bnf3_g, bnf3_b, fc4_w, fc4_b, out);
}